// Round 10
// baseline (1135.018 us; speedup 1.0000x reference)
//
#include <hip/hip_runtime.h>
#include <hip/hip_bf16.h>

#define L_ 4
#define E_ 4
#define D_ 512
#define DFF_ 2048
#define H_ 8
#define B_ 16
#define T_ 256
#define S_ 512
#define HD_ 64
#define NSLOT 32   // B * K

typedef __attribute__((ext_vector_type(4))) float f32x4;
typedef __attribute__((ext_vector_type(8))) short bf16x8;
typedef __attribute__((ext_vector_type(4))) int i32x4;

static __device__ __forceinline__ float bf2f(unsigned short u){
  union{float f; unsigned u;} c; c.u = ((unsigned)u)<<16; return c.f;
}
static __device__ __forceinline__ unsigned short f2bf(float f){
  union{float f; unsigned u;} c; c.f=f;
  unsigned u=c.u;
  return (unsigned short)((u + 0x7FFFu + ((u>>16)&1u))>>16);
}

static __device__ __forceinline__ void gload16(const unsigned short* g, unsigned short* l){
  __builtin_amdgcn_global_load_lds(
      (const __attribute__((address_space(1))) void*)g,
      (__attribute__((address_space(3))) void*)l, 16, 0, 0);
}

// bijective XCD-chunked block remap (m204)
static __device__ __forceinline__ int xcd_swz(int orig, int nwg){
  int q = nwg >> 3, r = nwg & 7;
  int xcd = orig & 7, idx = orig >> 3;
  return (xcd < r) ? (xcd*(q+1) + idx) : (r*(q+1) + (xcd-r)*q + idx);
}

// ---------------- routing ----------------
__global__ void __launch_bounds__(256) route_k(const float* __restrict__ x,
    const float* __restrict__ rw, int* __restrict__ eidx, float* __restrict__ wgt)
{
  __shared__ float pooled[D_];
  __shared__ float logit[E_];
  int b = blockIdx.x, tid = threadIdx.x;
  for (int d = tid; d < D_; d += 256) {
    float s = 0.f;
    const float* xp = x + ((long)b*T_)*D_ + d;
    for (int t=0;t<T_;t++) s += xp[(long)t*D_];
    pooled[d] = s * (1.f/T_);
  }
  __syncthreads();
  int wave = tid>>6, lane = tid&63;
  {
    float s=0.f;
    const float* w = rw + (long)wave*D_;
    for (int d=lane; d<D_; d+=64) s += pooled[d]*w[d];
    #pragma unroll
    for (int o=32;o;o>>=1) s += __shfl_xor(s,o);
    if (lane==0) logit[wave] = s;
  }
  __syncthreads();
  if (tid==0){
    int i1=0; float v1=logit[0];
    for (int e=1;e<E_;e++) if (logit[e] > v1){ v1=logit[e]; i1=e; }
    int i2=-1; float v2=-3.4e38f;
    for (int e=0;e<E_;e++) if (e!=i1 && logit[e] > v2){ v2=logit[e]; i2=e; }
    float e2 = __expf(v2 - v1);
    float w1 = 1.f/(1.f+e2);
    eidx[2*b]=i1; eidx[2*b+1]=i2;
    wgt[2*b]=w1; wgt[2*b+1]=e2*w1;
  }
}

// ---------------- casts ----------------
__global__ void __launch_bounds__(256) cast_bf16_k(const float* __restrict__ in,
    unsigned short* __restrict__ out, long n){
  long i = ((long)blockIdx.x*blockDim.x + threadIdx.x)*4;
  long st = (long)gridDim.x*blockDim.x*4;
  for (; i<n; i+=st){
    float4 v = *(const float4*)(in+i);
    ushort4 o; o.x=f2bf(v.x); o.y=f2bf(v.y); o.z=f2bf(v.z); o.w=f2bf(v.w);
    *(ushort4*)(out+i) = o;
  }
}

// fused per-layer weight cast (6 segments)
__global__ void __launch_bounds__(256) cast_weights_k(
    const float* __restrict__ s0, const float* __restrict__ s1,
    const float* __restrict__ s2, const float* __restrict__ s3,
    const float* __restrict__ s4, const float* __restrict__ s5,
    unsigned short* __restrict__ d0, unsigned short* __restrict__ d1,
    unsigned short* __restrict__ d2, unsigned short* __restrict__ d3,
    unsigned short* __restrict__ d4, unsigned short* __restrict__ d5)
{
  const long N0=(long)E_*3*D_*D_, N1=(long)E_*D_*D_;
  const long N2=N0, N3=N1, N4=(long)E_*DFF_*D_, N5=N4;
  const long total = N0+N1+N2+N3+N4+N5;
  long i = ((long)blockIdx.x*256 + threadIdx.x)*4;
  long st = (long)gridDim.x*256*4;
  for (; i<total; i+=st){
    const float* s; unsigned short* d; long j = i;
    if (j < N0){ s=s0; d=d0; }
    else if ((j-=N0) < N1){ s=s1; d=d1; }
    else if ((j-=N1) < N2){ s=s2; d=d2; }
    else if ((j-=N2) < N3){ s=s3; d=d3; }
    else if ((j-=N3) < N4){ s=s4; d=d4; }
    else { j-=N4; s=s5; d=d5; }
    float4 v = *(const float4*)(s+j);
    ushort4 o; o.x=f2bf(v.x); o.y=f2bf(v.y); o.z=f2bf(v.z); o.w=f2bf(v.w);
    *(ushort4*)(d+j) = o;
  }
}

// ---------------- V transpose ----------------
__global__ void __launch_bounds__(256) vtrans_k(const unsigned short* __restrict__ src,
    long sSlot, int ld, unsigned short* __restrict__ dst, int rows)
{
  __shared__ unsigned short t[64][68];
  int s0 = blockIdx.x*64; int h = blockIdx.y; int slot = blockIdx.z;
  const unsigned short* sp = src + (long)slot*sSlot + (long)h*64;
  int c = threadIdx.x&63, w = threadIdx.x>>6;
  #pragma unroll
  for (int i=0;i<16;i++){
    int r = i*4 + w;
    t[r][c] = sp[(long)(s0+r)*ld + c];
  }
  __syncthreads();
  unsigned short* dp = dst + ((long)slot*H_ + h)*((long)64*rows) + s0;
  #pragma unroll
  for (int i=0;i<16;i++){
    int d = i*4 + w;
    dp[(long)d*rows + c] = t[c][d];
  }
}

// ---------------- fused flash attention ----------------
template<int NT>
__global__ void __launch_bounds__(256) fattn_k(
    const unsigned short* __restrict__ Qg, long qSlot, int ldq,
    const unsigned short* __restrict__ Kg, long kSlot, int ldk,
    const unsigned short* __restrict__ Vtg,
    unsigned short* __restrict__ Og, long oSlot, int ldo)
{
  constexpr int SLEN = NT*64;
  __shared__ unsigned short K_lds[64][72];
  __shared__ unsigned short V_lds[64][72];
  __shared__ unsigned short P_lds[4][16][72];

  int nwg = gridDim.x*gridDim.y;
  int wg = xcd_swz(blockIdx.x + gridDim.x*blockIdx.y, nwg);
  int qb = wg % gridDim.x;
  int z  = wg / gridDim.x;        // slot*H + h
  int slot = z >> 3, h = z & 7;
  int tid = threadIdx.x, wave = tid>>6, lane = tid&63;
  int lr = lane&15, lg = lane>>4;
  int lk = lg*8;

  const unsigned short* Qp = Qg + (long)slot*qSlot + (long)h*HD_;
  const unsigned short* Kp = Kg + (long)slot*kSlot + (long)h*HD_;
  const unsigned short* Vp = Vtg + (long)z*((long)HD_*SLEN);

  bf16x8 qf[2];
  {
    int qrow = qb*64 + wave*16 + lr;
    const unsigned short* qr = Qp + (long)qrow*ldq;
    qf[0] = *(const bf16x8*)(qr + lk);
    qf[1] = *(const bf16x8*)(qr + 32 + lk);
  }

  float m_prev[4], l_run[4];
  f32x4 acc_o[4];
  #pragma unroll
  for (int r=0;r<4;r++){ m_prev[r]=-1e30f; l_run[r]=0.f; }
  #pragma unroll
  for (int ni=0;ni<4;ni++) acc_o[ni]=(f32x4){0.f,0.f,0.f,0.f};

  int srow = tid>>3, sch = tid&7;

  i32x4 kr0 = *(const i32x4*)(Kp + (long)srow*ldk + sch*8);
  i32x4 kr1 = *(const i32x4*)(Kp + (long)(srow+32)*ldk + sch*8);
  i32x4 vr0 = *(const i32x4*)(Vp + (long)srow*SLEN + sch*8);
  i32x4 vr1 = *(const i32x4*)(Vp + (long)(srow+32)*SLEN + sch*8);

  for (int t=0; t<NT; ++t){
    __syncthreads();
    *(i32x4*)&K_lds[srow][sch*8] = kr0;
    *(i32x4*)&K_lds[srow+32][sch*8] = kr1;
    *(i32x4*)&V_lds[srow][sch*8] = vr0;
    *(i32x4*)&V_lds[srow+32][sch*8] = vr1;
    __syncthreads();

    int tn = (t+1 < NT) ? t+1 : t;
    int k0n = tn*64;
    kr0 = *(const i32x4*)(Kp + (long)(k0n+srow)*ldk + sch*8);
    kr1 = *(const i32x4*)(Kp + (long)(k0n+srow+32)*ldk + sch*8);
    vr0 = *(const i32x4*)(Vp + (long)srow*SLEN + k0n + sch*8);
    vr1 = *(const i32x4*)(Vp + (long)(srow+32)*SLEN + k0n + sch*8);

    // S = Q @ K^T
    f32x4 s[4];
    #pragma unroll
    for (int ni=0;ni<4;ni++) s[ni]=(f32x4){0.f,0.f,0.f,0.f};
    __builtin_amdgcn_s_setprio(1);
    #pragma unroll
    for (int ki=0;ki<2;ki++){
      #pragma unroll
      for (int ni=0;ni<4;ni++){
        bf16x8 kf = *(const bf16x8*)&K_lds[ni*16+lr][ki*32+lk];
        s[ni] = __builtin_amdgcn_mfma_f32_16x16x32_bf16(qf[ki], kf, s[ni],0,0,0);
      }
    }
    __builtin_amdgcn_s_setprio(0);
    // online softmax with rescale-skip (exact: corr==1 when max unchanged)
    float tmax[4];
    #pragma unroll
    for (int r=0;r<4;r++){
      tmax[r] = fmaxf(fmaxf(s[0][r],s[1][r]),fmaxf(s[2][r],s[3][r]));
      #pragma unroll
      for (int msk=1; msk<16; msk<<=1) tmax[r]=fmaxf(tmax[r], __shfl_xor(tmax[r],msk));
    }
    bool inc = (tmax[0]>m_prev[0])|(tmax[1]>m_prev[1])|(tmax[2]>m_prev[2])|(tmax[3]>m_prev[3]);
    if (__any(inc)){
      #pragma unroll
      for (int r=0;r<4;r++){
        float mnew = fmaxf(m_prev[r], tmax[r]);
        float corr = __expf(m_prev[r]-mnew);
        m_prev[r] = mnew;
        l_run[r] *= corr;
        #pragma unroll
        for (int ni=0;ni<4;ni++) acc_o[ni][r] *= corr;
      }
    }
    float rs[4] = {0.f,0.f,0.f,0.f};
    #pragma unroll
    for (int ni=0;ni<4;ni++){
      #pragma unroll
      for (int r=0;r<4;r++){
        float p = __expf(s[ni][r]-m_prev[r]);
        rs[r] += p;
        P_lds[wave][lg*4+r][ni*16+lr] = f2bf(p);
      }
    }
    #pragma unroll
    for (int r=0;r<4;r++){
      #pragma unroll
      for (int msk=1; msk<16; msk<<=1) rs[r] += __shfl_xor(rs[r],msk);
      l_run[r] += rs[r];
    }
    // O += P @ V
    __builtin_amdgcn_s_setprio(1);
    #pragma unroll
    for (int ki=0;ki<2;ki++){
      bf16x8 pf = *(const bf16x8*)&P_lds[wave][lr][ki*32+lk];
      #pragma unroll
      for (int ni=0;ni<4;ni++){
        bf16x8 vf = *(const bf16x8*)&V_lds[ni*16+lr][ki*32+lk];
        acc_o[ni] = __builtin_amdgcn_mfma_f32_16x16x32_bf16(pf, vf, acc_o[ni],0,0,0);
      }
    }
    __builtin_amdgcn_s_setprio(0);
  }
  unsigned short* Op = Og + (long)slot*oSlot + (long)h*HD_;
  #pragma unroll
  for (int r=0;r<4;r++){
    float inv = 1.f/l_run[r];
    int q = qb*64 + wave*16 + lg*4 + r;
    #pragma unroll
    for (int ni=0;ni<4;ni++)
      Op[(long)q*ldo + ni*16 + lr] = f2bf(acc_o[ni][r]*inv);
  }
}

// ---------------- LDS-staged GEMM  C = A @ W^T (+bias)(*scale)(relu), optional split-K ----------------
// dbuf LDS, chunk-XOR swizzle, 8 waves, XCD remap.
//   <128,128,64,32,64,KS> : small GEMMs (KS=2 split-K -> 2 blocks/CU)
//   <128,256,64,64,32,1>  : big GEMMs
template<int BM, int BN, int WTM, int WTN, int BK, int KS>
__global__ void __launch_bounds__(512) gemm_lds(
    const unsigned short* __restrict__ A, long aSlot, int aDiv, long aHead, int lda,
    const unsigned short* __restrict__ W, long wSlot, long wHead, long wExp, int ldw,
    const int* __restrict__ eidx, const float* __restrict__ bias, long biasExp,
    void* __restrict__ Cp, long cSlot, long cHead, int ldc, long cSplit,
    int K, int HZ, int f32out, int relu, int scaleNlim, float scaleVal)
{
  constexpr int WAVES_N = BN/WTN;
  constexpr int MI = WTM/16, NI = WTN/16;
  constexpr int SLOTS = BK/8;
  static_assert((BM/WTM)*(BN/WTN) == 8, "8 waves");
  static_assert((BM*SLOTS)%512==0 && (BN*SLOTS)%512==0, "stage coverage");
  __shared__ unsigned short smem[2*(BM+BN)*BK];

  int nwg = gridDim.x*gridDim.y*gridDim.z;
  int wg = xcd_swz(blockIdx.x + gridDim.x*(blockIdx.y + gridDim.y*blockIdx.z), nwg);
  int bx = wg % gridDim.x; int t1 = wg / gridDim.x;
  int by = t1 % gridDim.y; int zz = t1 / gridDim.y;

  int ks = zz % KS; int z = zz / KS;
  int slot = z / HZ;
  int h = z - slot*HZ;
  int e = eidx ? eidx[slot] : 0;
  const unsigned short* Ap = A + (long)(slot/aDiv)*aSlot + (long)h*aHead + (long)ks*K;
  const unsigned short* Wp = W + (long)slot*wSlot + (long)h*wHead + (long)e*wExp + (long)ks*K;
  const float* bp = (bias && ks==0) ? (bias + (long)e*biasExp) : nullptr;

  int tid  = threadIdx.x;
  int wave = tid>>6, lane = tid&63;
  int wm = wave / WAVES_N, wn = wave % WAVES_N;
  int bm0 = by*BM;
  int bn0 = bx*BN;
  int lr = lane&15;
  int lg = lane>>4;
  int swz = (BK==64) ? (lr&7) : ((lr>>1)&3);

  Ap += (long)bm0*lda;
  Wp += (long)bn0*ldw;

  f32x4 acc[MI][NI];
  #pragma unroll
  for (int i=0;i<MI;i++)
  #pragma unroll
  for (int j=0;j<NI;j++) acc[i][j] = (f32x4){0.f,0.f,0.f,0.f};

  auto stage = [&](int buf, int k0){
    unsigned short* as = &smem[(size_t)buf*(BM+BN)*BK];
    unsigned short* bs = as + BM*BK;
    #pragma unroll
    for (int i=0;i<BM*SLOTS/512;i++){
      int cch = i*512 + tid;
      int row = cch / SLOTS, c = cch % SLOTS;
      int cs = (BK==64) ? (c ^ (row&7)) : (c ^ ((row>>1)&3));
      gload16(Ap + (long)row*lda + k0 + (cs<<3), as + cch*8);
    }
    #pragma unroll
    for (int i=0;i<BN*SLOTS/512;i++){
      int cch = i*512 + tid;
      int row = cch / SLOTS, c = cch % SLOTS;
      int cs = (BK==64) ? (c ^ (row&7)) : (c ^ ((row>>1)&3));
      gload16(Wp + (long)row*ldw + k0 + (cs<<3), bs + cch*8);
    }
  };

  auto compute = [&](int buf){
    unsigned short* as = &smem[(size_t)buf*(BM+BN)*BK];
    unsigned short* bs = as + BM*BK;
    #pragma unroll
    for (int ki=0;ki<BK/32;ki++){
      bf16x8 af[MI], bfr[NI];
      #pragma unroll
      for (int mi=0;mi<MI;mi++){
        int row = wm*WTM + mi*16 + lr;
        af[mi] = *(const bf16x8*)&as[row*BK + (((ki*4+lg) ^ swz)<<3)];
      }
      #pragma unroll
      for (int ni=0;ni<NI;ni++){
        int row = wn*WTN + ni*16 + lr;
        bfr[ni] = *(const bf16x8*)&bs[row*BK + (((ki*4+lg) ^ swz)<<3)];
      }
      __builtin_amdgcn_s_setprio(1);
      #pragma unroll
      for (int mi=0;mi<MI;mi++)
      #pragma unroll
      for (int ni=0;ni<NI;ni++)
        acc[mi][ni] = __builtin_amdgcn_mfma_f32_16x16x32_bf16(af[mi], bfr[ni], acc[mi][ni], 0,0,0);
      __builtin_amdgcn_s_setprio(0);
    }
  };

  int NT = K / BK;
  stage(0, 0);
  __syncthreads();
  int cur = 0;
  for (int t=0; t<NT; ++t){
    if (t+1 < NT) stage(cur^1, (t+1)*BK);
    compute(cur);
    __syncthreads();
    cur ^= 1;
  }

  long cbase = (long)slot*cSlot + (long)h*cHead + (long)ks*cSplit;
  int rbase = lg*4;
  #pragma unroll
  for (int mi=0;mi<MI;mi++)
  #pragma unroll
  for (int ni=0;ni<NI;ni++){
    f32x4 v = acc[mi][ni];
    int n = bn0 + wn*WTN + ni*16 + lr;
    float bv = bp ? bp[n] : 0.f;
    float scv = (n < scaleNlim) ? scaleVal : 1.f;
    #pragma unroll
    for (int r=0;r<4;r++){
      int m = bm0 + wm*WTM + mi*16 + rbase + r;
      float val = (v[r] + bv) * scv;
      if (relu) val = fmaxf(val, 0.f);
      long o = cbase + (long)m*ldc + n;
      if (f32out) ((float*)Cp)[o] = val;
      else ((unsigned short*)Cp)[o] = f2bf(val);
    }
  }
}

// ---------------- residual add (+optional second partial) + LayerNorm ----------------
__global__ void __launch_bounds__(256) add_ln_k(
    const float* __restrict__ Ab, int aDiv, long aStride,
    const float* __restrict__ Bb, const float* __restrict__ Bb2, long bStride,
    const float* __restrict__ G, const float* __restrict__ Bt,
    const int* __restrict__ eidx,
    float* __restrict__ OutF, unsigned short* __restrict__ OutB)
{
  int row = blockIdx.x*4 + (threadIdx.x>>6);
  int slot = row>>8, t = row&255;
  int lane = threadIdx.x&63;
  const float* a = Ab + (long)(slot/aDiv)*aStride + (long)t*D_;
  const float* b = Bb + (long)slot*bStride + (long)t*D_;
  const float* b2 = Bb2 ? (Bb2 + (long)slot*bStride + (long)t*D_) : nullptr;
  int e = eidx[slot];
  const float* g  = G  + (long)e*D_;
  const float* bt = Bt + (long)e*D_;
  float x[8]; float s=0.f;
  #pragma unroll
  for (int i=0;i<8;i++){
    float v = a[lane+i*64]+b[lane+i*64];
    if (b2) v += b2[lane+i*64];
    x[i]=v; s+=v;
  }
  #pragma unroll
  for (int o=32;o;o>>=1) s += __shfl_xor(s,o);
  float m = s*(1.f/D_);
  float q=0.f;
  #pragma unroll
  for (int i=0;i<8;i++){ float d=x[i]-m; q+=d*d; }
  #pragma unroll
  for (int o=32;o;o>>=1) q += __shfl_xor(q,o);
  float rs = rsqrtf(q*(1.f/D_)+1e-5f);
  long ob = (long)slot*(T_*D_) + (long)t*D_;
  #pragma unroll
  for (int i=0;i<8;i++){
    int d = lane+i*64;
    float y = (x[i]-m)*rs*g[d]+bt[d];
    OutF[ob+d]=y;
    if (OutB) OutB[ob+d]=f2bf(y);
  }
}

// ---------------- residual add(2 partials) + LayerNorm (n3) + weighted combine ----------------
__global__ void __launch_bounds__(256) add_ln_comb_k(
    const float* __restrict__ x2, const float* __restrict__ proj, const float* __restrict__ proj2,
    const float* __restrict__ G, const float* __restrict__ Bt,
    const int* __restrict__ eidx, const float* __restrict__ wgt,
    float* __restrict__ dstF, unsigned short* __restrict__ dstB)
{
  int row = blockIdx.x*4 + (threadIdx.x>>6);   // b*256+t
  int b = row>>8, t = row&255;
  int lane = threadIdx.x&63;
  float out[8];
  #pragma unroll
  for (int i=0;i<8;i++) out[i]=0.f;
  #pragma unroll
  for (int s2i=0;s2i<2;s2i++){
    int slot = 2*b + s2i;
    int e = eidx[slot];
    float w = wgt[slot];
    const float* a = x2 + (long)slot*(T_*D_) + (long)t*D_;
    const float* p = proj + (long)slot*(T_*D_) + (long)t*D_;
    const float* p2 = proj2 + (long)slot*(T_*D_) + (long)t*D_;
    const float* g  = G  + (long)e*D_;
    const float* bt = Bt + (long)e*D_;
    float x[8]; float s=0.f;
    #pragma unroll
    for (int i=0;i<8;i++){ x[i] = a[lane+i*64]+p[lane+i*64]+p2[lane+i*64]; s+=x[i]; }
    #pragma unroll
    for (int o=32;o;o>>=1) s += __shfl_xor(s,o);
    float m = s*(1.f/D_);
    float q=0.f;
    #pragma unroll
    for (int i=0;i<8;i++){ float d=x[i]-m; q+=d*d; }
    #pragma unroll
    for (int o=32;o;o>>=1) q += __shfl_xor(q,o);
    float rs = rsqrtf(q*(1.f/D_)+1e-5f);
    #pragma unroll
    for (int i=0;i<8;i++){
      int d = lane+i*64;
      out[i] += w*((x[i]-m)*rs*g[d]+bt[d]);
    }
  }
  long ob = (long)row*D_;
  #pragma unroll
  for (int i=0;i<8;i++){
    int d = lane+i*64;
    dstF[ob+d] = out[i];
    dstB[ob+d] = f2bf(out[i]);
  }
}

extern "C" void kernel_launch(void* const* d_in, const int* in_sizes, int n_in,
                              void* d_out, int out_size, void* d_ws, size_t ws_size,
                              hipStream_t stream)
{
  const float* tgt      = (const float*)d_in[0];
  const float* memory   = (const float*)d_in[1];
  const float* router_w = (const float*)d_in[2];
  const float* sa_in_w  = (const float*)d_in[3];
  const float* sa_in_b  = (const float*)d_in[4];
  const float* sa_out_w = (const float*)d_in[5];
  const float* sa_out_b = (const float*)d_in[6];
  const float* ca_in_w  = (const float*)d_in[7];
  const float* ca_in_b  = (const float*)d_in[8];
  const float* ca_out_w = (const float*)d_in[9];
  const float* ca_out_b = (const float*)d_in[10];
  const float* lin1_w   = (const float*)d_in[11];
  const float* lin1_b   = (const float*)d_in[12];
  const float* lin2_w   = (const float*)d_in[13];
  const float* lin2_b   = (const float*)d_in[14];
  const float* n1_g = (const float*)d_in[15];
  const float* n1_b = (const float*)d_in[16];
  const float* n2_g = (const float*)d_in[17];
  const float* n2_b = (const float*)d_in[18];
  const float* n3_g = (const float*)d_in[19];
  const float* n3_b = (const float*)d_in[20];

  char* ws = (char*)d_ws;
  size_t off = 0;
  auto alloc = [&](size_t bytes)->char*{
    char* p = ws + off; off += (bytes + 255) & ~(size_t)255; return p;
  };
  unsigned short* xb    = (unsigned short*)alloc(2ull*B_*T_*D_);
  unsigned short* memb  = (unsigned short*)alloc(2ull*B_*S_*D_);
  float*          x     = (float*)alloc(4ull*B_*T_*D_);
  int*            eidx  = (int*)alloc(4ull*NSLOT);
  float*          wgt   = (float*)alloc(4ull*NSLOT);
  unsigned short* wSaIn  = (unsigned short*)alloc(2ull*E_*3*D_*D_);
  unsigned short* wSaOut = (unsigned short*)alloc(2ull*E_*D_*D_);
  unsigned short* wCaIn  = (unsigned short*)alloc(2ull*E_*3*D_*D_);
  unsigned short* wCaOut = (unsigned short*)alloc(2ull*E_*D_*D_);
  unsigned short* wL1    = (unsigned short*)alloc(2ull*E_*DFF_*D_);
  unsigned short* wL2    = (unsigned short*)alloc(2ull*E_*D_*DFF_);
  unsigned short* qkv   = (unsigned short*)alloc(2ull*NSLOT*T_*3*D_);
  unsigned short* ffh   = (unsigned short*)alloc(2ull*NSLOT*T_*DFF_);
  unsigned short* attn  = (unsigned short*)alloc(2ull*NSLOT*T_*D_);
  float*          proj  = (float*)alloc(4ull*NSLOT*T_*D_);
  float*          proj2 = (float*)alloc(4ull*NSLOT*T_*D_);
  float*          x1    = (float*)alloc(4ull*NSLOT*T_*D_);
  unsigned short* x1b   = (unsigned short*)alloc(2ull*NSLOT*T_*D_);
  unsigned short* cq    = (unsigned short*)alloc(2ull*NSLOT*T_*D_);
  unsigned short* mkv   = (unsigned short*)alloc(2ull*NSLOT*S_*2*D_);
  float*          x2    = (float*)alloc(4ull*NSLOT*T_*D_);
  unsigned short* x2b   = (unsigned short*)alloc(2ull*NSLOT*T_*D_);
  unsigned short* Vt1   = cq;   // alias
  unsigned short* Vt2   = qkv;  // alias
  long projSplit = (long)(proj2 - proj);

  cast_bf16_k<<<1024,256,0,stream>>>(tgt,    xb,   (long)B_*T_*D_);
  cast_bf16_k<<<1024,256,0,stream>>>(memory, memb, (long)B_*S_*D_);

  const float* xcur = tgt;
  for (int l=0; l<L_; ++l){
    route_k<<<B_,256,0,stream>>>(xcur, router_w + (size_t)l*E_*D_, eidx, wgt);
    cast_weights_k<<<2048,256,0,stream>>>(
      sa_in_w  + (size_t)l*E_*3*D_*D_, sa_out_w + (size_t)l*E_*D_*D_,
      ca_in_w  + (size_t)l*E_*3*D_*D_, ca_out_w + (size_t)l*E_*D_*D_,
      lin1_w   + (size_t)l*E_*DFF_*D_, lin2_w   + (size_t)l*E_*D_*DFF_,
      wSaIn, wSaOut, wCaIn, wCaOut, wL1, wL2);

    // QKV = x @ sa_in^T + b  (Q cols scaled by 1/8)
    gemm_lds<128,256,64,64,32,1><<<dim3(6,2,NSLOT),512,0,stream>>>(
      xb, (long)T_*D_, 2, 0, D_,
      wSaIn, 0, 0, (long)3*D_*D_, D_,
      eidx, sa_in_b + (size_t)l*E_*3*D_, 3*D_,
      qkv, (long)T_*3*D_, 0, 3*D_, 0,
      512, 1, 0, 0, D_, 0.125f);
    // Vt1 = transpose of self V
    vtrans_k<<<dim3(T_/64,H_,NSLOT),256,0,stream>>>(
      qkv + 2*D_, (long)T_*3*D_, 3*D_, Vt1, T_);
    // fused self-attention
    fattn_k<4><<<dim3(T_/64, NSLOT*H_),256,0,stream>>>(
      qkv, (long)T_*3*D_, 3*D_,
      qkv + D_, (long)T_*3*D_, 3*D_,
      Vt1, attn, (long)T_*D_, D_);
    // self-attn out proj (fp32, split-K=2)
    gemm_lds<128,128,64,32,64,2><<<dim3(4,2,NSLOT*2),512,0,stream>>>(
      attn, (long)T_*D_, 1, 0, D_,
      wSaOut, 0, 0, (long)D_*D_, D_,
      eidx, sa_out_b + (size_t)l*E_*D_, D_,
      proj, (long)T_*D_, 0, D_, projSplit,
      256, 1, 1, 0, 0, 1.f);
    add_ln_k<<<2048,256,0,stream>>>(xcur, 2, (long)T_*D_, proj, proj2, (long)T_*D_,
      n1_g + (size_t)l*E_*D_, n1_b + (size_t)l*E_*D_, eidx, x1, x1b);
    // cross-attn Q (scaled)
    gemm_lds<128,128,64,32,64,1><<<dim3(4,2,NSLOT),512,0,stream>>>(
      x1b, (long)T_*D_, 1, 0, D_,
      wCaIn, 0, 0, (long)3*D_*D_, D_,
      eidx, ca_in_b + (size_t)l*E_*3*D_, 3*D_,
      cq, (long)T_*D_, 0, D_, 0,
      512, 1, 0, 0, D_, 0.125f);
    // cross-attn K,V from memory
    gemm_lds<128,256,64,64,32,1><<<dim3(4,4,NSLOT),512,0,stream>>>(
      memb, (long)S_*D_, 2, 0, D_,
      wCaIn + (size_t)D_*D_, 0, 0, (long)3*D_*D_, D_,
      eidx, ca_in_b + (size_t)l*E_*3*D_ + D_, 3*D_,
      mkv, (long)S_*2*D_, 0, 2*D_, 0,
      512, 1, 0, 0, 0, 1.f);
    // Vt2 = transpose of cross V
    vtrans_k<<<dim3(S_/64,H_,NSLOT),256,0,stream>>>(
      mkv + D_, (long)S_*2*D_, 2*D_, Vt2, S_);
    // fused cross-attention
    fattn_k<8><<<dim3(T_/64, NSLOT*H_),256,0,stream>>>(
      cq, (long)T_*D_, D_,
      mkv, (long)S_*2*D_, 2*D_,
      Vt2, attn, (long)T_*D_, D_);
    // cross-attn out proj (fp32, split-K=2)
    gemm_lds<128,128,64,32,64,2><<<dim3(4,2,NSLOT*2),512,0,stream>>>(
      attn, (long)T_*D_, 1, 0, D_,
      wCaOut, 0, 0, (long)D_*D_, D_,
      eidx, ca_out_b + (size_t)l*E_*D_, D_,
      proj, (long)T_*D_, 0, D_, projSplit,
      256, 1, 1, 0, 0, 1.f);
    add_ln_k<<<2048,256,0,stream>>>(x1, 1, (long)T_*D_, proj, proj2, (long)T_*D_,
      n2_g + (size_t)l*E_*D_, n2_b + (size_t)l*E_*D_, eidx, x2, x2b);
    // FFN1 (+relu)
    gemm_lds<128,256,64,64,32,1><<<dim3(8,2,NSLOT),512,0,stream>>>(
      x2b, (long)T_*D_, 1, 0, D_,
      wL1, 0, 0, (long)DFF_*D_, D_,
      eidx, lin1_b + (size_t)l*E_*DFF_, DFF_,
      ffh, (long)T_*DFF_, 0, DFF_, 0,
      512, 1, 0, 1, 0, 1.f);
    // FFN2 (fp32, split-K=2)
    gemm_lds<128,128,64,32,64,2><<<dim3(4,2,NSLOT*2),512,0,stream>>>(
      ffh, (long)T_*DFF_, 1, 0, DFF_,
      wL2, 0, 0, (long)D_*DFF_, DFF_,
      eidx, lin2_b + (size_t)l*E_*D_, D_,
      proj, (long)T_*D_, 0, D_, projSplit,
      1024, 1, 1, 0, 0, 1.f);
    // n3 LN + weighted combine
    float* dstF = (l==L_-1) ? (float*)d_out : x;
    add_ln_comb_k<<<1024,256,0,stream>>>(x2, proj, proj2,
      n3_g + (size_t)l*E_*D_, n3_b + (size_t)l*E_*D_, eidx, wgt, dstF, xb);
    xcur = x;
  }
}

// Round 11
// 1080.793 us; speedup vs baseline: 1.0502x; 1.0502x over previous
//
#include <hip/hip_runtime.h>
#include <hip/hip_bf16.h>

#define L_ 4
#define E_ 4
#define D_ 512
#define DFF_ 2048
#define H_ 8
#define B_ 16
#define T_ 256
#define S_ 512
#define HD_ 64
#define NSLOT 32   // B * K

typedef __attribute__((ext_vector_type(4))) float f32x4;
typedef __attribute__((ext_vector_type(8))) short bf16x8;
typedef __attribute__((ext_vector_type(4))) int i32x4;

static __device__ __forceinline__ float bf2f(unsigned short u){
  union{float f; unsigned u;} c; c.u = ((unsigned)u)<<16; return c.f;
}
static __device__ __forceinline__ unsigned short f2bf(float f){
  union{float f; unsigned u;} c; c.f=f;
  unsigned u=c.u;
  return (unsigned short)((u + 0x7FFFu + ((u>>16)&1u))>>16);
}

static __device__ __forceinline__ void gload16(const unsigned short* g, unsigned short* l){
  __builtin_amdgcn_global_load_lds(
      (const __attribute__((address_space(1))) void*)g,
      (__attribute__((address_space(3))) void*)l, 16, 0, 0);
}

// bijective XCD-chunked block remap (m204)
static __device__ __forceinline__ int xcd_swz(int orig, int nwg){
  int q = nwg >> 3, r = nwg & 7;
  int xcd = orig & 7, idx = orig >> 3;
  return (xcd < r) ? (xcd*(q+1) + idx) : (r*(q+1) + (xcd-r)*q + idx);
}

// ---------------- routing ----------------
__global__ void __launch_bounds__(256) route_k(const float* __restrict__ x,
    const float* __restrict__ rw, int* __restrict__ eidx, float* __restrict__ wgt)
{
  __shared__ float pooled[D_];
  __shared__ float logit[E_];
  int b = blockIdx.x, tid = threadIdx.x;
  for (int d = tid; d < D_; d += 256) {
    float s = 0.f;
    const float* xp = x + ((long)b*T_)*D_ + d;
    for (int t=0;t<T_;t++) s += xp[(long)t*D_];
    pooled[d] = s * (1.f/T_);
  }
  __syncthreads();
  int wave = tid>>6, lane = tid&63;
  {
    float s=0.f;
    const float* w = rw + (long)wave*D_;
    for (int d=lane; d<D_; d+=64) s += pooled[d]*w[d];
    #pragma unroll
    for (int o=32;o;o>>=1) s += __shfl_xor(s,o);
    if (lane==0) logit[wave] = s;
  }
  __syncthreads();
  if (tid==0){
    int i1=0; float v1=logit[0];
    for (int e=1;e<E_;e++) if (logit[e] > v1){ v1=logit[e]; i1=e; }
    int i2=-1; float v2=-3.4e38f;
    for (int e=0;e<E_;e++) if (e!=i1 && logit[e] > v2){ v2=logit[e]; i2=e; }
    float e2 = __expf(v2 - v1);
    float w1 = 1.f/(1.f+e2);
    eidx[2*b]=i1; eidx[2*b+1]=i2;
    wgt[2*b]=w1; wgt[2*b+1]=e2*w1;
  }
}

// ---------------- casts ----------------
__global__ void __launch_bounds__(256) cast_bf16_k(const float* __restrict__ in,
    unsigned short* __restrict__ out, long n){
  long i = ((long)blockIdx.x*blockDim.x + threadIdx.x)*4;
  long st = (long)gridDim.x*blockDim.x*4;
  for (; i<n; i+=st){
    float4 v = *(const float4*)(in+i);
    ushort4 o; o.x=f2bf(v.x); o.y=f2bf(v.y); o.z=f2bf(v.z); o.w=f2bf(v.w);
    *(ushort4*)(out+i) = o;
  }
}

// fused per-layer weight cast (6 segments)
__global__ void __launch_bounds__(256) cast_weights_k(
    const float* __restrict__ s0, const float* __restrict__ s1,
    const float* __restrict__ s2, const float* __restrict__ s3,
    const float* __restrict__ s4, const float* __restrict__ s5,
    unsigned short* __restrict__ d0, unsigned short* __restrict__ d1,
    unsigned short* __restrict__ d2, unsigned short* __restrict__ d3,
    unsigned short* __restrict__ d4, unsigned short* __restrict__ d5)
{
  const long N0=(long)E_*3*D_*D_, N1=(long)E_*D_*D_;
  const long N2=N0, N3=N1, N4=(long)E_*DFF_*D_, N5=N4;
  const long total = N0+N1+N2+N3+N4+N5;
  long i = ((long)blockIdx.x*256 + threadIdx.x)*4;
  long st = (long)gridDim.x*256*4;
  for (; i<total; i+=st){
    const float* s; unsigned short* d; long j = i;
    if (j < N0){ s=s0; d=d0; }
    else if ((j-=N0) < N1){ s=s1; d=d1; }
    else if ((j-=N1) < N2){ s=s2; d=d2; }
    else if ((j-=N2) < N3){ s=s3; d=d3; }
    else if ((j-=N3) < N4){ s=s4; d=d4; }
    else { j-=N4; s=s5; d=d5; }
    float4 v = *(const float4*)(s+j);
    ushort4 o; o.x=f2bf(v.x); o.y=f2bf(v.y); o.z=f2bf(v.z); o.w=f2bf(v.w);
    *(ushort4*)(d+j) = o;
  }
}

// ---------------- V transpose ----------------
__global__ void __launch_bounds__(256) vtrans_k(const unsigned short* __restrict__ src,
    long sSlot, int ld, unsigned short* __restrict__ dst, int rows)
{
  __shared__ unsigned short t[64][68];
  int s0 = blockIdx.x*64; int h = blockIdx.y; int slot = blockIdx.z;
  const unsigned short* sp = src + (long)slot*sSlot + (long)h*64;
  int c = threadIdx.x&63, w = threadIdx.x>>6;
  #pragma unroll
  for (int i=0;i<16;i++){
    int r = i*4 + w;
    t[r][c] = sp[(long)(s0+r)*ld + c];
  }
  __syncthreads();
  unsigned short* dp = dst + ((long)slot*H_ + h)*((long)64*rows) + s0;
  #pragma unroll
  for (int i=0;i<16;i++){
    int d = i*4 + w;
    dp[(long)d*rows + c] = t[c][d];
  }
}

// ---------------- fused flash attention ----------------
template<int NT>
__global__ void __launch_bounds__(256) fattn_k(
    const unsigned short* __restrict__ Qg, long qSlot, int ldq,
    const unsigned short* __restrict__ Kg, long kSlot, int ldk,
    const unsigned short* __restrict__ Vtg,
    unsigned short* __restrict__ Og, long oSlot, int ldo)
{
  constexpr int SLEN = NT*64;
  __shared__ unsigned short K_lds[64][72];
  __shared__ unsigned short V_lds[64][72];
  __shared__ unsigned short P_lds[4][16][72];

  int nwg = gridDim.x*gridDim.y;
  int wg = xcd_swz(blockIdx.x + gridDim.x*blockIdx.y, nwg);
  int qb = wg % gridDim.x;
  int z  = wg / gridDim.x;        // slot*H + h
  int slot = z >> 3, h = z & 7;
  int tid = threadIdx.x, wave = tid>>6, lane = tid&63;
  int lr = lane&15, lg = lane>>4;
  int lk = lg*8;

  const unsigned short* Qp = Qg + (long)slot*qSlot + (long)h*HD_;
  const unsigned short* Kp = Kg + (long)slot*kSlot + (long)h*HD_;
  const unsigned short* Vp = Vtg + (long)z*((long)HD_*SLEN);

  bf16x8 qf[2];
  {
    int qrow = qb*64 + wave*16 + lr;
    const unsigned short* qr = Qp + (long)qrow*ldq;
    qf[0] = *(const bf16x8*)(qr + lk);
    qf[1] = *(const bf16x8*)(qr + 32 + lk);
  }

  float m_prev[4], l_run[4];
  f32x4 acc_o[4];
  #pragma unroll
  for (int r=0;r<4;r++){ m_prev[r]=-1e30f; l_run[r]=0.f; }
  #pragma unroll
  for (int ni=0;ni<4;ni++) acc_o[ni]=(f32x4){0.f,0.f,0.f,0.f};

  int srow = tid>>3, sch = tid&7;

  i32x4 kr0 = *(const i32x4*)(Kp + (long)srow*ldk + sch*8);
  i32x4 kr1 = *(const i32x4*)(Kp + (long)(srow+32)*ldk + sch*8);
  i32x4 vr0 = *(const i32x4*)(Vp + (long)srow*SLEN + sch*8);
  i32x4 vr1 = *(const i32x4*)(Vp + (long)(srow+32)*SLEN + sch*8);

  for (int t=0; t<NT; ++t){
    __syncthreads();
    *(i32x4*)&K_lds[srow][sch*8] = kr0;
    *(i32x4*)&K_lds[srow+32][sch*8] = kr1;
    *(i32x4*)&V_lds[srow][sch*8] = vr0;
    *(i32x4*)&V_lds[srow+32][sch*8] = vr1;
    __syncthreads();

    int tn = (t+1 < NT) ? t+1 : t;
    int k0n = tn*64;
    kr0 = *(const i32x4*)(Kp + (long)(k0n+srow)*ldk + sch*8);
    kr1 = *(const i32x4*)(Kp + (long)(k0n+srow+32)*ldk + sch*8);
    vr0 = *(const i32x4*)(Vp + (long)srow*SLEN + k0n + sch*8);
    vr1 = *(const i32x4*)(Vp + (long)(srow+32)*SLEN + k0n + sch*8);

    // S = Q @ K^T
    f32x4 s[4];
    #pragma unroll
    for (int ni=0;ni<4;ni++) s[ni]=(f32x4){0.f,0.f,0.f,0.f};
    __builtin_amdgcn_s_setprio(1);
    #pragma unroll
    for (int ki=0;ki<2;ki++){
      #pragma unroll
      for (int ni=0;ni<4;ni++){
        bf16x8 kf = *(const bf16x8*)&K_lds[ni*16+lr][ki*32+lk];
        s[ni] = __builtin_amdgcn_mfma_f32_16x16x32_bf16(qf[ki], kf, s[ni],0,0,0);
      }
    }
    __builtin_amdgcn_s_setprio(0);
    // online softmax with rescale-skip (exact: corr==1 when max unchanged)
    float tmax[4];
    #pragma unroll
    for (int r=0;r<4;r++){
      tmax[r] = fmaxf(fmaxf(s[0][r],s[1][r]),fmaxf(s[2][r],s[3][r]));
      #pragma unroll
      for (int msk=1; msk<16; msk<<=1) tmax[r]=fmaxf(tmax[r], __shfl_xor(tmax[r],msk));
    }
    bool inc = (tmax[0]>m_prev[0])|(tmax[1]>m_prev[1])|(tmax[2]>m_prev[2])|(tmax[3]>m_prev[3]);
    if (__any(inc)){
      #pragma unroll
      for (int r=0;r<4;r++){
        float mnew = fmaxf(m_prev[r], tmax[r]);
        float corr = __expf(m_prev[r]-mnew);
        m_prev[r] = mnew;
        l_run[r] *= corr;
        #pragma unroll
        for (int ni=0;ni<4;ni++) acc_o[ni][r] *= corr;
      }
    }
    float rs[4] = {0.f,0.f,0.f,0.f};
    #pragma unroll
    for (int ni=0;ni<4;ni++){
      #pragma unroll
      for (int r=0;r<4;r++){
        float p = __expf(s[ni][r]-m_prev[r]);
        rs[r] += p;
        P_lds[wave][lg*4+r][ni*16+lr] = f2bf(p);
      }
    }
    #pragma unroll
    for (int r=0;r<4;r++){
      #pragma unroll
      for (int msk=1; msk<16; msk<<=1) rs[r] += __shfl_xor(rs[r],msk);
      l_run[r] += rs[r];
    }
    // O += P @ V
    __builtin_amdgcn_s_setprio(1);
    #pragma unroll
    for (int ki=0;ki<2;ki++){
      bf16x8 pf = *(const bf16x8*)&P_lds[wave][lr][ki*32+lk];
      #pragma unroll
      for (int ni=0;ni<4;ni++){
        bf16x8 vf = *(const bf16x8*)&V_lds[ni*16+lr][ki*32+lk];
        acc_o[ni] = __builtin_amdgcn_mfma_f32_16x16x32_bf16(pf, vf, acc_o[ni],0,0,0);
      }
    }
    __builtin_amdgcn_s_setprio(0);
  }
  unsigned short* Op = Og + (long)slot*oSlot + (long)h*HD_;
  #pragma unroll
  for (int r=0;r<4;r++){
    float inv = 1.f/l_run[r];
    int q = qb*64 + wave*16 + lg*4 + r;
    #pragma unroll
    for (int ni=0;ni<4;ni++)
      Op[(long)q*ldo + ni*16 + lr] = f2bf(acc_o[ni][r]*inv);
  }
}

// ---------------- LDS-staged GEMM  C = A @ W^T (+bias)(*scale)(relu) ----------------
// dbuf LDS, chunk-XOR swizzle, 8 waves, XCD remap.
//   <128,128,64,32,64> : small GEMMs
//   <128,256,64,64,32> : big GEMMs
template<int BM, int BN, int WTM, int WTN, int BK>
__global__ void __launch_bounds__(512) gemm_lds(
    const unsigned short* __restrict__ A, long aSlot, int aDiv, long aHead, int lda,
    const unsigned short* __restrict__ W, long wSlot, long wHead, long wExp, int ldw,
    const int* __restrict__ eidx, const float* __restrict__ bias, long biasExp,
    void* __restrict__ Cp, long cSlot, long cHead, int ldc,
    int K, int HZ, int f32out, int relu, int scaleNlim, float scaleVal)
{
  constexpr int WAVES_N = BN/WTN;
  constexpr int MI = WTM/16, NI = WTN/16;
  constexpr int SLOTS = BK/8;
  static_assert((BM/WTM)*(BN/WTN) == 8, "8 waves");
  static_assert((BM*SLOTS)%512==0 && (BN*SLOTS)%512==0, "stage coverage");
  __shared__ unsigned short smem[2*(BM+BN)*BK];

  int nwg = gridDim.x*gridDim.y*gridDim.z;
  int wg = xcd_swz(blockIdx.x + gridDim.x*(blockIdx.y + gridDim.y*blockIdx.z), nwg);
  int bx = wg % gridDim.x; int t1 = wg / gridDim.x;
  int by = t1 % gridDim.y; int z  = t1 / gridDim.y;

  int slot = z / HZ;
  int h = z - slot*HZ;
  int e = eidx ? eidx[slot] : 0;
  const unsigned short* Ap = A + (long)(slot/aDiv)*aSlot + (long)h*aHead;
  const unsigned short* Wp = W + (long)slot*wSlot + (long)h*wHead + (long)e*wExp;
  const float* bp = bias ? (bias + (long)e*biasExp) : nullptr;

  int tid  = threadIdx.x;
  int wave = tid>>6, lane = tid&63;
  int wm = wave / WAVES_N, wn = wave % WAVES_N;
  int bm0 = by*BM;
  int bn0 = bx*BN;
  int lr = lane&15;
  int lg = lane>>4;
  int swz = (BK==64) ? (lr&7) : ((lr>>1)&3);

  Ap += (long)bm0*lda;
  Wp += (long)bn0*ldw;

  f32x4 acc[MI][NI];
  #pragma unroll
  for (int i=0;i<MI;i++)
  #pragma unroll
  for (int j=0;j<NI;j++) acc[i][j] = (f32x4){0.f,0.f,0.f,0.f};

  auto stage = [&](int buf, int k0){
    unsigned short* as = &smem[(size_t)buf*(BM+BN)*BK];
    unsigned short* bs = as + BM*BK;
    #pragma unroll
    for (int i=0;i<BM*SLOTS/512;i++){
      int cch = i*512 + tid;
      int row = cch / SLOTS, c = cch % SLOTS;
      int cs = (BK==64) ? (c ^ (row&7)) : (c ^ ((row>>1)&3));
      gload16(Ap + (long)row*lda + k0 + (cs<<3), as + cch*8);
    }
    #pragma unroll
    for (int i=0;i<BN*SLOTS/512;i++){
      int cch = i*512 + tid;
      int row = cch / SLOTS, c = cch % SLOTS;
      int cs = (BK==64) ? (c ^ (row&7)) : (c ^ ((row>>1)&3));
      gload16(Wp + (long)row*ldw + k0 + (cs<<3), bs + cch*8);
    }
  };

  auto compute = [&](int buf){
    unsigned short* as = &smem[(size_t)buf*(BM+BN)*BK];
    unsigned short* bs = as + BM*BK;
    #pragma unroll
    for (int ki=0;ki<BK/32;ki++){
      bf16x8 af[MI], bfr[NI];
      #pragma unroll
      for (int mi=0;mi<MI;mi++){
        int row = wm*WTM + mi*16 + lr;
        af[mi] = *(const bf16x8*)&as[row*BK + (((ki*4+lg) ^ swz)<<3)];
      }
      #pragma unroll
      for (int ni=0;ni<NI;ni++){
        int row = wn*WTN + ni*16 + lr;
        bfr[ni] = *(const bf16x8*)&bs[row*BK + (((ki*4+lg) ^ swz)<<3)];
      }
      __builtin_amdgcn_s_setprio(1);
      #pragma unroll
      for (int mi=0;mi<MI;mi++)
      #pragma unroll
      for (int ni=0;ni<NI;ni++)
        acc[mi][ni] = __builtin_amdgcn_mfma_f32_16x16x32_bf16(af[mi], bfr[ni], acc[mi][ni], 0,0,0);
      __builtin_amdgcn_s_setprio(0);
    }
  };

  int NT = K / BK;
  stage(0, 0);
  __syncthreads();
  int cur = 0;
  for (int t=0; t<NT; ++t){
    if (t+1 < NT) stage(cur^1, (t+1)*BK);
    compute(cur);
    __syncthreads();
    cur ^= 1;
  }

  long cbase = (long)slot*cSlot + (long)h*cHead;
  int rbase = lg*4;
  #pragma unroll
  for (int mi=0;mi<MI;mi++)
  #pragma unroll
  for (int ni=0;ni<NI;ni++){
    f32x4 v = acc[mi][ni];
    int n = bn0 + wn*WTN + ni*16 + lr;
    float bv = bp ? bp[n] : 0.f;
    float scv = (n < scaleNlim) ? scaleVal : 1.f;
    #pragma unroll
    for (int r=0;r<4;r++){
      int m = bm0 + wm*WTM + mi*16 + rbase + r;
      float val = (v[r] + bv) * scv;
      if (relu) val = fmaxf(val, 0.f);
      long o = cbase + (long)m*ldc + n;
      if (f32out) ((float*)Cp)[o] = val;
      else ((unsigned short*)Cp)[o] = f2bf(val);
    }
  }
}

// ---------------- residual add + LayerNorm (proj is bf16) ----------------
__global__ void __launch_bounds__(256) add_ln_k(
    const float* __restrict__ Ab, int aDiv, long aStride,
    const unsigned short* __restrict__ Bb, long bStride,
    const float* __restrict__ G, const float* __restrict__ Bt,
    const int* __restrict__ eidx,
    float* __restrict__ OutF, unsigned short* __restrict__ OutB)
{
  int row = blockIdx.x*4 + (threadIdx.x>>6);
  int slot = row>>8, t = row&255;
  int lane = threadIdx.x&63;
  const float* a = Ab + (long)(slot/aDiv)*aStride + (long)t*D_;
  const unsigned short* b = Bb + (long)slot*bStride + (long)t*D_;
  int e = eidx[slot];
  const float* g  = G  + (long)e*D_;
  const float* bt = Bt + (long)e*D_;
  float x[8]; float s=0.f;
  #pragma unroll
  for (int i=0;i<8;i++){ x[i] = a[lane+i*64]+bf2f(b[lane+i*64]); s+=x[i]; }
  #pragma unroll
  for (int o=32;o;o>>=1) s += __shfl_xor(s,o);
  float m = s*(1.f/D_);
  float q=0.f;
  #pragma unroll
  for (int i=0;i<8;i++){ float d=x[i]-m; q+=d*d; }
  #pragma unroll
  for (int o=32;o;o>>=1) q += __shfl_xor(q,o);
  float rs = rsqrtf(q*(1.f/D_)+1e-5f);
  long ob = (long)slot*(T_*D_) + (long)t*D_;
  #pragma unroll
  for (int i=0;i<8;i++){
    int d = lane+i*64;
    float y = (x[i]-m)*rs*g[d]+bt[d];
    OutF[ob+d]=y;
    if (OutB) OutB[ob+d]=f2bf(y);
  }
}

// ---------------- residual add + LayerNorm (n3) + weighted slot combine (proj bf16) ----------------
__global__ void __launch_bounds__(256) add_ln_comb_k(
    const float* __restrict__ x2, const unsigned short* __restrict__ proj,
    const float* __restrict__ G, const float* __restrict__ Bt,
    const int* __restrict__ eidx, const float* __restrict__ wgt,
    float* __restrict__ dstF, unsigned short* __restrict__ dstB)
{
  int row = blockIdx.x*4 + (threadIdx.x>>6);   // b*256+t
  int b = row>>8, t = row&255;
  int lane = threadIdx.x&63;
  float out[8];
  #pragma unroll
  for (int i=0;i<8;i++) out[i]=0.f;
  #pragma unroll
  for (int s2i=0;s2i<2;s2i++){
    int slot = 2*b + s2i;
    int e = eidx[slot];
    float w = wgt[slot];
    const float* a = x2 + (long)slot*(T_*D_) + (long)t*D_;
    const unsigned short* p = proj + (long)slot*(T_*D_) + (long)t*D_;
    const float* g  = G  + (long)e*D_;
    const float* bt = Bt + (long)e*D_;
    float x[8]; float s=0.f;
    #pragma unroll
    for (int i=0;i<8;i++){ x[i] = a[lane+i*64]+bf2f(p[lane+i*64]); s+=x[i]; }
    #pragma unroll
    for (int o=32;o;o>>=1) s += __shfl_xor(s,o);
    float m = s*(1.f/D_);
    float q=0.f;
    #pragma unroll
    for (int i=0;i<8;i++){ float d=x[i]-m; q+=d*d; }
    #pragma unroll
    for (int o=32;o;o>>=1) q += __shfl_xor(q,o);
    float rs = rsqrtf(q*(1.f/D_)+1e-5f);
    #pragma unroll
    for (int i=0;i<8;i++){
      int d = lane+i*64;
      out[i] += w*((x[i]-m)*rs*g[d]+bt[d]);
    }
  }
  long ob = (long)row*D_;
  #pragma unroll
  for (int i=0;i<8;i++){
    int d = lane+i*64;
    dstF[ob+d] = out[i];
    dstB[ob+d] = f2bf(out[i]);
  }
}

extern "C" void kernel_launch(void* const* d_in, const int* in_sizes, int n_in,
                              void* d_out, int out_size, void* d_ws, size_t ws_size,
                              hipStream_t stream)
{
  const float* tgt      = (const float*)d_in[0];
  const float* memory   = (const float*)d_in[1];
  const float* router_w = (const float*)d_in[2];
  const float* sa_in_w  = (const float*)d_in[3];
  const float* sa_in_b  = (const float*)d_in[4];
  const float* sa_out_w = (const float*)d_in[5];
  const float* sa_out_b = (const float*)d_in[6];
  const float* ca_in_w  = (const float*)d_in[7];
  const float* ca_in_b  = (const float*)d_in[8];
  const float* ca_out_w = (const float*)d_in[9];
  const float* ca_out_b = (const float*)d_in[10];
  const float* lin1_w   = (const float*)d_in[11];
  const float* lin1_b   = (const float*)d_in[12];
  const float* lin2_w   = (const float*)d_in[13];
  const float* lin2_b   = (const float*)d_in[14];
  const float* n1_g = (const float*)d_in[15];
  const float* n1_b = (const float*)d_in[16];
  const float* n2_g = (const float*)d_in[17];
  const float* n2_b = (const float*)d_in[18];
  const float* n3_g = (const float*)d_in[19];
  const float* n3_b = (const float*)d_in[20];

  char* ws = (char*)d_ws;
  size_t off = 0;
  auto alloc = [&](size_t bytes)->char*{
    char* p = ws + off; off += (bytes + 255) & ~(size_t)255; return p;
  };
  unsigned short* xb    = (unsigned short*)alloc(2ull*B_*T_*D_);
  unsigned short* memb  = (unsigned short*)alloc(2ull*B_*S_*D_);
  float*          x     = (float*)alloc(4ull*B_*T_*D_);
  int*            eidx  = (int*)alloc(4ull*NSLOT);
  float*          wgt   = (float*)alloc(4ull*NSLOT);
  unsigned short* wSaIn  = (unsigned short*)alloc(2ull*E_*3*D_*D_);
  unsigned short* wSaOut = (unsigned short*)alloc(2ull*E_*D_*D_);
  unsigned short* wCaIn  = (unsigned short*)alloc(2ull*E_*3*D_*D_);
  unsigned short* wCaOut = (unsigned short*)alloc(2ull*E_*D_*D_);
  unsigned short* wL1    = (unsigned short*)alloc(2ull*E_*DFF_*D_);
  unsigned short* wL2    = (unsigned short*)alloc(2ull*E_*D_*DFF_);
  unsigned short* qkv   = (unsigned short*)alloc(2ull*NSLOT*T_*3*D_);
  unsigned short* ffh   = (unsigned short*)alloc(2ull*NSLOT*T_*DFF_);
  unsigned short* attn  = (unsigned short*)alloc(2ull*NSLOT*T_*D_);
  unsigned short* proj  = (unsigned short*)alloc(2ull*NSLOT*T_*D_);
  float*          x1    = (float*)alloc(4ull*NSLOT*T_*D_);
  unsigned short* x1b   = (unsigned short*)alloc(2ull*NSLOT*T_*D_);
  unsigned short* cq    = (unsigned short*)alloc(2ull*NSLOT*T_*D_);
  unsigned short* mkv   = (unsigned short*)alloc(2ull*NSLOT*S_*2*D_);
  float*          x2    = (float*)alloc(4ull*NSLOT*T_*D_);
  unsigned short* x2b   = (unsigned short*)alloc(2ull*NSLOT*T_*D_);
  unsigned short* Vt1   = cq;   // alias: [slot][h][64][T]; cq written after fattn-self consumed Vt1
  unsigned short* Vt2   = qkv;  // alias: [slot][h][64][S]; qkv dead after fattn-self

  cast_bf16_k<<<1024,256,0,stream>>>(tgt,    xb,   (long)B_*T_*D_);
  cast_bf16_k<<<1024,256,0,stream>>>(memory, memb, (long)B_*S_*D_);

  const float* xcur = tgt;
  for (int l=0; l<L_; ++l){
    route_k<<<B_,256,0,stream>>>(xcur, router_w + (size_t)l*E_*D_, eidx, wgt);
    cast_weights_k<<<2048,256,0,stream>>>(
      sa_in_w  + (size_t)l*E_*3*D_*D_, sa_out_w + (size_t)l*E_*D_*D_,
      ca_in_w  + (size_t)l*E_*3*D_*D_, ca_out_w + (size_t)l*E_*D_*D_,
      lin1_w   + (size_t)l*E_*DFF_*D_, lin2_w   + (size_t)l*E_*D_*DFF_,
      wSaIn, wSaOut, wCaIn, wCaOut, wL1, wL2);

    // QKV = x @ sa_in^T + b  (Q cols scaled by 1/8)
    gemm_lds<128,256,64,64,32><<<dim3(6,2,NSLOT),512,0,stream>>>(
      xb, (long)T_*D_, 2, 0, D_,
      wSaIn, 0, 0, (long)3*D_*D_, D_,
      eidx, sa_in_b + (size_t)l*E_*3*D_, 3*D_,
      qkv, (long)T_*3*D_, 0, 3*D_,
      512, 1, 0, 0, D_, 0.125f);
    // Vt1 = transpose of self V
    vtrans_k<<<dim3(T_/64,H_,NSLOT),256,0,stream>>>(
      qkv + 2*D_, (long)T_*3*D_, 3*D_, Vt1, T_);
    // fused self-attention
    fattn_k<4><<<dim3(T_/64, NSLOT*H_),256,0,stream>>>(
      qkv, (long)T_*3*D_, 3*D_,
      qkv + D_, (long)T_*3*D_, 3*D_,
      Vt1, attn, (long)T_*D_, D_);
    // self-attn out proj (bf16 out)
    gemm_lds<128,128,64,32,64><<<dim3(4,2,NSLOT),512,0,stream>>>(
      attn, (long)T_*D_, 1, 0, D_,
      wSaOut, 0, 0, (long)D_*D_, D_,
      eidx, sa_out_b + (size_t)l*E_*D_, D_,
      proj, (long)T_*D_, 0, D_,
      512, 1, 0, 0, 0, 1.f);
    add_ln_k<<<2048,256,0,stream>>>(xcur, 2, (long)T_*D_, proj, (long)T_*D_,
      n1_g + (size_t)l*E_*D_, n1_b + (size_t)l*E_*D_, eidx, x1, x1b);
    // cross-attn Q (scaled)
    gemm_lds<128,128,64,32,64><<<dim3(4,2,NSLOT),512,0,stream>>>(
      x1b, (long)T_*D_, 1, 0, D_,
      wCaIn, 0, 0, (long)3*D_*D_, D_,
      eidx, ca_in_b + (size_t)l*E_*3*D_, 3*D_,
      cq, (long)T_*D_, 0, D_,
      512, 1, 0, 0, D_, 0.125f);
    // cross-attn K,V from memory
    gemm_lds<128,256,64,64,32><<<dim3(4,4,NSLOT),512,0,stream>>>(
      memb, (long)S_*D_, 2, 0, D_,
      wCaIn + (size_t)D_*D_, 0, 0, (long)3*D_*D_, D_,
      eidx, ca_in_b + (size_t)l*E_*3*D_ + D_, 3*D_,
      mkv, (long)S_*2*D_, 0, 2*D_,
      512, 1, 0, 0, 0, 1.f);
    // Vt2 = transpose of cross V
    vtrans_k<<<dim3(S_/64,H_,NSLOT),256,0,stream>>>(
      mkv + D_, (long)S_*2*D_, 2*D_, Vt2, S_);
    // fused cross-attention
    fattn_k<8><<<dim3(T_/64, NSLOT*H_),256,0,stream>>>(
      cq, (long)T_*D_, D_,
      mkv, (long)S_*2*D_, 2*D_,
      Vt2, attn, (long)T_*D_, D_);
    // cross-attn out proj (bf16 out)
    gemm_lds<128,128,64,32,64><<<dim3(4,2,NSLOT),512,0,stream>>>(
      attn, (long)T_*D_, 1, 0, D_,
      wCaOut, 0, 0, (long)D_*D_, D_,
      eidx, ca_out_b + (size_t)l*E_*D_, D_,
      proj, (long)T_*D_, 0, D_,
      512, 1, 0, 0, 0, 1.f);
    add_ln_k<<<2048,256,0,stream>>>(x1, 1, (long)T_*D_, proj, (long)T_*D_,
      n2_g + (size_t)l*E_*D_, n2_b + (size_t)l*E_*D_, eidx, x2, x2b);
    // FFN1 (+relu)
    gemm_lds<128,256,64,64,32><<<dim3(8,2,NSLOT),512,0,stream>>>(
      x2b, (long)T_*D_, 1, 0, D_,
      wL1, 0, 0, (long)DFF_*D_, D_,
      eidx, lin1_b + (size_t)l*E_*DFF_, DFF_,
      ffh, (long)T_*DFF_, 0, DFF_,
      512, 1, 0, 1, 0, 1.f);
    // FFN2 (bf16 out)
    gemm_lds<128,128,64,32,64><<<dim3(4,2,NSLOT),512,0,stream>>>(
      ffh, (long)T_*DFF_, 1, 0, DFF_,
      wL2, 0, 0, (long)D_*DFF_, DFF_,
      eidx, lin2_b + (size_t)l*E_*D_, D_,
      proj, (long)T_*D_, 0, D_,
      2048, 1, 0, 0, 0, 1.f);
    // n3 LN + weighted combine
    float* dstF = (l==L_-1) ? (float*)d_out : x;
    add_ln_comb_k<<<1024,256,0,stream>>>(x2, proj,
      n3_g + (size_t)l*E_*D_, n3_b + (size_t)l*E_*D_, eidx, wgt, dstF, xb);
    xcur = x;
  }
}

// Round 12
// 986.177 us; speedup vs baseline: 1.1509x; 1.0959x over previous
//
#include <hip/hip_runtime.h>
#include <hip/hip_bf16.h>

#define L_ 4
#define E_ 4
#define D_ 512
#define DFF_ 2048
#define H_ 8
#define B_ 16
#define T_ 256
#define S_ 512
#define HD_ 64
#define NSLOT 32   // B * K

typedef __attribute__((ext_vector_type(4))) float f32x4;
typedef __attribute__((ext_vector_type(8))) short bf16x8;
typedef __attribute__((ext_vector_type(4))) int i32x4;

static __device__ __forceinline__ float bf2f(unsigned short u){
  union{float f; unsigned u;} c; c.u = ((unsigned)u)<<16; return c.f;
}
static __device__ __forceinline__ unsigned short f2bf(float f){
  union{float f; unsigned u;} c; c.f=f;
  unsigned u=c.u;
  return (unsigned short)((u + 0x7FFFu + ((u>>16)&1u))>>16);
}

static __device__ __forceinline__ void gload16(const unsigned short* g, unsigned short* l){
  __builtin_amdgcn_global_load_lds(
      (const __attribute__((address_space(1))) void*)g,
      (__attribute__((address_space(3))) void*)l, 16, 0, 0);
}

// bijective XCD-chunked block remap (m204)
static __device__ __forceinline__ int xcd_swz(int orig, int nwg){
  int q = nwg >> 3, r = nwg & 7;
  int xcd = orig & 7, idx = orig >> 3;
  return (xcd < r) ? (xcd*(q+1) + idx) : (r*(q+1) + (xcd-r)*q + idx);
}

// ---------------- routing: stage 1 — chunked pooled partial sums (deterministic) ----------------
__global__ void __launch_bounds__(256) pool_k(const float* __restrict__ x,
    float* __restrict__ part)
{
  int b = blockIdx.x >> 3, ch = blockIdx.x & 7;
  int tid = threadIdx.x;
  const float* xp = x + ((long)b*T_ + ch*32)*D_ + tid*2;
  float s0=0.f, s1=0.f;
  #pragma unroll 8
  for (int t=0;t<32;t++){
    float2 v = *(const float2*)(xp + (long)t*D_);
    s0 += v.x; s1 += v.y;
  }
  float* pp = part + ((long)b*8 + ch)*D_ + tid*2;
  pp[0]=s0; pp[1]=s1;
}

// ---------------- routing: stage 2 — combine partials, logits, top-2 ----------------
__global__ void __launch_bounds__(256) route2_k(const float* __restrict__ part,
    const float* __restrict__ rw, int* __restrict__ eidx, float* __restrict__ wgt)
{
  __shared__ float pooled[D_];
  __shared__ float logit[E_];
  int b = blockIdx.x, tid = threadIdx.x;
  for (int d = tid; d < D_; d += 256){
    float s = 0.f;
    #pragma unroll
    for (int c=0;c<8;c++) s += part[((long)b*8 + c)*D_ + d];
    pooled[d] = s * (1.f/T_);
  }
  __syncthreads();
  int wave = tid>>6, lane = tid&63;
  {
    float s=0.f;
    const float* w = rw + (long)wave*D_;
    for (int d=lane; d<D_; d+=64) s += pooled[d]*w[d];
    #pragma unroll
    for (int o=32;o;o>>=1) s += __shfl_xor(s,o);
    if (lane==0) logit[wave] = s;
  }
  __syncthreads();
  if (tid==0){
    int i1=0; float v1=logit[0];
    for (int e=1;e<E_;e++) if (logit[e] > v1){ v1=logit[e]; i1=e; }
    int i2=-1; float v2=-3.4e38f;
    for (int e=0;e<E_;e++) if (e!=i1 && logit[e] > v2){ v2=logit[e]; i2=e; }
    float e2 = __expf(v2 - v1);
    float w1 = 1.f/(1.f+e2);
    eidx[2*b]=i1; eidx[2*b+1]=i2;
    wgt[2*b]=w1; wgt[2*b+1]=e2*w1;
  }
}

// ---------------- casts ----------------
__global__ void __launch_bounds__(256) cast_bf16_k(const float* __restrict__ in,
    unsigned short* __restrict__ out, long n){
  long i = ((long)blockIdx.x*blockDim.x + threadIdx.x)*4;
  long st = (long)gridDim.x*blockDim.x*4;
  for (; i<n; i+=st){
    float4 v = *(const float4*)(in+i);
    ushort4 o; o.x=f2bf(v.x); o.y=f2bf(v.y); o.z=f2bf(v.z); o.w=f2bf(v.w);
    *(ushort4*)(out+i) = o;
  }
}

// fused per-layer weight cast (6 segments)
__global__ void __launch_bounds__(256) cast_weights_k(
    const float* __restrict__ s0, const float* __restrict__ s1,
    const float* __restrict__ s2, const float* __restrict__ s3,
    const float* __restrict__ s4, const float* __restrict__ s5,
    unsigned short* __restrict__ d0, unsigned short* __restrict__ d1,
    unsigned short* __restrict__ d2, unsigned short* __restrict__ d3,
    unsigned short* __restrict__ d4, unsigned short* __restrict__ d5)
{
  const long N0=(long)E_*3*D_*D_, N1=(long)E_*D_*D_;
  const long N2=N0, N3=N1, N4=(long)E_*DFF_*D_, N5=N4;
  const long total = N0+N1+N2+N3+N4+N5;
  long i = ((long)blockIdx.x*256 + threadIdx.x)*4;
  long st = (long)gridDim.x*256*4;
  for (; i<total; i+=st){
    const float* s; unsigned short* d; long j = i;
    if (j < N0){ s=s0; d=d0; }
    else if ((j-=N0) < N1){ s=s1; d=d1; }
    else if ((j-=N1) < N2){ s=s2; d=d2; }
    else if ((j-=N2) < N3){ s=s3; d=d3; }
    else if ((j-=N3) < N4){ s=s4; d=d4; }
    else { j-=N4; s=s5; d=d5; }
    float4 v = *(const float4*)(s+j);
    ushort4 o; o.x=f2bf(v.x); o.y=f2bf(v.y); o.z=f2bf(v.z); o.w=f2bf(v.w);
    *(ushort4*)(d+j) = o;
  }
}

// ---------------- V transpose ----------------
__global__ void __launch_bounds__(256) vtrans_k(const unsigned short* __restrict__ src,
    long sSlot, int ld, unsigned short* __restrict__ dst, int rows)
{
  __shared__ unsigned short t[64][68];
  int s0 = blockIdx.x*64; int h = blockIdx.y; int slot = blockIdx.z;
  const unsigned short* sp = src + (long)slot*sSlot + (long)h*64;
  int c = threadIdx.x&63, w = threadIdx.x>>6;
  #pragma unroll
  for (int i=0;i<16;i++){
    int r = i*4 + w;
    t[r][c] = sp[(long)(s0+r)*ld + c];
  }
  __syncthreads();
  unsigned short* dp = dst + ((long)slot*H_ + h)*((long)64*rows) + s0;
  #pragma unroll
  for (int i=0;i<16;i++){
    int d = i*4 + w;
    dp[(long)d*rows + c] = t[c][d];
  }
}

// ---------------- fused flash attention ----------------
template<int NT>
__global__ void __launch_bounds__(256) fattn_k(
    const unsigned short* __restrict__ Qg, long qSlot, int ldq,
    const unsigned short* __restrict__ Kg, long kSlot, int ldk,
    const unsigned short* __restrict__ Vtg,
    unsigned short* __restrict__ Og, long oSlot, int ldo)
{
  constexpr int SLEN = NT*64;
  __shared__ unsigned short K_lds[64][72];
  __shared__ unsigned short V_lds[64][72];
  __shared__ unsigned short P_lds[4][16][72];

  int nwg = gridDim.x*gridDim.y;
  int wg = xcd_swz(blockIdx.x + gridDim.x*blockIdx.y, nwg);
  int qb = wg % gridDim.x;
  int z  = wg / gridDim.x;        // slot*H + h
  int slot = z >> 3, h = z & 7;
  int tid = threadIdx.x, wave = tid>>6, lane = tid&63;
  int lr = lane&15, lg = lane>>4;
  int lk = lg*8;

  const unsigned short* Qp = Qg + (long)slot*qSlot + (long)h*HD_;
  const unsigned short* Kp = Kg + (long)slot*kSlot + (long)h*HD_;
  const unsigned short* Vp = Vtg + (long)z*((long)HD_*SLEN);

  bf16x8 qf[2];
  {
    int qrow = qb*64 + wave*16 + lr;
    const unsigned short* qr = Qp + (long)qrow*ldq;
    qf[0] = *(const bf16x8*)(qr + lk);
    qf[1] = *(const bf16x8*)(qr + 32 + lk);
  }

  float m_prev[4], l_run[4];
  f32x4 acc_o[4];
  #pragma unroll
  for (int r=0;r<4;r++){ m_prev[r]=-1e30f; l_run[r]=0.f; }
  #pragma unroll
  for (int ni=0;ni<4;ni++) acc_o[ni]=(f32x4){0.f,0.f,0.f,0.f};

  int srow = tid>>3, sch = tid&7;

  i32x4 kr0 = *(const i32x4*)(Kp + (long)srow*ldk + sch*8);
  i32x4 kr1 = *(const i32x4*)(Kp + (long)(srow+32)*ldk + sch*8);
  i32x4 vr0 = *(const i32x4*)(Vp + (long)srow*SLEN + sch*8);
  i32x4 vr1 = *(const i32x4*)(Vp + (long)(srow+32)*SLEN + sch*8);

  for (int t=0; t<NT; ++t){
    __syncthreads();
    *(i32x4*)&K_lds[srow][sch*8] = kr0;
    *(i32x4*)&K_lds[srow+32][sch*8] = kr1;
    *(i32x4*)&V_lds[srow][sch*8] = vr0;
    *(i32x4*)&V_lds[srow+32][sch*8] = vr1;
    __syncthreads();

    int tn = (t+1 < NT) ? t+1 : t;
    int k0n = tn*64;
    kr0 = *(const i32x4*)(Kp + (long)(k0n+srow)*ldk + sch*8);
    kr1 = *(const i32x4*)(Kp + (long)(k0n+srow+32)*ldk + sch*8);
    vr0 = *(const i32x4*)(Vp + (long)srow*SLEN + k0n + sch*8);
    vr1 = *(const i32x4*)(Vp + (long)(srow+32)*SLEN + k0n + sch*8);

    // S = Q @ K^T
    f32x4 s[4];
    #pragma unroll
    for (int ni=0;ni<4;ni++) s[ni]=(f32x4){0.f,0.f,0.f,0.f};
    __builtin_amdgcn_s_setprio(1);
    #pragma unroll
    for (int ki=0;ki<2;ki++){
      #pragma unroll
      for (int ni=0;ni<4;ni++){
        bf16x8 kf = *(const bf16x8*)&K_lds[ni*16+lr][ki*32+lk];
        s[ni] = __builtin_amdgcn_mfma_f32_16x16x32_bf16(qf[ki], kf, s[ni],0,0,0);
      }
    }
    __builtin_amdgcn_s_setprio(0);
    // online softmax with rescale-skip (exact: corr==1 when max unchanged)
    float tmax[4];
    #pragma unroll
    for (int r=0;r<4;r++){
      tmax[r] = fmaxf(fmaxf(s[0][r],s[1][r]),fmaxf(s[2][r],s[3][r]));
      #pragma unroll
      for (int msk=1; msk<16; msk<<=1) tmax[r]=fmaxf(tmax[r], __shfl_xor(tmax[r],msk));
    }
    bool inc = (tmax[0]>m_prev[0])|(tmax[1]>m_prev[1])|(tmax[2]>m_prev[2])|(tmax[3]>m_prev[3]);
    if (__any(inc)){
      #pragma unroll
      for (int r=0;r<4;r++){
        float mnew = fmaxf(m_prev[r], tmax[r]);
        float corr = __expf(m_prev[r]-mnew);
        m_prev[r] = mnew;
        l_run[r] *= corr;
        #pragma unroll
        for (int ni=0;ni<4;ni++) acc_o[ni][r] *= corr;
      }
    }
    float rs[4] = {0.f,0.f,0.f,0.f};
    #pragma unroll
    for (int ni=0;ni<4;ni++){
      #pragma unroll
      for (int r=0;r<4;r++){
        float p = __expf(s[ni][r]-m_prev[r]);
        rs[r] += p;
        P_lds[wave][lg*4+r][ni*16+lr] = f2bf(p);
      }
    }
    #pragma unroll
    for (int r=0;r<4;r++){
      #pragma unroll
      for (int msk=1; msk<16; msk<<=1) rs[r] += __shfl_xor(rs[r],msk);
      l_run[r] += rs[r];
    }
    // O += P @ V
    __builtin_amdgcn_s_setprio(1);
    #pragma unroll
    for (int ki=0;ki<2;ki++){
      bf16x8 pf = *(const bf16x8*)&P_lds[wave][lr][ki*32+lk];
      #pragma unroll
      for (int ni=0;ni<4;ni++){
        bf16x8 vf = *(const bf16x8*)&V_lds[ni*16+lr][ki*32+lk];
        acc_o[ni] = __builtin_amdgcn_mfma_f32_16x16x32_bf16(pf, vf, acc_o[ni],0,0,0);
      }
    }
    __builtin_amdgcn_s_setprio(0);
  }
  unsigned short* Op = Og + (long)slot*oSlot + (long)h*HD_;
  #pragma unroll
  for (int r=0;r<4;r++){
    float inv = 1.f/l_run[r];
    int q = qb*64 + wave*16 + lg*4 + r;
    #pragma unroll
    for (int ni=0;ni<4;ni++)
      Op[(long)q*ldo + ni*16 + lr] = f2bf(acc_o[ni][r]*inv);
  }
}

// ---------------- LDS-staged GEMM  C = A @ W^T (+bias)(*scale)(relu) ----------------
// dbuf LDS, chunk-XOR swizzle, 8 waves, XCD remap.
//   <128,128,64,32,64> : small GEMMs
//   <128,256,64,64,32> : big GEMMs
template<int BM, int BN, int WTM, int WTN, int BK>
__global__ void __launch_bounds__(512) gemm_lds(
    const unsigned short* __restrict__ A, long aSlot, int aDiv, long aHead, int lda,
    const unsigned short* __restrict__ W, long wSlot, long wHead, long wExp, int ldw,
    const int* __restrict__ eidx, const float* __restrict__ bias, long biasExp,
    void* __restrict__ Cp, long cSlot, long cHead, int ldc,
    int K, int HZ, int f32out, int relu, int scaleNlim, float scaleVal)
{
  constexpr int WAVES_N = BN/WTN;
  constexpr int MI = WTM/16, NI = WTN/16;
  constexpr int SLOTS = BK/8;
  static_assert((BM/WTM)*(BN/WTN) == 8, "8 waves");
  static_assert((BM*SLOTS)%512==0 && (BN*SLOTS)%512==0, "stage coverage");
  __shared__ unsigned short smem[2*(BM+BN)*BK];

  int nwg = gridDim.x*gridDim.y*gridDim.z;
  int wg = xcd_swz(blockIdx.x + gridDim.x*(blockIdx.y + gridDim.y*blockIdx.z), nwg);
  int bx = wg % gridDim.x; int t1 = wg / gridDim.x;
  int by = t1 % gridDim.y; int z  = t1 / gridDim.y;

  int slot = z / HZ;
  int h = z - slot*HZ;
  int e = eidx ? eidx[slot] : 0;
  const unsigned short* Ap = A + (long)(slot/aDiv)*aSlot + (long)h*aHead;
  const unsigned short* Wp = W + (long)slot*wSlot + (long)h*wHead + (long)e*wExp;
  const float* bp = bias ? (bias + (long)e*biasExp) : nullptr;

  int tid  = threadIdx.x;
  int wave = tid>>6, lane = tid&63;
  int wm = wave / WAVES_N, wn = wave % WAVES_N;
  int bm0 = by*BM;
  int bn0 = bx*BN;
  int lr = lane&15;
  int lg = lane>>4;
  int swz = (BK==64) ? (lr&7) : ((lr>>1)&3);

  Ap += (long)bm0*lda;
  Wp += (long)bn0*ldw;

  f32x4 acc[MI][NI];
  #pragma unroll
  for (int i=0;i<MI;i++)
  #pragma unroll
  for (int j=0;j<NI;j++) acc[i][j] = (f32x4){0.f,0.f,0.f,0.f};

  auto stage = [&](int buf, int k0){
    unsigned short* as = &smem[(size_t)buf*(BM+BN)*BK];
    unsigned short* bs = as + BM*BK;
    #pragma unroll
    for (int i=0;i<BM*SLOTS/512;i++){
      int cch = i*512 + tid;
      int row = cch / SLOTS, c = cch % SLOTS;
      int cs = (BK==64) ? (c ^ (row&7)) : (c ^ ((row>>1)&3));
      gload16(Ap + (long)row*lda + k0 + (cs<<3), as + cch*8);
    }
    #pragma unroll
    for (int i=0;i<BN*SLOTS/512;i++){
      int cch = i*512 + tid;
      int row = cch / SLOTS, c = cch % SLOTS;
      int cs = (BK==64) ? (c ^ (row&7)) : (c ^ ((row>>1)&3));
      gload16(Wp + (long)row*ldw + k0 + (cs<<3), bs + cch*8);
    }
  };

  auto compute = [&](int buf){
    unsigned short* as = &smem[(size_t)buf*(BM+BN)*BK];
    unsigned short* bs = as + BM*BK;
    #pragma unroll
    for (int ki=0;ki<BK/32;ki++){
      bf16x8 af[MI], bfr[NI];
      #pragma unroll
      for (int mi=0;mi<MI;mi++){
        int row = wm*WTM + mi*16 + lr;
        af[mi] = *(const bf16x8*)&as[row*BK + (((ki*4+lg) ^ swz)<<3)];
      }
      #pragma unroll
      for (int ni=0;ni<NI;ni++){
        int row = wn*WTN + ni*16 + lr;
        bfr[ni] = *(const bf16x8*)&bs[row*BK + (((ki*4+lg) ^ swz)<<3)];
      }
      __builtin_amdgcn_s_setprio(1);
      #pragma unroll
      for (int mi=0;mi<MI;mi++)
      #pragma unroll
      for (int ni=0;ni<NI;ni++)
        acc[mi][ni] = __builtin_amdgcn_mfma_f32_16x16x32_bf16(af[mi], bfr[ni], acc[mi][ni], 0,0,0);
      __builtin_amdgcn_s_setprio(0);
    }
  };

  int NT = K / BK;
  stage(0, 0);
  __syncthreads();
  int cur = 0;
  for (int t=0; t<NT; ++t){
    if (t+1 < NT) stage(cur^1, (t+1)*BK);
    compute(cur);
    __syncthreads();
    cur ^= 1;
  }

  long cbase = (long)slot*cSlot + (long)h*cHead;
  int rbase = lg*4;
  #pragma unroll
  for (int mi=0;mi<MI;mi++)
  #pragma unroll
  for (int ni=0;ni<NI;ni++){
    f32x4 v = acc[mi][ni];
    int n = bn0 + wn*WTN + ni*16 + lr;
    float bv = bp ? bp[n] : 0.f;
    float scv = (n < scaleNlim) ? scaleVal : 1.f;
    #pragma unroll
    for (int r=0;r<4;r++){
      int m = bm0 + wm*WTM + mi*16 + rbase + r;
      float val = (v[r] + bv) * scv;
      if (relu) val = fmaxf(val, 0.f);
      long o = cbase + (long)m*ldc + n;
      if (f32out) ((float*)Cp)[o] = val;
      else ((unsigned short*)Cp)[o] = f2bf(val);
    }
  }
}

// ---------------- residual add + LayerNorm (vectorized; A fp32 or bf16; bf16 out) ----------------
template<int ABF>
__global__ void __launch_bounds__(256) add_ln_k(
    const void* __restrict__ Ab_, int aDiv, long aStride,
    const unsigned short* __restrict__ Bb, long bStride,
    const float* __restrict__ G, const float* __restrict__ Bt,
    const int* __restrict__ eidx,
    unsigned short* __restrict__ OutB)
{
  int row = blockIdx.x*4 + (threadIdx.x>>6);
  int slot = row>>8, t = row&255;
  int lane = threadIdx.x&63;
  int d0 = lane*8;
  float x[8];
  if (ABF){
    const unsigned short* a = (const unsigned short*)Ab_ + (long)(slot/aDiv)*aStride + (long)t*D_ + d0;
    ushort4 a0 = *(const ushort4*)a, a1 = *(const ushort4*)(a+4);
    x[0]=bf2f(a0.x); x[1]=bf2f(a0.y); x[2]=bf2f(a0.z); x[3]=bf2f(a0.w);
    x[4]=bf2f(a1.x); x[5]=bf2f(a1.y); x[6]=bf2f(a1.z); x[7]=bf2f(a1.w);
  } else {
    const float* a = (const float*)Ab_ + (long)(slot/aDiv)*aStride + (long)t*D_ + d0;
    float4 a0 = *(const float4*)a, a1 = *(const float4*)(a+4);
    x[0]=a0.x; x[1]=a0.y; x[2]=a0.z; x[3]=a0.w;
    x[4]=a1.x; x[5]=a1.y; x[6]=a1.z; x[7]=a1.w;
  }
  const unsigned short* b = Bb + (long)slot*bStride + (long)t*D_ + d0;
  ushort4 b0 = *(const ushort4*)b, b1 = *(const ushort4*)(b+4);
  x[0]+=bf2f(b0.x); x[1]+=bf2f(b0.y); x[2]+=bf2f(b0.z); x[3]+=bf2f(b0.w);
  x[4]+=bf2f(b1.x); x[5]+=bf2f(b1.y); x[6]+=bf2f(b1.z); x[7]+=bf2f(b1.w);
  float s=0.f;
  #pragma unroll
  for (int i=0;i<8;i++) s += x[i];
  #pragma unroll
  for (int o=32;o;o>>=1) s += __shfl_xor(s,o);
  float m = s*(1.f/D_);
  float q=0.f;
  #pragma unroll
  for (int i=0;i<8;i++){ float d=x[i]-m; q+=d*d; }
  #pragma unroll
  for (int o=32;o;o>>=1) q += __shfl_xor(q,o);
  float rs = rsqrtf(q*(1.f/D_)+1e-5f);
  int e = eidx[slot];
  const float* g  = G  + (long)e*D_ + d0;
  const float* bt = Bt + (long)e*D_ + d0;
  float4 g0 = *(const float4*)g, g1 = *(const float4*)(g+4);
  float4 t0 = *(const float4*)bt, t1 = *(const float4*)(bt+4);
  float gg[8] = {g0.x,g0.y,g0.z,g0.w,g1.x,g1.y,g1.z,g1.w};
  float tt[8] = {t0.x,t0.y,t0.z,t0.w,t1.x,t1.y,t1.z,t1.w};
  long ob = (long)slot*(T_*D_) + (long)t*D_ + d0;
  ushort4 o0, o1;
  float y0=(x[0]-m)*rs*gg[0]+tt[0], y1=(x[1]-m)*rs*gg[1]+tt[1];
  float y2=(x[2]-m)*rs*gg[2]+tt[2], y3=(x[3]-m)*rs*gg[3]+tt[3];
  float y4=(x[4]-m)*rs*gg[4]+tt[4], y5=(x[5]-m)*rs*gg[5]+tt[5];
  float y6=(x[6]-m)*rs*gg[6]+tt[6], y7=(x[7]-m)*rs*gg[7]+tt[7];
  o0.x=f2bf(y0); o0.y=f2bf(y1); o0.z=f2bf(y2); o0.w=f2bf(y3);
  o1.x=f2bf(y4); o1.y=f2bf(y5); o1.z=f2bf(y6); o1.w=f2bf(y7);
  *(ushort4*)(OutB+ob) = o0;
  *(ushort4*)(OutB+ob+4) = o1;
}

// ---------------- residual add + LayerNorm (n3) + weighted slot combine (bf16 in) ----------------
__global__ void __launch_bounds__(256) add_ln_comb_k(
    const unsigned short* __restrict__ x2b, const unsigned short* __restrict__ proj,
    const float* __restrict__ G, const float* __restrict__ Bt,
    const int* __restrict__ eidx, const float* __restrict__ wgt,
    float* __restrict__ dstF, unsigned short* __restrict__ dstB)
{
  int row = blockIdx.x*4 + (threadIdx.x>>6);   // b*256+t
  int b = row>>8, t = row&255;
  int lane = threadIdx.x&63;
  int d0 = lane*8;
  float out[8];
  #pragma unroll
  for (int i=0;i<8;i++) out[i]=0.f;
  #pragma unroll
  for (int s2i=0;s2i<2;s2i++){
    int slot = 2*b + s2i;
    int e = eidx[slot];
    float w = wgt[slot];
    const unsigned short* a = x2b + (long)slot*(T_*D_) + (long)t*D_ + d0;
    const unsigned short* p = proj + (long)slot*(T_*D_) + (long)t*D_ + d0;
    ushort4 a0 = *(const ushort4*)a, a1 = *(const ushort4*)(a+4);
    ushort4 p0 = *(const ushort4*)p, p1 = *(const ushort4*)(p+4);
    float x[8];
    x[0]=bf2f(a0.x)+bf2f(p0.x); x[1]=bf2f(a0.y)+bf2f(p0.y);
    x[2]=bf2f(a0.z)+bf2f(p0.z); x[3]=bf2f(a0.w)+bf2f(p0.w);
    x[4]=bf2f(a1.x)+bf2f(p1.x); x[5]=bf2f(a1.y)+bf2f(p1.y);
    x[6]=bf2f(a1.z)+bf2f(p1.z); x[7]=bf2f(a1.w)+bf2f(p1.w);
    float s=0.f;
    #pragma unroll
    for (int i=0;i<8;i++) s += x[i];
    #pragma unroll
    for (int o=32;o;o>>=1) s += __shfl_xor(s,o);
    float m = s*(1.f/D_);
    float q=0.f;
    #pragma unroll
    for (int i=0;i<8;i++){ float d=x[i]-m; q+=d*d; }
    #pragma unroll
    for (int o=32;o;o>>=1) q += __shfl_xor(q,o);
    float rs = rsqrtf(q*(1.f/D_)+1e-5f);
    const float* g  = G  + (long)e*D_ + d0;
    const float* bt = Bt + (long)e*D_ + d0;
    float4 g0 = *(const float4*)g, g1 = *(const float4*)(g+4);
    float4 t0 = *(const float4*)bt, t1 = *(const float4*)(bt+4);
    float gg[8] = {g0.x,g0.y,g0.z,g0.w,g1.x,g1.y,g1.z,g1.w};
    float tt[8] = {t0.x,t0.y,t0.z,t0.w,t1.x,t1.y,t1.z,t1.w};
    #pragma unroll
    for (int i=0;i<8;i++) out[i] += w*((x[i]-m)*rs*gg[i]+tt[i]);
  }
  long ob = (long)row*D_ + d0;
  float4 f0 = {out[0],out[1],out[2],out[3]};
  float4 f1 = {out[4],out[5],out[6],out[7]};
  *(float4*)(dstF+ob) = f0;
  *(float4*)(dstF+ob+4) = f1;
  ushort4 o0, o1;
  o0.x=f2bf(out[0]); o0.y=f2bf(out[1]); o0.z=f2bf(out[2]); o0.w=f2bf(out[3]);
  o1.x=f2bf(out[4]); o1.y=f2bf(out[5]); o1.z=f2bf(out[6]); o1.w=f2bf(out[7]);
  *(ushort4*)(dstB+ob) = o0;
  *(ushort4*)(dstB+ob+4) = o1;
}

extern "C" void kernel_launch(void* const* d_in, const int* in_sizes, int n_in,
                              void* d_out, int out_size, void* d_ws, size_t ws_size,
                              hipStream_t stream)
{
  const float* tgt      = (const float*)d_in[0];
  const float* memory   = (const float*)d_in[1];
  const float* router_w = (const float*)d_in[2];
  const float* sa_in_w  = (const float*)d_in[3];
  const float* sa_in_b  = (const float*)d_in[4];
  const float* sa_out_w = (const float*)d_in[5];
  const float* sa_out_b = (const float*)d_in[6];
  const float* ca_in_w  = (const float*)d_in[7];
  const float* ca_in_b  = (const float*)d_in[8];
  const float* ca_out_w = (const float*)d_in[9];
  const float* ca_out_b = (const float*)d_in[10];
  const float* lin1_w   = (const float*)d_in[11];
  const float* lin1_b   = (const float*)d_in[12];
  const float* lin2_w   = (const float*)d_in[13];
  const float* lin2_b   = (const float*)d_in[14];
  const float* n1_g = (const float*)d_in[15];
  const float* n1_b = (const float*)d_in[16];
  const float* n2_g = (const float*)d_in[17];
  const float* n2_b = (const float*)d_in[18];
  const float* n3_g = (const float*)d_in[19];
  const float* n3_b = (const float*)d_in[20];

  char* ws = (char*)d_ws;
  size_t off = 0;
  auto alloc = [&](size_t bytes)->char*{
    char* p = ws + off; off += (bytes + 255) & ~(size_t)255; return p;
  };
  unsigned short* xb    = (unsigned short*)alloc(2ull*B_*T_*D_);
  unsigned short* memb  = (unsigned short*)alloc(2ull*B_*S_*D_);
  float*          x     = (float*)alloc(4ull*B_*T_*D_);
  float*          part  = (float*)alloc(4ull*B_*8*D_);
  int*            eidx  = (int*)alloc(4ull*NSLOT);
  float*          wgt   = (float*)alloc(4ull*NSLOT);
  unsigned short* wSaIn  = (unsigned short*)alloc(2ull*E_*3*D_*D_);
  unsigned short* wSaOut = (unsigned short*)alloc(2ull*E_*D_*D_);
  unsigned short* wCaIn  = (unsigned short*)alloc(2ull*E_*3*D_*D_);
  unsigned short* wCaOut = (unsigned short*)alloc(2ull*E_*D_*D_);
  unsigned short* wL1    = (unsigned short*)alloc(2ull*E_*DFF_*D_);
  unsigned short* wL2    = (unsigned short*)alloc(2ull*E_*D_*DFF_);
  unsigned short* qkv   = (unsigned short*)alloc(2ull*NSLOT*T_*3*D_);
  unsigned short* ffh   = (unsigned short*)alloc(2ull*NSLOT*T_*DFF_);
  unsigned short* attn  = (unsigned short*)alloc(2ull*NSLOT*T_*D_);
  unsigned short* proj  = (unsigned short*)alloc(2ull*NSLOT*T_*D_);
  unsigned short* x1b   = (unsigned short*)alloc(2ull*NSLOT*T_*D_);
  unsigned short* cq    = (unsigned short*)alloc(2ull*NSLOT*T_*D_);
  unsigned short* mkv   = (unsigned short*)alloc(2ull*NSLOT*S_*2*D_);
  unsigned short* x2b   = (unsigned short*)alloc(2ull*NSLOT*T_*D_);
  unsigned short* Vt1   = cq;   // alias: [slot][h][64][T]; cq written after fattn-self consumed Vt1
  unsigned short* Vt2   = qkv;  // alias: [slot][h][64][S]; qkv dead after fattn-self

  cast_bf16_k<<<1024,256,0,stream>>>(tgt,    xb,   (long)B_*T_*D_);
  cast_bf16_k<<<1024,256,0,stream>>>(memory, memb, (long)B_*S_*D_);

  const float* xcur = tgt;
  for (int l=0; l<L_; ++l){
    pool_k<<<B_*8,256,0,stream>>>(xcur, part);
    route2_k<<<B_,256,0,stream>>>(part, router_w + (size_t)l*E_*D_, eidx, wgt);
    cast_weights_k<<<2048,256,0,stream>>>(
      sa_in_w  + (size_t)l*E_*3*D_*D_, sa_out_w + (size_t)l*E_*D_*D_,
      ca_in_w  + (size_t)l*E_*3*D_*D_, ca_out_w + (size_t)l*E_*D_*D_,
      lin1_w   + (size_t)l*E_*DFF_*D_, lin2_w   + (size_t)l*E_*D_*DFF_,
      wSaIn, wSaOut, wCaIn, wCaOut, wL1, wL2);

    // QKV = x @ sa_in^T + b  (Q cols scaled by 1/8)
    gemm_lds<128,256,64,64,32><<<dim3(6,2,NSLOT),512,0,stream>>>(
      xb, (long)T_*D_, 2, 0, D_,
      wSaIn, 0, 0, (long)3*D_*D_, D_,
      eidx, sa_in_b + (size_t)l*E_*3*D_, 3*D_,
      qkv, (long)T_*3*D_, 0, 3*D_,
      512, 1, 0, 0, D_, 0.125f);
    // Vt1 = transpose of self V
    vtrans_k<<<dim3(T_/64,H_,NSLOT),256,0,stream>>>(
      qkv + 2*D_, (long)T_*3*D_, 3*D_, Vt1, T_);
    // fused self-attention
    fattn_k<4><<<dim3(T_/64, NSLOT*H_),256,0,stream>>>(
      qkv, (long)T_*3*D_, 3*D_,
      qkv + D_, (long)T_*3*D_, 3*D_,
      Vt1, attn, (long)T_*D_, D_);
    // self-attn out proj (bf16 out)
    gemm_lds<128,128,64,32,64><<<dim3(4,2,NSLOT),512,0,stream>>>(
      attn, (long)T_*D_, 1, 0, D_,
      wSaOut, 0, 0, (long)D_*D_, D_,
      eidx, sa_out_b + (size_t)l*E_*D_, D_,
      proj, (long)T_*D_, 0, D_,
      512, 1, 0, 0, 0, 1.f);
    add_ln_k<0><<<2048,256,0,stream>>>(xcur, 2, (long)T_*D_, proj, (long)T_*D_,
      n1_g + (size_t)l*E_*D_, n1_b + (size_t)l*E_*D_, eidx, x1b);
    // cross-attn Q (scaled)
    gemm_lds<128,128,64,32,64><<<dim3(4,2,NSLOT),512,0,stream>>>(
      x1b, (long)T_*D_, 1, 0, D_,
      wCaIn, 0, 0, (long)3*D_*D_, D_,
      eidx, ca_in_b + (size_t)l*E_*3*D_, 3*D_,
      cq, (long)T_*D_, 0, D_,
      512, 1, 0, 0, D_, 0.125f);
    // cross-attn K,V from memory
    gemm_lds<128,256,64,64,32><<<dim3(4,4,NSLOT),512,0,stream>>>(
      memb, (long)S_*D_, 2, 0, D_,
      wCaIn + (size_t)D_*D_, 0, 0, (long)3*D_*D_, D_,
      eidx, ca_in_b + (size_t)l*E_*3*D_ + D_, 3*D_,
      mkv, (long)S_*2*D_, 0, 2*D_,
      512, 1, 0, 0, 0, 1.f);
    // Vt2 = transpose of cross V
    vtrans_k<<<dim3(S_/64,H_,NSLOT),256,0,stream>>>(
      mkv + D_, (long)S_*2*D_, 2*D_, Vt2, S_);
    // fused cross-attention
    fattn_k<8><<<dim3(T_/64, NSLOT*H_),256,0,stream>>>(
      cq, (long)T_*D_, D_,
      mkv, (long)S_*2*D_, 2*D_,
      Vt2, attn, (long)T_*D_, D_);
    // cross-attn out proj (bf16 out)
    gemm_lds<128,128,64,32,64><<<dim3(4,2,NSLOT),512,0,stream>>>(
      attn, (long)T_*D_, 1, 0, D_,
      wCaOut, 0, 0, (long)D_*D_, D_,
      eidx, ca_out_b + (size_t)l*E_*D_, D_,
      proj, (long)T_*D_, 0, D_,
      512, 1, 0, 0, 0, 1.f);
    add_ln_k<1><<<2048,256,0,stream>>>(x1b, 1, (long)T_*D_, proj, (long)T_*D_,
      n2_g + (size_t)l*E_*D_, n2_b + (size_t)l*E_*D_, eidx, x2b);
    // FFN1 (+relu)
    gemm_lds<128,256,64,64,32><<<dim3(8,2,NSLOT),512,0,stream>>>(
      x2b, (long)T_*D_, 1, 0, D_,
      wL1, 0, 0, (long)DFF_*D_, D_,
      eidx, lin1_b + (size_t)l*E_*DFF_, DFF_,
      ffh, (long)T_*DFF_, 0, DFF_,
      512, 1, 0, 1, 0, 1.f);
    // FFN2 (bf16 out)
    gemm_lds<128,128,64,32,64><<<dim3(4,2,NSLOT),512,0,stream>>>(
      ffh, (long)T_*DFF_, 1, 0, DFF_,
      wL2, 0, 0, (long)D_*DFF_, DFF_,
      eidx, lin2_b + (size_t)l*E_*D_, D_,
      proj, (long)T_*D_, 0, D_,
      2048, 1, 0, 0, 0, 1.f);
    // n3 LN + weighted combine
    float* dstF = (l==L_-1) ? (float*)d_out : x;
    add_ln_comb_k<<<1024,256,0,stream>>>(x2b, proj,
      n3_g + (size_t)l*E_*D_, n3_b + (size_t)l*E_*D_, eidx, wgt, dstF, xb);
    xcur = x;
  }
}

// Round 13
// 951.239 us; speedup vs baseline: 1.1932x; 1.0367x over previous
//
#include <hip/hip_runtime.h>
#include <hip/hip_bf16.h>

#define L_ 4
#define E_ 4
#define D_ 512
#define DFF_ 2048
#define H_ 8
#define B_ 16
#define T_ 256
#define S_ 512
#define HD_ 64
#define NSLOT 32   // B * K

typedef __attribute__((ext_vector_type(4))) float f32x4;
typedef __attribute__((ext_vector_type(8))) short bf16x8;
typedef __attribute__((ext_vector_type(4))) int i32x4;

static __device__ __forceinline__ float bf2f(unsigned short u){
  union{float f; unsigned u;} c; c.u = ((unsigned)u)<<16; return c.f;
}
static __device__ __forceinline__ unsigned short f2bf(float f){
  union{float f; unsigned u;} c; c.f=f;
  unsigned u=c.u;
  return (unsigned short)((u + 0x7FFFu + ((u>>16)&1u))>>16);
}

static __device__ __forceinline__ void gload16(const unsigned short* g, unsigned short* l){
  __builtin_amdgcn_global_load_lds(
      (const __attribute__((address_space(1))) void*)g,
      (__attribute__((address_space(3))) void*)l, 16, 0, 0);
}

// bijective XCD-chunked block remap (m204)
static __device__ __forceinline__ int xcd_swz(int orig, int nwg){
  int q = nwg >> 3, r = nwg & 7;
  int xcd = orig & 7, idx = orig >> 3;
  return (xcd < r) ? (xcd*(q+1) + idx) : (r*(q+1) + (xcd-r)*q + idx);
}

// ---------------- routing: stage 1 — chunked pooled partial sums (deterministic) ----------------
__global__ void __launch_bounds__(256) pool_k(const float* __restrict__ x,
    float* __restrict__ part)
{
  int b = blockIdx.x >> 3, ch = blockIdx.x & 7;
  int tid = threadIdx.x;
  const float* xp = x + ((long)b*T_ + ch*32)*D_ + tid*2;
  float s0=0.f, s1=0.f;
  #pragma unroll 8
  for (int t=0;t<32;t++){
    float2 v = *(const float2*)(xp + (long)t*D_);
    s0 += v.x; s1 += v.y;
  }
  float* pp = part + ((long)b*8 + ch)*D_ + tid*2;
  pp[0]=s0; pp[1]=s1;
}

// ---------------- routing: stage 2 — combine partials, logits, top-2 ----------------
__global__ void __launch_bounds__(256) route2_k(const float* __restrict__ part,
    const float* __restrict__ rw, int* __restrict__ eidx, float* __restrict__ wgt)
{
  __shared__ float pooled[D_];
  __shared__ float logit[E_];
  int b = blockIdx.x, tid = threadIdx.x;
  for (int d = tid; d < D_; d += 256){
    float s = 0.f;
    #pragma unroll
    for (int c=0;c<8;c++) s += part[((long)b*8 + c)*D_ + d];
    pooled[d] = s * (1.f/T_);
  }
  __syncthreads();
  int wave = tid>>6, lane = tid&63;
  {
    float s=0.f;
    const float* w = rw + (long)wave*D_;
    for (int d=lane; d<D_; d+=64) s += pooled[d]*w[d];
    #pragma unroll
    for (int o=32;o;o>>=1) s += __shfl_xor(s,o);
    if (lane==0) logit[wave] = s;
  }
  __syncthreads();
  if (tid==0){
    int i1=0; float v1=logit[0];
    for (int e=1;e<E_;e++) if (logit[e] > v1){ v1=logit[e]; i1=e; }
    int i2=-1; float v2=-3.4e38f;
    for (int e=0;e<E_;e++) if (e!=i1 && logit[e] > v2){ v2=logit[e]; i2=e; }
    float e2 = __expf(v2 - v1);
    float w1 = 1.f/(1.f+e2);
    eidx[2*b]=i1; eidx[2*b+1]=i2;
    wgt[2*b]=w1; wgt[2*b+1]=e2*w1;
  }
}

// ---------------- casts ----------------
__global__ void __launch_bounds__(256) cast_bf16_k(const float* __restrict__ in,
    unsigned short* __restrict__ out, long n){
  long i = ((long)blockIdx.x*blockDim.x + threadIdx.x)*4;
  long st = (long)gridDim.x*blockDim.x*4;
  for (; i<n; i+=st){
    float4 v = *(const float4*)(in+i);
    ushort4 o; o.x=f2bf(v.x); o.y=f2bf(v.y); o.z=f2bf(v.z); o.w=f2bf(v.w);
    *(ushort4*)(out+i) = o;
  }
}

// fused per-layer weight cast (6 segments)
__global__ void __launch_bounds__(256) cast_weights_k(
    const float* __restrict__ s0, const float* __restrict__ s1,
    const float* __restrict__ s2, const float* __restrict__ s3,
    const float* __restrict__ s4, const float* __restrict__ s5,
    unsigned short* __restrict__ d0, unsigned short* __restrict__ d1,
    unsigned short* __restrict__ d2, unsigned short* __restrict__ d3,
    unsigned short* __restrict__ d4, unsigned short* __restrict__ d5)
{
  const long N0=(long)E_*3*D_*D_, N1=(long)E_*D_*D_;
  const long N2=N0, N3=N1, N4=(long)E_*DFF_*D_, N5=N4;
  const long total = N0+N1+N2+N3+N4+N5;
  long i = ((long)blockIdx.x*256 + threadIdx.x)*4;
  long st = (long)gridDim.x*256*4;
  for (; i<total; i+=st){
    const float* s; unsigned short* d; long j = i;
    if (j < N0){ s=s0; d=d0; }
    else if ((j-=N0) < N1){ s=s1; d=d1; }
    else if ((j-=N1) < N2){ s=s2; d=d2; }
    else if ((j-=N2) < N3){ s=s3; d=d3; }
    else if ((j-=N3) < N4){ s=s4; d=d4; }
    else { j-=N4; s=s5; d=d5; }
    float4 v = *(const float4*)(s+j);
    ushort4 o; o.x=f2bf(v.x); o.y=f2bf(v.y); o.z=f2bf(v.z); o.w=f2bf(v.w);
    *(ushort4*)(d+j) = o;
  }
}

// ---------------- V transpose ----------------
__global__ void __launch_bounds__(256) vtrans_k(const unsigned short* __restrict__ src,
    long sSlot, int ld, unsigned short* __restrict__ dst, int rows)
{
  __shared__ unsigned short t[64][68];
  int s0 = blockIdx.x*64; int h = blockIdx.y; int slot = blockIdx.z;
  const unsigned short* sp = src + (long)slot*sSlot + (long)h*64;
  int c = threadIdx.x&63, w = threadIdx.x>>6;
  #pragma unroll
  for (int i=0;i<16;i++){
    int r = i*4 + w;
    t[r][c] = sp[(long)(s0+r)*ld + c];
  }
  __syncthreads();
  unsigned short* dp = dst + ((long)slot*H_ + h)*((long)64*rows) + s0;
  #pragma unroll
  for (int i=0;i<16;i++){
    int d = i*4 + w;
    dp[(long)d*rows + c] = t[c][d];
  }
}

// ---------------- fused flash attention (128 q-rows per block, 8 waves) ----------------
template<int NT>
__global__ void __launch_bounds__(512) fattn_k(
    const unsigned short* __restrict__ Qg, long qSlot, int ldq,
    const unsigned short* __restrict__ Kg, long kSlot, int ldk,
    const unsigned short* __restrict__ Vtg,
    unsigned short* __restrict__ Og, long oSlot, int ldo)
{
  constexpr int SLEN = NT*64;
  __shared__ unsigned short K_lds[64][72];
  __shared__ unsigned short V_lds[64][72];
  __shared__ unsigned short P_lds[8][16][72];

  int nwg = gridDim.x*gridDim.y;
  int wg = xcd_swz(blockIdx.x + gridDim.x*blockIdx.y, nwg);
  int qb = wg % gridDim.x;
  int z  = wg / gridDim.x;        // slot*H + h
  int slot = z >> 3, h = z & 7;
  int tid = threadIdx.x, wave = tid>>6, lane = tid&63;
  int lr = lane&15, lg = lane>>4;
  int lk = lg*8;

  const unsigned short* Qp = Qg + (long)slot*qSlot + (long)h*HD_;
  const unsigned short* Kp = Kg + (long)slot*kSlot + (long)h*HD_;
  const unsigned short* Vp = Vtg + (long)z*((long)HD_*SLEN);

  bf16x8 qf[2];
  {
    int qrow = qb*128 + wave*16 + lr;
    const unsigned short* qr = Qp + (long)qrow*ldq;
    qf[0] = *(const bf16x8*)(qr + lk);
    qf[1] = *(const bf16x8*)(qr + 32 + lk);
  }

  float m_prev[4], l_run[4];
  f32x4 acc_o[4];
  #pragma unroll
  for (int r=0;r<4;r++){ m_prev[r]=-1e30f; l_run[r]=0.f; }
  #pragma unroll
  for (int ni=0;ni<4;ni++) acc_o[ni]=(f32x4){0.f,0.f,0.f,0.f};

  int srow = tid>>3, sch = tid&7;   // 512 threads: rows 0..63, one 16B chunk each

  i32x4 kr0 = *(const i32x4*)(Kp + (long)srow*ldk + sch*8);
  i32x4 vr0 = *(const i32x4*)(Vp + (long)srow*SLEN + sch*8);

  for (int t=0; t<NT; ++t){
    __syncthreads();
    *(i32x4*)&K_lds[srow][sch*8] = kr0;
    *(i32x4*)&V_lds[srow][sch*8] = vr0;
    __syncthreads();

    int tn = (t+1 < NT) ? t+1 : t;
    int k0n = tn*64;
    kr0 = *(const i32x4*)(Kp + (long)(k0n+srow)*ldk + sch*8);
    vr0 = *(const i32x4*)(Vp + (long)srow*SLEN + k0n + sch*8);

    // S = Q @ K^T
    f32x4 s[4];
    #pragma unroll
    for (int ni=0;ni<4;ni++) s[ni]=(f32x4){0.f,0.f,0.f,0.f};
    __builtin_amdgcn_s_setprio(1);
    #pragma unroll
    for (int ki=0;ki<2;ki++){
      #pragma unroll
      for (int ni=0;ni<4;ni++){
        bf16x8 kf = *(const bf16x8*)&K_lds[ni*16+lr][ki*32+lk];
        s[ni] = __builtin_amdgcn_mfma_f32_16x16x32_bf16(qf[ki], kf, s[ni],0,0,0);
      }
    }
    __builtin_amdgcn_s_setprio(0);
    // online softmax with rescale-skip
    float tmax[4];
    #pragma unroll
    for (int r=0;r<4;r++){
      tmax[r] = fmaxf(fmaxf(s[0][r],s[1][r]),fmaxf(s[2][r],s[3][r]));
      #pragma unroll
      for (int msk=1; msk<16; msk<<=1) tmax[r]=fmaxf(tmax[r], __shfl_xor(tmax[r],msk));
    }
    bool inc = (tmax[0]>m_prev[0])|(tmax[1]>m_prev[1])|(tmax[2]>m_prev[2])|(tmax[3]>m_prev[3]);
    if (__any(inc)){
      #pragma unroll
      for (int r=0;r<4;r++){
        float mnew = fmaxf(m_prev[r], tmax[r]);
        float corr = __expf(m_prev[r]-mnew);
        m_prev[r] = mnew;
        l_run[r] *= corr;
        #pragma unroll
        for (int ni=0;ni<4;ni++) acc_o[ni][r] *= corr;
      }
    }
    float rs[4] = {0.f,0.f,0.f,0.f};
    #pragma unroll
    for (int ni=0;ni<4;ni++){
      #pragma unroll
      for (int r=0;r<4;r++){
        float p = __expf(s[ni][r]-m_prev[r]);
        rs[r] += p;
        P_lds[wave][lg*4+r][ni*16+lr] = f2bf(p);
      }
    }
    #pragma unroll
    for (int r=0;r<4;r++){
      #pragma unroll
      for (int msk=1; msk<16; msk<<=1) rs[r] += __shfl_xor(rs[r],msk);
      l_run[r] += rs[r];
    }
    // O += P @ V   (P_lds wave-private)
    __builtin_amdgcn_s_setprio(1);
    #pragma unroll
    for (int ki=0;ki<2;ki++){
      bf16x8 pf = *(const bf16x8*)&P_lds[wave][lr][ki*32+lk];
      #pragma unroll
      for (int ni=0;ni<4;ni++){
        bf16x8 vf = *(const bf16x8*)&V_lds[ni*16+lr][ki*32+lk];
        acc_o[ni] = __builtin_amdgcn_mfma_f32_16x16x32_bf16(pf, vf, acc_o[ni],0,0,0);
      }
    }
    __builtin_amdgcn_s_setprio(0);
  }
  unsigned short* Op = Og + (long)slot*oSlot + (long)h*HD_;
  #pragma unroll
  for (int r=0;r<4;r++){
    float inv = 1.f/l_run[r];
    int q = qb*128 + wave*16 + lg*4 + r;
    #pragma unroll
    for (int ni=0;ni<4;ni++)
      Op[(long)q*ldo + ni*16 + lr] = f2bf(acc_o[ni][r]*inv);
  }
}

// ---------------- LDS-staged GEMM  C = A @ W^T (+bias)(*scale)(relu) ----------------
// dbuf LDS, chunk-XOR swizzle, 8 waves, XCD remap.
//   <64,128,32,32,64>  : small GEMMs (2 blocks/CU via 512-block grid)
//   <128,256,64,64,32> : big GEMMs
template<int BM, int BN, int WTM, int WTN, int BK>
__global__ void __launch_bounds__(512) gemm_lds(
    const unsigned short* __restrict__ A, long aSlot, int aDiv, long aHead, int lda,
    const unsigned short* __restrict__ W, long wSlot, long wHead, long wExp, int ldw,
    const int* __restrict__ eidx, const float* __restrict__ bias, long biasExp,
    void* __restrict__ Cp, long cSlot, long cHead, int ldc,
    int K, int HZ, int f32out, int relu, int scaleNlim, float scaleVal)
{
  constexpr int WAVES_N = BN/WTN;
  constexpr int MI = WTM/16, NI = WTN/16;
  constexpr int SLOTS = BK/8;
  static_assert((BM/WTM)*(BN/WTN) == 8, "8 waves");
  static_assert((BM*SLOTS)%512==0 && (BN*SLOTS)%512==0, "stage coverage");
  __shared__ unsigned short smem[2*(BM+BN)*BK];

  int nwg = gridDim.x*gridDim.y*gridDim.z;
  int wg = xcd_swz(blockIdx.x + gridDim.x*(blockIdx.y + gridDim.y*blockIdx.z), nwg);
  int bx = wg % gridDim.x; int t1 = wg / gridDim.x;
  int by = t1 % gridDim.y; int z  = t1 / gridDim.y;

  int slot = z / HZ;
  int h = z - slot*HZ;
  int e = eidx ? eidx[slot] : 0;
  const unsigned short* Ap = A + (long)(slot/aDiv)*aSlot + (long)h*aHead;
  const unsigned short* Wp = W + (long)slot*wSlot + (long)h*wHead + (long)e*wExp;
  const float* bp = bias ? (bias + (long)e*biasExp) : nullptr;

  int tid  = threadIdx.x;
  int wave = tid>>6, lane = tid&63;
  int wm = wave / WAVES_N, wn = wave % WAVES_N;
  int bm0 = by*BM;
  int bn0 = bx*BN;
  int lr = lane&15;
  int lg = lane>>4;
  int swz = (BK==64) ? (lr&7) : ((lr>>1)&3);

  Ap += (long)bm0*lda;
  Wp += (long)bn0*ldw;

  f32x4 acc[MI][NI];
  #pragma unroll
  for (int i=0;i<MI;i++)
  #pragma unroll
  for (int j=0;j<NI;j++) acc[i][j] = (f32x4){0.f,0.f,0.f,0.f};

  auto stage = [&](int buf, int k0){
    unsigned short* as = &smem[(size_t)buf*(BM+BN)*BK];
    unsigned short* bs = as + BM*BK;
    #pragma unroll
    for (int i=0;i<BM*SLOTS/512;i++){
      int cch = i*512 + tid;
      int row = cch / SLOTS, c = cch % SLOTS;
      int cs = (BK==64) ? (c ^ (row&7)) : (c ^ ((row>>1)&3));
      gload16(Ap + (long)row*lda + k0 + (cs<<3), as + cch*8);
    }
    #pragma unroll
    for (int i=0;i<BN*SLOTS/512;i++){
      int cch = i*512 + tid;
      int row = cch / SLOTS, c = cch % SLOTS;
      int cs = (BK==64) ? (c ^ (row&7)) : (c ^ ((row>>1)&3));
      gload16(Wp + (long)row*ldw + k0 + (cs<<3), bs + cch*8);
    }
  };

  auto compute = [&](int buf){
    unsigned short* as = &smem[(size_t)buf*(BM+BN)*BK];
    unsigned short* bs = as + BM*BK;
    #pragma unroll
    for (int ki=0;ki<BK/32;ki++){
      bf16x8 af[MI], bfr[NI];
      #pragma unroll
      for (int mi=0;mi<MI;mi++){
        int row = wm*WTM + mi*16 + lr;
        af[mi] = *(const bf16x8*)&as[row*BK + (((ki*4+lg) ^ swz)<<3)];
      }
      #pragma unroll
      for (int ni=0;ni<NI;ni++){
        int row = wn*WTN + ni*16 + lr;
        bfr[ni] = *(const bf16x8*)&bs[row*BK + (((ki*4+lg) ^ swz)<<3)];
      }
      __builtin_amdgcn_s_setprio(1);
      #pragma unroll
      for (int mi=0;mi<MI;mi++)
      #pragma unroll
      for (int ni=0;ni<NI;ni++)
        acc[mi][ni] = __builtin_amdgcn_mfma_f32_16x16x32_bf16(af[mi], bfr[ni], acc[mi][ni], 0,0,0);
      __builtin_amdgcn_s_setprio(0);
    }
  };

  int NT = K / BK;
  stage(0, 0);
  __syncthreads();
  int cur = 0;
  for (int t=0; t<NT; ++t){
    if (t+1 < NT) stage(cur^1, (t+1)*BK);
    compute(cur);
    __syncthreads();
    cur ^= 1;
  }

  long cbase = (long)slot*cSlot + (long)h*cHead;
  int rbase = lg*4;
  #pragma unroll
  for (int mi=0;mi<MI;mi++)
  #pragma unroll
  for (int ni=0;ni<NI;ni++){
    f32x4 v = acc[mi][ni];
    int n = bn0 + wn*WTN + ni*16 + lr;
    float bv = bp ? bp[n] : 0.f;
    float scv = (n < scaleNlim) ? scaleVal : 1.f;
    #pragma unroll
    for (int r=0;r<4;r++){
      int m = bm0 + wm*WTM + mi*16 + rbase + r;
      float val = (v[r] + bv) * scv;
      if (relu) val = fmaxf(val, 0.f);
      long o = cbase + (long)m*ldc + n;
      if (f32out) ((float*)Cp)[o] = val;
      else ((unsigned short*)Cp)[o] = f2bf(val);
    }
  }
}

// ---------------- residual add + LayerNorm (vectorized; A fp32 or bf16; bf16 out) ----------------
template<int ABF>
__global__ void __launch_bounds__(256) add_ln_k(
    const void* __restrict__ Ab_, int aDiv, long aStride,
    const unsigned short* __restrict__ Bb, long bStride,
    const float* __restrict__ G, const float* __restrict__ Bt,
    const int* __restrict__ eidx,
    unsigned short* __restrict__ OutB)
{
  int row = blockIdx.x*4 + (threadIdx.x>>6);
  int slot = row>>8, t = row&255;
  int lane = threadIdx.x&63;
  int d0 = lane*8;
  float x[8];
  if (ABF){
    const unsigned short* a = (const unsigned short*)Ab_ + (long)(slot/aDiv)*aStride + (long)t*D_ + d0;
    ushort4 a0 = *(const ushort4*)a, a1 = *(const ushort4*)(a+4);
    x[0]=bf2f(a0.x); x[1]=bf2f(a0.y); x[2]=bf2f(a0.z); x[3]=bf2f(a0.w);
    x[4]=bf2f(a1.x); x[5]=bf2f(a1.y); x[6]=bf2f(a1.z); x[7]=bf2f(a1.w);
  } else {
    const float* a = (const float*)Ab_ + (long)(slot/aDiv)*aStride + (long)t*D_ + d0;
    float4 a0 = *(const float4*)a, a1 = *(const float4*)(a+4);
    x[0]=a0.x; x[1]=a0.y; x[2]=a0.z; x[3]=a0.w;
    x[4]=a1.x; x[5]=a1.y; x[6]=a1.z; x[7]=a1.w;
  }
  const unsigned short* b = Bb + (long)slot*bStride + (long)t*D_ + d0;
  ushort4 b0 = *(const ushort4*)b, b1 = *(const ushort4*)(b+4);
  x[0]+=bf2f(b0.x); x[1]+=bf2f(b0.y); x[2]+=bf2f(b0.z); x[3]+=bf2f(b0.w);
  x[4]+=bf2f(b1.x); x[5]+=bf2f(b1.y); x[6]+=bf2f(b1.z); x[7]+=bf2f(b1.w);
  float s=0.f;
  #pragma unroll
  for (int i=0;i<8;i++) s += x[i];
  #pragma unroll
  for (int o=32;o;o>>=1) s += __shfl_xor(s,o);
  float m = s*(1.f/D_);
  float q=0.f;
  #pragma unroll
  for (int i=0;i<8;i++){ float d=x[i]-m; q+=d*d; }
  #pragma unroll
  for (int o=32;o;o>>=1) q += __shfl_xor(q,o);
  float rs = rsqrtf(q*(1.f/D_)+1e-5f);
  int e = eidx[slot];
  const float* g  = G  + (long)e*D_ + d0;
  const float* bt = Bt + (long)e*D_ + d0;
  float4 g0 = *(const float4*)g, g1 = *(const float4*)(g+4);
  float4 t0 = *(const float4*)bt, t1 = *(const float4*)(bt+4);
  float gg[8] = {g0.x,g0.y,g0.z,g0.w,g1.x,g1.y,g1.z,g1.w};
  float tt[8] = {t0.x,t0.y,t0.z,t0.w,t1.x,t1.y,t1.z,t1.w};
  long ob = (long)slot*(T_*D_) + (long)t*D_ + d0;
  ushort4 o0, o1;
  float y0=(x[0]-m)*rs*gg[0]+tt[0], y1=(x[1]-m)*rs*gg[1]+tt[1];
  float y2=(x[2]-m)*rs*gg[2]+tt[2], y3=(x[3]-m)*rs*gg[3]+tt[3];
  float y4=(x[4]-m)*rs*gg[4]+tt[4], y5=(x[5]-m)*rs*gg[5]+tt[5];
  float y6=(x[6]-m)*rs*gg[6]+tt[6], y7=(x[7]-m)*rs*gg[7]+tt[7];
  o0.x=f2bf(y0); o0.y=f2bf(y1); o0.z=f2bf(y2); o0.w=f2bf(y3);
  o1.x=f2bf(y4); o1.y=f2bf(y5); o1.z=f2bf(y6); o1.w=f2bf(y7);
  *(ushort4*)(OutB+ob) = o0;
  *(ushort4*)(OutB+ob+4) = o1;
}

// ---------------- residual add + LayerNorm (n3) + weighted slot combine (bf16 in) ----------------
__global__ void __launch_bounds__(256) add_ln_comb_k(
    const unsigned short* __restrict__ x2b, const unsigned short* __restrict__ proj,
    const float* __restrict__ G, const float* __restrict__ Bt,
    const int* __restrict__ eidx, const float* __restrict__ wgt,
    float* __restrict__ dstF, unsigned short* __restrict__ dstB)
{
  int row = blockIdx.x*4 + (threadIdx.x>>6);   // b*256+t
  int b = row>>8, t = row&255;
  int lane = threadIdx.x&63;
  int d0 = lane*8;
  float out[8];
  #pragma unroll
  for (int i=0;i<8;i++) out[i]=0.f;
  #pragma unroll
  for (int s2i=0;s2i<2;s2i++){
    int slot = 2*b + s2i;
    int e = eidx[slot];
    float w = wgt[slot];
    const unsigned short* a = x2b + (long)slot*(T_*D_) + (long)t*D_ + d0;
    const unsigned short* p = proj + (long)slot*(T_*D_) + (long)t*D_ + d0;
    ushort4 a0 = *(const ushort4*)a, a1 = *(const ushort4*)(a+4);
    ushort4 p0 = *(const ushort4*)p, p1 = *(const ushort4*)(p+4);
    float x[8];
    x[0]=bf2f(a0.x)+bf2f(p0.x); x[1]=bf2f(a0.y)+bf2f(p0.y);
    x[2]=bf2f(a0.z)+bf2f(p0.z); x[3]=bf2f(a0.w)+bf2f(p0.w);
    x[4]=bf2f(a1.x)+bf2f(p1.x); x[5]=bf2f(a1.y)+bf2f(p1.y);
    x[6]=bf2f(a1.z)+bf2f(p1.z); x[7]=bf2f(a1.w)+bf2f(p1.w);
    float s=0.f;
    #pragma unroll
    for (int i=0;i<8;i++) s += x[i];
    #pragma unroll
    for (int o=32;o;o>>=1) s += __shfl_xor(s,o);
    float m = s*(1.f/D_);
    float q=0.f;
    #pragma unroll
    for (int i=0;i<8;i++){ float d=x[i]-m; q+=d*d; }
    #pragma unroll
    for (int o=32;o;o>>=1) q += __shfl_xor(q,o);
    float rs = rsqrtf(q*(1.f/D_)+1e-5f);
    const float* g  = G  + (long)e*D_ + d0;
    const float* bt = Bt + (long)e*D_ + d0;
    float4 g0 = *(const float4*)g, g1 = *(const float4*)(g+4);
    float4 t0 = *(const float4*)bt, t1 = *(const float4*)(bt+4);
    float gg[8] = {g0.x,g0.y,g0.z,g0.w,g1.x,g1.y,g1.z,g1.w};
    float tt[8] = {t0.x,t0.y,t0.z,t0.w,t1.x,t1.y,t1.z,t1.w};
    #pragma unroll
    for (int i=0;i<8;i++) out[i] += w*((x[i]-m)*rs*gg[i]+tt[i]);
  }
  long ob = (long)row*D_ + d0;
  float4 f0 = {out[0],out[1],out[2],out[3]};
  float4 f1 = {out[4],out[5],out[6],out[7]};
  *(float4*)(dstF+ob) = f0;
  *(float4*)(dstF+ob+4) = f1;
  ushort4 o0, o1;
  o0.x=f2bf(out[0]); o0.y=f2bf(out[1]); o0.z=f2bf(out[2]); o0.w=f2bf(out[3]);
  o1.x=f2bf(out[4]); o1.y=f2bf(out[5]); o1.z=f2bf(out[6]); o1.w=f2bf(out[7]);
  *(ushort4*)(dstB+ob) = o0;
  *(ushort4*)(dstB+ob+4) = o1;
}

extern "C" void kernel_launch(void* const* d_in, const int* in_sizes, int n_in,
                              void* d_out, int out_size, void* d_ws, size_t ws_size,
                              hipStream_t stream)
{
  const float* tgt      = (const float*)d_in[0];
  const float* memory   = (const float*)d_in[1];
  const float* router_w = (const float*)d_in[2];
  const float* sa_in_w  = (const float*)d_in[3];
  const float* sa_in_b  = (const float*)d_in[4];
  const float* sa_out_w = (const float*)d_in[5];
  const float* sa_out_b = (const float*)d_in[6];
  const float* ca_in_w  = (const float*)d_in[7];
  const float* ca_in_b  = (const float*)d_in[8];
  const float* ca_out_w = (const float*)d_in[9];
  const float* ca_out_b = (const float*)d_in[10];
  const float* lin1_w   = (const float*)d_in[11];
  const float* lin1_b   = (const float*)d_in[12];
  const float* lin2_w   = (const float*)d_in[13];
  const float* lin2_b   = (const float*)d_in[14];
  const float* n1_g = (const float*)d_in[15];
  const float* n1_b = (const float*)d_in[16];
  const float* n2_g = (const float*)d_in[17];
  const float* n2_b = (const float*)d_in[18];
  const float* n3_g = (const float*)d_in[19];
  const float* n3_b = (const float*)d_in[20];

  char* ws = (char*)d_ws;
  size_t off = 0;
  auto alloc = [&](size_t bytes)->char*{
    char* p = ws + off; off += (bytes + 255) & ~(size_t)255; return p;
  };
  unsigned short* xb    = (unsigned short*)alloc(2ull*B_*T_*D_);
  unsigned short* memb  = (unsigned short*)alloc(2ull*B_*S_*D_);
  float*          x     = (float*)alloc(4ull*B_*T_*D_);
  float*          part  = (float*)alloc(4ull*B_*8*D_);
  int*            eidx  = (int*)alloc(4ull*NSLOT);
  float*          wgt   = (float*)alloc(4ull*NSLOT);
  unsigned short* wSaIn  = (unsigned short*)alloc(2ull*E_*3*D_*D_);
  unsigned short* wSaOut = (unsigned short*)alloc(2ull*E_*D_*D_);
  unsigned short* wCaIn  = (unsigned short*)alloc(2ull*E_*3*D_*D_);
  unsigned short* wCaOut = (unsigned short*)alloc(2ull*E_*D_*D_);
  unsigned short* wL1    = (unsigned short*)alloc(2ull*E_*DFF_*D_);
  unsigned short* wL2    = (unsigned short*)alloc(2ull*E_*D_*DFF_);
  unsigned short* qkv   = (unsigned short*)alloc(2ull*NSLOT*T_*3*D_);
  unsigned short* ffh   = (unsigned short*)alloc(2ull*NSLOT*T_*DFF_);
  unsigned short* attn  = (unsigned short*)alloc(2ull*NSLOT*T_*D_);
  unsigned short* proj  = (unsigned short*)alloc(2ull*NSLOT*T_*D_);
  unsigned short* x1b   = (unsigned short*)alloc(2ull*NSLOT*T_*D_);
  unsigned short* cq    = (unsigned short*)alloc(2ull*NSLOT*T_*D_);
  unsigned short* mkv   = (unsigned short*)alloc(2ull*NSLOT*S_*2*D_);
  unsigned short* x2b   = (unsigned short*)alloc(2ull*NSLOT*T_*D_);
  unsigned short* Vt1   = cq;   // alias: [slot][h][64][T]; cq written after fattn-self consumed Vt1
  unsigned short* Vt2   = qkv;  // alias: [slot][h][64][S]; qkv dead after fattn-self

  cast_bf16_k<<<1024,256,0,stream>>>(tgt,    xb,   (long)B_*T_*D_);
  cast_bf16_k<<<1024,256,0,stream>>>(memory, memb, (long)B_*S_*D_);

  const float* xcur = tgt;
  for (int l=0; l<L_; ++l){
    pool_k<<<B_*8,256,0,stream>>>(xcur, part);
    route2_k<<<B_,256,0,stream>>>(part, router_w + (size_t)l*E_*D_, eidx, wgt);
    cast_weights_k<<<2048,256,0,stream>>>(
      sa_in_w  + (size_t)l*E_*3*D_*D_, sa_out_w + (size_t)l*E_*D_*D_,
      ca_in_w  + (size_t)l*E_*3*D_*D_, ca_out_w + (size_t)l*E_*D_*D_,
      lin1_w   + (size_t)l*E_*DFF_*D_, lin2_w   + (size_t)l*E_*D_*DFF_,
      wSaIn, wSaOut, wCaIn, wCaOut, wL1, wL2);

    // QKV = x @ sa_in^T + b  (Q cols scaled by 1/8)
    gemm_lds<128,256,64,64,32><<<dim3(6,2,NSLOT),512,0,stream>>>(
      xb, (long)T_*D_, 2, 0, D_,
      wSaIn, 0, 0, (long)3*D_*D_, D_,
      eidx, sa_in_b + (size_t)l*E_*3*D_, 3*D_,
      qkv, (long)T_*3*D_, 0, 3*D_,
      512, 1, 0, 0, D_, 0.125f);
    // Vt1 = transpose of self V
    vtrans_k<<<dim3(T_/64,H_,NSLOT),256,0,stream>>>(
      qkv + 2*D_, (long)T_*3*D_, 3*D_, Vt1, T_);
    // fused self-attention (128 q-rows / block)
    fattn_k<4><<<dim3(T_/128, NSLOT*H_),512,0,stream>>>(
      qkv, (long)T_*3*D_, 3*D_,
      qkv + D_, (long)T_*3*D_, 3*D_,
      Vt1, attn, (long)T_*D_, D_);
    // self-attn out proj (bf16 out)
    gemm_lds<64,128,32,32,64><<<dim3(4,4,NSLOT),512,0,stream>>>(
      attn, (long)T_*D_, 1, 0, D_,
      wSaOut, 0, 0, (long)D_*D_, D_,
      eidx, sa_out_b + (size_t)l*E_*D_, D_,
      proj, (long)T_*D_, 0, D_,
      512, 1, 0, 0, 0, 1.f);
    add_ln_k<0><<<2048,256,0,stream>>>(xcur, 2, (long)T_*D_, proj, (long)T_*D_,
      n1_g + (size_t)l*E_*D_, n1_b + (size_t)l*E_*D_, eidx, x1b);
    // cross-attn Q (scaled)
    gemm_lds<64,128,32,32,64><<<dim3(4,4,NSLOT),512,0,stream>>>(
      x1b, (long)T_*D_, 1, 0, D_,
      wCaIn, 0, 0, (long)3*D_*D_, D_,
      eidx, ca_in_b + (size_t)l*E_*3*D_, 3*D_,
      cq, (long)T_*D_, 0, D_,
      512, 1, 0, 0, D_, 0.125f);
    // cross-attn K,V from memory
    gemm_lds<128,256,64,64,32><<<dim3(4,4,NSLOT),512,0,stream>>>(
      memb, (long)S_*D_, 2, 0, D_,
      wCaIn + (size_t)D_*D_, 0, 0, (long)3*D_*D_, D_,
      eidx, ca_in_b + (size_t)l*E_*3*D_ + D_, 3*D_,
      mkv, (long)S_*2*D_, 0, 2*D_,
      512, 1, 0, 0, 0, 1.f);
    // Vt2 = transpose of cross V
    vtrans_k<<<dim3(S_/64,H_,NSLOT),256,0,stream>>>(
      mkv + D_, (long)S_*2*D_, 2*D_, Vt2, S_);
    // fused cross-attention (128 q-rows / block)
    fattn_k<8><<<dim3(T_/128, NSLOT*H_),512,0,stream>>>(
      cq, (long)T_*D_, D_,
      mkv, (long)S_*2*D_, 2*D_,
      Vt2, attn, (long)T_*D_, D_);
    // cross-attn out proj (bf16 out)
    gemm_lds<64,128,32,32,64><<<dim3(4,4,NSLOT),512,0,stream>>>(
      attn, (long)T_*D_, 1, 0, D_,
      wCaOut, 0, 0, (long)D_*D_, D_,
      eidx, ca_out_b + (size_t)l*E_*D_, D_,
      proj, (long)T_*D_, 0, D_,
      512, 1, 0, 0, 0, 1.f);
    add_ln_k<1><<<2048,256,0,stream>>>(x1b, 1, (long)T_*D_, proj, (long)T_*D_,
      n2_g + (size_t)l*E_*D_, n2_b + (size_t)l*E_*D_, eidx, x2b);
    // FFN1 (+relu)
    gemm_lds<128,256,64,64,32><<<dim3(8,2,NSLOT),512,0,stream>>>(
      x2b, (long)T_*D_, 1, 0, D_,
      wL1, 0, 0, (long)DFF_*D_, D_,
      eidx, lin1_b + (size_t)l*E_*DFF_, DFF_,
      ffh, (long)T_*DFF_, 0, DFF_,
      512, 1, 0, 1, 0, 1.f);
    // FFN2 (bf16 out)
    gemm_lds<64,128,32,32,64><<<dim3(4,4,NSLOT),512,0,stream>>>(
      ffh, (long)T_*DFF_, 1, 0, DFF_,
      wL2, 0, 0, (long)D_*DFF_, DFF_,
      eidx, lin2_b + (size_t)l*E_*D_, D_,
      proj, (long)T_*D_, 0, D_,
      2048, 1, 0, 0, 0, 1.f);
    // n3 LN + weighted combine
    float* dstF = (l==L_-1) ? (float*)d_out : x;
    add_ln_comb_k<<<1024,256,0,stream>>>(x2b, proj,
      n3_g + (size_t)l*E_*D_, n3_b + (size_t)l*E_*D_, eidx, wgt, dstF, xb);
    xcur = x;
  }
}

// Round 14
// 934.050 us; speedup vs baseline: 1.2152x; 1.0184x over previous
//
#include <hip/hip_runtime.h>
#include <hip/hip_bf16.h>

#define L_ 4
#define E_ 4
#define D_ 512
#define DFF_ 2048
#define H_ 8
#define B_ 16
#define T_ 256
#define S_ 512
#define HD_ 64
#define NSLOT 32   // B * K

typedef __attribute__((ext_vector_type(4))) float f32x4;
typedef __attribute__((ext_vector_type(8))) short bf16x8;
typedef __attribute__((ext_vector_type(4))) int i32x4;

static __device__ __forceinline__ float bf2f(unsigned short u){
  union{float f; unsigned u;} c; c.u = ((unsigned)u)<<16; return c.f;
}
static __device__ __forceinline__ unsigned short f2bf(float f){
  union{float f; unsigned u;} c; c.f=f;
  unsigned u=c.u;
  return (unsigned short)((u + 0x7FFFu + ((u>>16)&1u))>>16);
}

static __device__ __forceinline__ void gload16(const unsigned short* g, unsigned short* l){
  __builtin_amdgcn_global_load_lds(
      (const __attribute__((address_space(1))) void*)g,
      (__attribute__((address_space(3))) void*)l, 16, 0, 0);
}

// bijective XCD-chunked block remap (m204)
static __device__ __forceinline__ int xcd_swz(int orig, int nwg){
  int q = nwg >> 3, r = nwg & 7;
  int xcd = orig & 7, idx = orig >> 3;
  return (xcd < r) ? (xcd*(q+1) + idx) : (r*(q+1) + (xcd-r)*q + idx);
}

// ---------------- routing: stage 1 — chunked pooled partial sums (deterministic) ----------------
__global__ void __launch_bounds__(256) pool_k(const float* __restrict__ x,
    float* __restrict__ part)
{
  int b = blockIdx.x >> 3, ch = blockIdx.x & 7;
  int tid = threadIdx.x;
  const float* xp = x + ((long)b*T_ + ch*32)*D_ + tid*2;
  float s0=0.f, s1=0.f;
  #pragma unroll 8
  for (int t=0;t<32;t++){
    float2 v = *(const float2*)(xp + (long)t*D_);
    s0 += v.x; s1 += v.y;
  }
  float* pp = part + ((long)b*8 + ch)*D_ + tid*2;
  pp[0]=s0; pp[1]=s1;
}

// ---------------- routing: stage 2 — combine partials, logits, top-2 ----------------
__global__ void __launch_bounds__(256) route2_k(const float* __restrict__ part,
    const float* __restrict__ rw, int* __restrict__ eidx, float* __restrict__ wgt)
{
  __shared__ float pooled[D_];
  __shared__ float logit[E_];
  int b = blockIdx.x, tid = threadIdx.x;
  for (int d = tid; d < D_; d += 256){
    float s = 0.f;
    #pragma unroll
    for (int c=0;c<8;c++) s += part[((long)b*8 + c)*D_ + d];
    pooled[d] = s * (1.f/T_);
  }
  __syncthreads();
  int wave = tid>>6, lane = tid&63;
  {
    float s=0.f;
    const float* w = rw + (long)wave*D_;
    for (int d=lane; d<D_; d+=64) s += pooled[d]*w[d];
    #pragma unroll
    for (int o=32;o;o>>=1) s += __shfl_xor(s,o);
    if (lane==0) logit[wave] = s;
  }
  __syncthreads();
  if (tid==0){
    int i1=0; float v1=logit[0];
    for (int e=1;e<E_;e++) if (logit[e] > v1){ v1=logit[e]; i1=e; }
    int i2=-1; float v2=-3.4e38f;
    for (int e=0;e<E_;e++) if (e!=i1 && logit[e] > v2){ v2=logit[e]; i2=e; }
    float e2 = __expf(v2 - v1);
    float w1 = 1.f/(1.f+e2);
    eidx[2*b]=i1; eidx[2*b+1]=i2;
    wgt[2*b]=w1; wgt[2*b+1]=e2*w1;
  }
}

// ---------------- casts ----------------
__global__ void __launch_bounds__(256) cast_bf16_k(const float* __restrict__ in,
    unsigned short* __restrict__ out, long n){
  long i = ((long)blockIdx.x*blockDim.x + threadIdx.x)*4;
  long st = (long)gridDim.x*blockDim.x*4;
  for (; i<n; i+=st){
    float4 v = *(const float4*)(in+i);
    ushort4 o; o.x=f2bf(v.x); o.y=f2bf(v.y); o.z=f2bf(v.z); o.w=f2bf(v.w);
    *(ushort4*)(out+i) = o;
  }
}

// fused per-layer weight cast (6 segments)
__global__ void __launch_bounds__(256) cast_weights_k(
    const float* __restrict__ s0, const float* __restrict__ s1,
    const float* __restrict__ s2, const float* __restrict__ s3,
    const float* __restrict__ s4, const float* __restrict__ s5,
    unsigned short* __restrict__ d0, unsigned short* __restrict__ d1,
    unsigned short* __restrict__ d2, unsigned short* __restrict__ d3,
    unsigned short* __restrict__ d4, unsigned short* __restrict__ d5)
{
  const long N0=(long)E_*3*D_*D_, N1=(long)E_*D_*D_;
  const long N2=N0, N3=N1, N4=(long)E_*DFF_*D_, N5=N4;
  const long total = N0+N1+N2+N3+N4+N5;
  long i = ((long)blockIdx.x*256 + threadIdx.x)*4;
  long st = (long)gridDim.x*256*4;
  for (; i<total; i+=st){
    const float* s; unsigned short* d; long j = i;
    if (j < N0){ s=s0; d=d0; }
    else if ((j-=N0) < N1){ s=s1; d=d1; }
    else if ((j-=N1) < N2){ s=s2; d=d2; }
    else if ((j-=N2) < N3){ s=s3; d=d3; }
    else if ((j-=N3) < N4){ s=s4; d=d4; }
    else { j-=N4; s=s5; d=d5; }
    float4 v = *(const float4*)(s+j);
    ushort4 o; o.x=f2bf(v.x); o.y=f2bf(v.y); o.z=f2bf(v.z); o.w=f2bf(v.w);
    *(ushort4*)(d+j) = o;
  }
}

// ---------------- dual V transpose (Vt1 from qkv-V, Vt2 from mkv-V) ----------------
__global__ void __launch_bounds__(256) vtrans2_k(
    const unsigned short* __restrict__ src0, long sSlot0, int ld0,
    unsigned short* __restrict__ dst0, int rows0,
    const unsigned short* __restrict__ src1, long sSlot1, int ld1,
    unsigned short* __restrict__ dst1, int rows1)
{
  __shared__ unsigned short t[64][68];
  int xb = blockIdx.x;
  const unsigned short* src; long sSlot; int ld; unsigned short* dst; int rows; int s0;
  if (xb < rows0/64){ src=src0; sSlot=sSlot0; ld=ld0; dst=dst0; rows=rows0; s0=xb*64; }
  else              { src=src1; sSlot=sSlot1; ld=ld1; dst=dst1; rows=rows1; s0=(xb-rows0/64)*64; }
  int h = blockIdx.y; int slot = blockIdx.z;
  const unsigned short* sp = src + (long)slot*sSlot + (long)h*64;
  int c = threadIdx.x&63, w = threadIdx.x>>6;
  #pragma unroll
  for (int i=0;i<16;i++){
    int r = i*4 + w;
    t[r][c] = sp[(long)(s0+r)*ld + c];
  }
  __syncthreads();
  unsigned short* dp = dst + ((long)slot*H_ + h)*((long)64*rows) + s0;
  #pragma unroll
  for (int i=0;i<16;i++){
    int d = i*4 + w;
    dp[(long)d*rows + c] = t[c][d];
  }
}

// ---------------- fused flash attention (128 q-rows per block, 8 waves) ----------------
template<int NT>
__global__ void __launch_bounds__(512) fattn_k(
    const unsigned short* __restrict__ Qg, long qSlot, int ldq,
    const unsigned short* __restrict__ Kg, long kSlot, int ldk,
    const unsigned short* __restrict__ Vtg,
    unsigned short* __restrict__ Og, long oSlot, int ldo)
{
  constexpr int SLEN = NT*64;
  __shared__ unsigned short K_lds[64][72];
  __shared__ unsigned short V_lds[64][72];
  __shared__ unsigned short P_lds[8][16][72];

  int nwg = gridDim.x*gridDim.y;
  int wg = xcd_swz(blockIdx.x + gridDim.x*blockIdx.y, nwg);
  int qb = wg % gridDim.x;
  int z  = wg / gridDim.x;        // slot*H + h
  int slot = z >> 3, h = z & 7;
  int tid = threadIdx.x, wave = tid>>6, lane = tid&63;
  int lr = lane&15, lg = lane>>4;
  int lk = lg*8;

  const unsigned short* Qp = Qg + (long)slot*qSlot + (long)h*HD_;
  const unsigned short* Kp = Kg + (long)slot*kSlot + (long)h*HD_;
  const unsigned short* Vp = Vtg + (long)z*((long)HD_*SLEN);

  bf16x8 qf[2];
  {
    int qrow = qb*128 + wave*16 + lr;
    const unsigned short* qr = Qp + (long)qrow*ldq;
    qf[0] = *(const bf16x8*)(qr + lk);
    qf[1] = *(const bf16x8*)(qr + 32 + lk);
  }

  float m_prev[4], l_run[4];
  f32x4 acc_o[4];
  #pragma unroll
  for (int r=0;r<4;r++){ m_prev[r]=-1e30f; l_run[r]=0.f; }
  #pragma unroll
  for (int ni=0;ni<4;ni++) acc_o[ni]=(f32x4){0.f,0.f,0.f,0.f};

  int srow = tid>>3, sch = tid&7;   // 512 threads: rows 0..63, one 16B chunk each

  i32x4 kr0 = *(const i32x4*)(Kp + (long)srow*ldk + sch*8);
  i32x4 vr0 = *(const i32x4*)(Vp + (long)srow*SLEN + sch*8);

  for (int t=0; t<NT; ++t){
    __syncthreads();
    *(i32x4*)&K_lds[srow][sch*8] = kr0;
    *(i32x4*)&V_lds[srow][sch*8] = vr0;
    __syncthreads();

    int tn = (t+1 < NT) ? t+1 : t;
    int k0n = tn*64;
    kr0 = *(const i32x4*)(Kp + (long)(k0n+srow)*ldk + sch*8);
    vr0 = *(const i32x4*)(Vp + (long)srow*SLEN + k0n + sch*8);

    // S = Q @ K^T
    f32x4 s[4];
    #pragma unroll
    for (int ni=0;ni<4;ni++) s[ni]=(f32x4){0.f,0.f,0.f,0.f};
    __builtin_amdgcn_s_setprio(1);
    #pragma unroll
    for (int ki=0;ki<2;ki++){
      #pragma unroll
      for (int ni=0;ni<4;ni++){
        bf16x8 kf = *(const bf16x8*)&K_lds[ni*16+lr][ki*32+lk];
        s[ni] = __builtin_amdgcn_mfma_f32_16x16x32_bf16(qf[ki], kf, s[ni],0,0,0);
      }
    }
    __builtin_amdgcn_s_setprio(0);
    // online softmax with rescale-skip
    float tmax[4];
    #pragma unroll
    for (int r=0;r<4;r++){
      tmax[r] = fmaxf(fmaxf(s[0][r],s[1][r]),fmaxf(s[2][r],s[3][r]));
      #pragma unroll
      for (int msk=1; msk<16; msk<<=1) tmax[r]=fmaxf(tmax[r], __shfl_xor(tmax[r],msk));
    }
    bool inc = (tmax[0]>m_prev[0])|(tmax[1]>m_prev[1])|(tmax[2]>m_prev[2])|(tmax[3]>m_prev[3]);
    if (__any(inc)){
      #pragma unroll
      for (int r=0;r<4;r++){
        float mnew = fmaxf(m_prev[r], tmax[r]);
        float corr = __expf(m_prev[r]-mnew);
        m_prev[r] = mnew;
        l_run[r] *= corr;
        #pragma unroll
        for (int ni=0;ni<4;ni++) acc_o[ni][r] *= corr;
      }
    }
    float rs[4] = {0.f,0.f,0.f,0.f};
    #pragma unroll
    for (int ni=0;ni<4;ni++){
      #pragma unroll
      for (int r=0;r<4;r++){
        float p = __expf(s[ni][r]-m_prev[r]);
        rs[r] += p;
        P_lds[wave][lg*4+r][ni*16+lr] = f2bf(p);
      }
    }
    #pragma unroll
    for (int r=0;r<4;r++){
      #pragma unroll
      for (int msk=1; msk<16; msk<<=1) rs[r] += __shfl_xor(rs[r],msk);
      l_run[r] += rs[r];
    }
    // O += P @ V   (P_lds wave-private)
    __builtin_amdgcn_s_setprio(1);
    #pragma unroll
    for (int ki=0;ki<2;ki++){
      bf16x8 pf = *(const bf16x8*)&P_lds[wave][lr][ki*32+lk];
      #pragma unroll
      for (int ni=0;ni<4;ni++){
        bf16x8 vf = *(const bf16x8*)&V_lds[ni*16+lr][ki*32+lk];
        acc_o[ni] = __builtin_amdgcn_mfma_f32_16x16x32_bf16(pf, vf, acc_o[ni],0,0,0);
      }
    }
    __builtin_amdgcn_s_setprio(0);
  }
  unsigned short* Op = Og + (long)slot*oSlot + (long)h*HD_;
  #pragma unroll
  for (int r=0;r<4;r++){
    float inv = 1.f/l_run[r];
    int q = qb*128 + wave*16 + lg*4 + r;
    #pragma unroll
    for (int ni=0;ni<4;ni++)
      Op[(long)q*ldo + ni*16 + lr] = f2bf(acc_o[ni][r]*inv);
  }
}

// ---------------- GEMM core (per-block body; dbuf LDS, chunk-XOR swizzle, 8 waves) ----------------
template<int BM, int BN, int WTM, int WTN, int BK>
static __device__ __forceinline__ void gemm_core(
    const unsigned short* __restrict__ Ap,   // pre-offset to bm0 row
    const unsigned short* __restrict__ Wp,   // pre-offset to bn0 row
    const float* __restrict__ bp,            // bias (or null)
    void* __restrict__ Cp, long cbase, int ldc,
    int lda, int ldw, int bm0, int bn0,
    int K, int f32out, int relu, int scaleNlim, float scaleVal,
    unsigned short* smem)
{
  constexpr int WAVES_N = BN/WTN;
  constexpr int MI = WTM/16, NI = WTN/16;
  constexpr int SLOTS = BK/8;
  int tid  = threadIdx.x;
  int wave = tid>>6, lane = tid&63;
  int wm = wave / WAVES_N, wn = wave % WAVES_N;
  int lr = lane&15;
  int lg = lane>>4;
  int swz = (BK==64) ? (lr&7) : ((lr>>1)&3);

  f32x4 acc[MI][NI];
  #pragma unroll
  for (int i=0;i<MI;i++)
  #pragma unroll
  for (int j=0;j<NI;j++) acc[i][j] = (f32x4){0.f,0.f,0.f,0.f};

  auto stage = [&](int buf, int k0){
    unsigned short* as = &smem[(size_t)buf*(BM+BN)*BK];
    unsigned short* bs = as + BM*BK;
    #pragma unroll
    for (int i=0;i<BM*SLOTS/512;i++){
      int cch = i*512 + tid;
      int row = cch / SLOTS, c = cch % SLOTS;
      int cs = (BK==64) ? (c ^ (row&7)) : (c ^ ((row>>1)&3));
      gload16(Ap + (long)row*lda + k0 + (cs<<3), as + cch*8);
    }
    #pragma unroll
    for (int i=0;i<BN*SLOTS/512;i++){
      int cch = i*512 + tid;
      int row = cch / SLOTS, c = cch % SLOTS;
      int cs = (BK==64) ? (c ^ (row&7)) : (c ^ ((row>>1)&3));
      gload16(Wp + (long)row*ldw + k0 + (cs<<3), bs + cch*8);
    }
  };

  auto compute = [&](int buf){
    unsigned short* as = &smem[(size_t)buf*(BM+BN)*BK];
    unsigned short* bs = as + BM*BK;
    #pragma unroll
    for (int ki=0;ki<BK/32;ki++){
      bf16x8 af[MI], bfr[NI];
      #pragma unroll
      for (int mi=0;mi<MI;mi++){
        int row = wm*WTM + mi*16 + lr;
        af[mi] = *(const bf16x8*)&as[row*BK + (((ki*4+lg) ^ swz)<<3)];
      }
      #pragma unroll
      for (int ni=0;ni<NI;ni++){
        int row = wn*WTN + ni*16 + lr;
        bfr[ni] = *(const bf16x8*)&bs[row*BK + (((ki*4+lg) ^ swz)<<3)];
      }
      __builtin_amdgcn_s_setprio(1);
      #pragma unroll
      for (int mi=0;mi<MI;mi++)
      #pragma unroll
      for (int ni=0;ni<NI;ni++)
        acc[mi][ni] = __builtin_amdgcn_mfma_f32_16x16x32_bf16(af[mi], bfr[ni], acc[mi][ni], 0,0,0);
      __builtin_amdgcn_s_setprio(0);
    }
  };

  int NT = K / BK;
  stage(0, 0);
  __syncthreads();
  int cur = 0;
  for (int t=0; t<NT; ++t){
    if (t+1 < NT) stage(cur^1, (t+1)*BK);
    compute(cur);
    __syncthreads();
    cur ^= 1;
  }

  int rbase = lg*4;
  #pragma unroll
  for (int mi=0;mi<MI;mi++)
  #pragma unroll
  for (int ni=0;ni<NI;ni++){
    f32x4 v = acc[mi][ni];
    int n = bn0 + wn*WTN + ni*16 + lr;
    float bv = bp ? bp[n] : 0.f;
    float scv = (n < scaleNlim) ? scaleVal : 1.f;
    #pragma unroll
    for (int r=0;r<4;r++){
      int m = bm0 + wm*WTM + mi*16 + rbase + r;
      float val = (v[r] + bv) * scv;
      if (relu) val = fmaxf(val, 0.f);
      long o = cbase + (long)m*ldc + n;
      if (f32out) ((float*)Cp)[o] = val;
      else ((unsigned short*)Cp)[o] = f2bf(val);
    }
  }
}

// ---------------- single GEMM  C = A @ W^T ----------------
template<int BM, int BN, int WTM, int WTN, int BK>
__global__ void __launch_bounds__(512) gemm_lds(
    const unsigned short* __restrict__ A, long aSlot, int aDiv, long aHead, int lda,
    const unsigned short* __restrict__ W, long wSlot, long wHead, long wExp, int ldw,
    const int* __restrict__ eidx, const float* __restrict__ bias, long biasExp,
    void* __restrict__ Cp, long cSlot, long cHead, int ldc,
    int K, int HZ, int f32out, int relu, int scaleNlim, float scaleVal)
{
  constexpr int SLOTS = BK/8;
  static_assert((BM/WTM)*(BN/WTN) == 8, "8 waves");
  static_assert((BM*SLOTS)%512==0 && (BN*SLOTS)%512==0, "stage coverage");
  __shared__ unsigned short smem[2*(BM+BN)*BK];

  int nwg = gridDim.x*gridDim.y*gridDim.z;
  int wg = xcd_swz(blockIdx.x + gridDim.x*(blockIdx.y + gridDim.y*blockIdx.z), nwg);
  int bx = wg % gridDim.x; int t1 = wg / gridDim.x;
  int by = t1 % gridDim.y; int z  = t1 / gridDim.y;

  int slot = z / HZ;
  int h = z - slot*HZ;
  int e = eidx ? eidx[slot] : 0;
  const unsigned short* Ap = A + (long)(slot/aDiv)*aSlot + (long)h*aHead + (long)by*BM*lda;
  const unsigned short* Wp = W + (long)slot*wSlot + (long)h*wHead + (long)e*wExp + (long)bx*BN*ldw;
  const float* bp = bias ? (bias + (long)e*biasExp) : nullptr;
  long cbase = (long)slot*cSlot + (long)h*cHead;

  gemm_core<BM,BN,WTM,WTN,BK>(Ap, Wp, bp, Cp, cbase, ldc, lda, ldw,
      by*BM, bx*BN, K, f32out, relu, scaleNlim, scaleVal, smem);
}

// ---------------- dual GEMM: QKV (set0) + CA-KV (set1) in one launch ----------------
// Both <128,256,64,64,32>; shared: lda=ldw=D_, wExp=3*D_*D_, biasExp=3*D_, K=512,
// aDiv=2, bf16 out, no relu. set0 scales first D_ cols by 0.125.
__global__ void __launch_bounds__(512) gemm_dual(
    const unsigned short* __restrict__ A0, long aSlot0,
    const unsigned short* __restrict__ W0, const float* __restrict__ bias0,
    unsigned short* __restrict__ C0, long cSlot0, int ldc0,
    const unsigned short* __restrict__ A1, long aSlot1,
    const unsigned short* __restrict__ W1, const float* __restrict__ bias1,
    unsigned short* __restrict__ C1, long cSlot1, int ldc1,
    const int* __restrict__ eidx)
{
  constexpr int BM=128, BN=256, WTM=64, WTN=64, BK=32;
  __shared__ unsigned short smem[2*(BM+BN)*BK];
  const int NBLK0 = 6*2*NSLOT;   // QKV: bx<6, by<2
  int nwg = gridDim.x;
  int wg = xcd_swz(blockIdx.x, nwg);

  const unsigned short *Ap, *Wp; const float* bp;
  unsigned short* Cp; long cbase; int ldc, bm0, bn0, scaleNlim;
  if (wg < NBLK0){
    int bx = wg % 6; int t1 = wg / 6;
    int by = t1 % 2; int slot = t1 / 2;
    int e = eidx[slot];
    bm0 = by*BM; bn0 = bx*BN;
    Ap = A0 + (long)(slot/2)*aSlot0 + (long)bm0*D_;
    Wp = W0 + (long)e*(3*D_*D_) + (long)bn0*D_;
    bp = bias0 + (long)e*(3*D_);
    Cp = C0; cbase = (long)slot*cSlot0; ldc = ldc0; scaleNlim = D_;
  } else {
    int w1 = wg - NBLK0;
    int bx = w1 % 4; int t1 = w1 / 4;
    int by = t1 % 4; int slot = t1 / 4;
    int e = eidx[slot];
    bm0 = by*BM; bn0 = bx*BN;
    Ap = A1 + (long)(slot/2)*aSlot1 + (long)bm0*D_;
    Wp = W1 + (long)e*(3*D_*D_) + (long)bn0*D_;
    bp = bias1 + (long)e*(3*D_);
    Cp = C1; cbase = (long)slot*cSlot1; ldc = ldc1; scaleNlim = 0;
  }
  gemm_core<BM,BN,WTM,WTN,BK>(Ap, Wp, bp, Cp, cbase, ldc, D_, D_,
      bm0, bn0, 512, 0, 0, scaleNlim, 0.125f, smem);
}

// ---------------- residual add + LayerNorm (vectorized; A fp32 or bf16; bf16 out) ----------------
template<int ABF>
__global__ void __launch_bounds__(256) add_ln_k(
    const void* __restrict__ Ab_, int aDiv, long aStride,
    const unsigned short* __restrict__ Bb, long bStride,
    const float* __restrict__ G, const float* __restrict__ Bt,
    const int* __restrict__ eidx,
    unsigned short* __restrict__ OutB)
{
  int row = blockIdx.x*4 + (threadIdx.x>>6);
  int slot = row>>8, t = row&255;
  int lane = threadIdx.x&63;
  int d0 = lane*8;
  float x[8];
  if (ABF){
    const unsigned short* a = (const unsigned short*)Ab_ + (long)(slot/aDiv)*aStride + (long)t*D_ + d0;
    ushort4 a0 = *(const ushort4*)a, a1 = *(const ushort4*)(a+4);
    x[0]=bf2f(a0.x); x[1]=bf2f(a0.y); x[2]=bf2f(a0.z); x[3]=bf2f(a0.w);
    x[4]=bf2f(a1.x); x[5]=bf2f(a1.y); x[6]=bf2f(a1.z); x[7]=bf2f(a1.w);
  } else {
    const float* a = (const float*)Ab_ + (long)(slot/aDiv)*aStride + (long)t*D_ + d0;
    float4 a0 = *(const float4*)a, a1 = *(const float4*)(a+4);
    x[0]=a0.x; x[1]=a0.y; x[2]=a0.z; x[3]=a0.w;
    x[4]=a1.x; x[5]=a1.y; x[6]=a1.z; x[7]=a1.w;
  }
  const unsigned short* b = Bb + (long)slot*bStride + (long)t*D_ + d0;
  ushort4 b0 = *(const ushort4*)b, b1 = *(const ushort4*)(b+4);
  x[0]+=bf2f(b0.x); x[1]+=bf2f(b0.y); x[2]+=bf2f(b0.z); x[3]+=bf2f(b0.w);
  x[4]+=bf2f(b1.x); x[5]+=bf2f(b1.y); x[6]+=bf2f(b1.z); x[7]+=bf2f(b1.w);
  float s=0.f;
  #pragma unroll
  for (int i=0;i<8;i++) s += x[i];
  #pragma unroll
  for (int o=32;o;o>>=1) s += __shfl_xor(s,o);
  float m = s*(1.f/D_);
  float q=0.f;
  #pragma unroll
  for (int i=0;i<8;i++){ float d=x[i]-m; q+=d*d; }
  #pragma unroll
  for (int o=32;o;o>>=1) q += __shfl_xor(q,o);
  float rs = rsqrtf(q*(1.f/D_)+1e-5f);
  int e = eidx[slot];
  const float* g  = G  + (long)e*D_ + d0;
  const float* bt = Bt + (long)e*D_ + d0;
  float4 g0 = *(const float4*)g, g1 = *(const float4*)(g+4);
  float4 t0 = *(const float4*)bt, t1 = *(const float4*)(bt+4);
  float gg[8] = {g0.x,g0.y,g0.z,g0.w,g1.x,g1.y,g1.z,g1.w};
  float tt[8] = {t0.x,t0.y,t0.z,t0.w,t1.x,t1.y,t1.z,t1.w};
  long ob = (long)slot*(T_*D_) + (long)t*D_ + d0;
  ushort4 o0, o1;
  float y0=(x[0]-m)*rs*gg[0]+tt[0], y1=(x[1]-m)*rs*gg[1]+tt[1];
  float y2=(x[2]-m)*rs*gg[2]+tt[2], y3=(x[3]-m)*rs*gg[3]+tt[3];
  float y4=(x[4]-m)*rs*gg[4]+tt[4], y5=(x[5]-m)*rs*gg[5]+tt[5];
  float y6=(x[6]-m)*rs*gg[6]+tt[6], y7=(x[7]-m)*rs*gg[7]+tt[7];
  o0.x=f2bf(y0); o0.y=f2bf(y1); o0.z=f2bf(y2); o0.w=f2bf(y3);
  o1.x=f2bf(y4); o1.y=f2bf(y5); o1.z=f2bf(y6); o1.w=f2bf(y7);
  *(ushort4*)(OutB+ob) = o0;
  *(ushort4*)(OutB+ob+4) = o1;
}

// ---------------- residual add + LayerNorm (n3) + weighted slot combine (bf16 in) ----------------
__global__ void __launch_bounds__(256) add_ln_comb_k(
    const unsigned short* __restrict__ x2b, const unsigned short* __restrict__ proj,
    const float* __restrict__ G, const float* __restrict__ Bt,
    const int* __restrict__ eidx, const float* __restrict__ wgt,
    float* __restrict__ dstF, unsigned short* __restrict__ dstB)
{
  int row = blockIdx.x*4 + (threadIdx.x>>6);   // b*256+t
  int b = row>>8, t = row&255;
  int lane = threadIdx.x&63;
  int d0 = lane*8;
  float out[8];
  #pragma unroll
  for (int i=0;i<8;i++) out[i]=0.f;
  #pragma unroll
  for (int s2i=0;s2i<2;s2i++){
    int slot = 2*b + s2i;
    int e = eidx[slot];
    float w = wgt[slot];
    const unsigned short* a = x2b + (long)slot*(T_*D_) + (long)t*D_ + d0;
    const unsigned short* p = proj + (long)slot*(T_*D_) + (long)t*D_ + d0;
    ushort4 a0 = *(const ushort4*)a, a1 = *(const ushort4*)(a+4);
    ushort4 p0 = *(const ushort4*)p, p1 = *(const ushort4*)(p+4);
    float x[8];
    x[0]=bf2f(a0.x)+bf2f(p0.x); x[1]=bf2f(a0.y)+bf2f(p0.y);
    x[2]=bf2f(a0.z)+bf2f(p0.z); x[3]=bf2f(a0.w)+bf2f(p0.w);
    x[4]=bf2f(a1.x)+bf2f(p1.x); x[5]=bf2f(a1.y)+bf2f(p1.y);
    x[6]=bf2f(a1.z)+bf2f(p1.z); x[7]=bf2f(a1.w)+bf2f(p1.w);
    float s=0.f;
    #pragma unroll
    for (int i=0;i<8;i++) s += x[i];
    #pragma unroll
    for (int o=32;o;o>>=1) s += __shfl_xor(s,o);
    float m = s*(1.f/D_);
    float q=0.f;
    #pragma unroll
    for (int i=0;i<8;i++){ float d=x[i]-m; q+=d*d; }
    #pragma unroll
    for (int o=32;o;o>>=1) q += __shfl_xor(q,o);
    float rs = rsqrtf(q*(1.f/D_)+1e-5f);
    const float* g  = G  + (long)e*D_ + d0;
    const float* bt = Bt + (long)e*D_ + d0;
    float4 g0 = *(const float4*)g, g1 = *(const float4*)(g+4);
    float4 t0 = *(const float4*)bt, t1 = *(const float4*)(bt+4);
    float gg[8] = {g0.x,g0.y,g0.z,g0.w,g1.x,g1.y,g1.z,g1.w};
    float tt[8] = {t0.x,t0.y,t0.z,t0.w,t1.x,t1.y,t1.z,t1.w};
    #pragma unroll
    for (int i=0;i<8;i++) out[i] += w*((x[i]-m)*rs*gg[i]+tt[i]);
  }
  long ob = (long)row*D_ + d0;
  float4 f0 = {out[0],out[1],out[2],out[3]};
  float4 f1 = {out[4],out[5],out[6],out[7]};
  *(float4*)(dstF+ob) = f0;
  *(float4*)(dstF+ob+4) = f1;
  ushort4 o0, o1;
  o0.x=f2bf(out[0]); o0.y=f2bf(out[1]); o0.z=f2bf(out[2]); o0.w=f2bf(out[3]);
  o1.x=f2bf(out[4]); o1.y=f2bf(out[5]); o1.z=f2bf(out[6]); o1.w=f2bf(out[7]);
  *(ushort4*)(dstB+ob) = o0;
  *(ushort4*)(dstB+ob+4) = o1;
}

extern "C" void kernel_launch(void* const* d_in, const int* in_sizes, int n_in,
                              void* d_out, int out_size, void* d_ws, size_t ws_size,
                              hipStream_t stream)
{
  const float* tgt      = (const float*)d_in[0];
  const float* memory   = (const float*)d_in[1];
  const float* router_w = (const float*)d_in[2];
  const float* sa_in_w  = (const float*)d_in[3];
  const float* sa_in_b  = (const float*)d_in[4];
  const float* sa_out_w = (const float*)d_in[5];
  const float* sa_out_b = (const float*)d_in[6];
  const float* ca_in_w  = (const float*)d_in[7];
  const float* ca_in_b  = (const float*)d_in[8];
  const float* ca_out_w = (const float*)d_in[9];
  const float* ca_out_b = (const float*)d_in[10];
  const float* lin1_w   = (const float*)d_in[11];
  const float* lin1_b   = (const float*)d_in[12];
  const float* lin2_w   = (const float*)d_in[13];
  const float* lin2_b   = (const float*)d_in[14];
  const float* n1_g = (const float*)d_in[15];
  const float* n1_b = (const float*)d_in[16];
  const float* n2_g = (const float*)d_in[17];
  const float* n2_b = (const float*)d_in[18];
  const float* n3_g = (const float*)d_in[19];
  const float* n3_b = (const float*)d_in[20];

  char* ws = (char*)d_ws;
  size_t off = 0;
  auto alloc = [&](size_t bytes)->char*{
    char* p = ws + off; off += (bytes + 255) & ~(size_t)255; return p;
  };
  unsigned short* xb    = (unsigned short*)alloc(2ull*B_*T_*D_);
  unsigned short* memb  = (unsigned short*)alloc(2ull*B_*S_*D_);
  float*          x     = (float*)alloc(4ull*B_*T_*D_);
  float*          part  = (float*)alloc(4ull*B_*8*D_);
  int*            eidx  = (int*)alloc(4ull*NSLOT);
  float*          wgt   = (float*)alloc(4ull*NSLOT);
  unsigned short* wSaIn  = (unsigned short*)alloc(2ull*E_*3*D_*D_);
  unsigned short* wSaOut = (unsigned short*)alloc(2ull*E_*D_*D_);
  unsigned short* wCaIn  = (unsigned short*)alloc(2ull*E_*3*D_*D_);
  unsigned short* wCaOut = (unsigned short*)alloc(2ull*E_*D_*D_);
  unsigned short* wL1    = (unsigned short*)alloc(2ull*E_*DFF_*D_);
  unsigned short* wL2    = (unsigned short*)alloc(2ull*E_*D_*DFF_);
  unsigned short* qkv   = (unsigned short*)alloc(2ull*NSLOT*T_*3*D_);
  unsigned short* ffh   = (unsigned short*)alloc(2ull*NSLOT*T_*DFF_);
  unsigned short* attn  = (unsigned short*)alloc(2ull*NSLOT*T_*D_);
  unsigned short* proj  = (unsigned short*)alloc(2ull*NSLOT*T_*D_);
  unsigned short* x1b   = (unsigned short*)alloc(2ull*NSLOT*T_*D_);
  unsigned short* cq    = (unsigned short*)alloc(2ull*NSLOT*T_*D_);
  unsigned short* mkv   = (unsigned short*)alloc(2ull*NSLOT*S_*2*D_);
  unsigned short* x2b   = (unsigned short*)alloc(2ull*NSLOT*T_*D_);
  unsigned short* Vt2   = (unsigned short*)alloc(2ull*NSLOT*H_*HD_*S_);
  unsigned short* Vt1   = cq;   // alias: [slot][h][64][T]; cq written after fattn-self consumed Vt1

  cast_bf16_k<<<1024,256,0,stream>>>(tgt,    xb,   (long)B_*T_*D_);
  cast_bf16_k<<<1024,256,0,stream>>>(memory, memb, (long)B_*S_*D_);

  const float* xcur = tgt;
  for (int l=0; l<L_; ++l){
    pool_k<<<B_*8,256,0,stream>>>(xcur, part);
    route2_k<<<B_,256,0,stream>>>(part, router_w + (size_t)l*E_*D_, eidx, wgt);
    cast_weights_k<<<2048,256,0,stream>>>(
      sa_in_w  + (size_t)l*E_*3*D_*D_, sa_out_w + (size_t)l*E_*D_*D_,
      ca_in_w  + (size_t)l*E_*3*D_*D_, ca_out_w + (size_t)l*E_*D_*D_,
      lin1_w   + (size_t)l*E_*DFF_*D_, lin2_w   + (size_t)l*E_*D_*DFF_,
      wSaIn, wSaOut, wCaIn, wCaOut, wL1, wL2);

    // fused QKV (set0) + cross-attn K,V (set1)
    gemm_dual<<<dim3(6*2*NSLOT + 4*4*NSLOT),512,0,stream>>>(
      xb,   (long)T_*D_, wSaIn,                sa_in_b + (size_t)l*E_*3*D_,
      qkv,  (long)T_*3*D_, 3*D_,
      memb, (long)S_*D_, wCaIn + (size_t)D_*D_, ca_in_b + (size_t)l*E_*3*D_ + D_,
      mkv,  (long)S_*2*D_, 2*D_,
      eidx);
    // dual V transpose: Vt1 from qkv-V, Vt2 from mkv-V
    vtrans2_k<<<dim3(T_/64 + S_/64, H_, NSLOT),256,0,stream>>>(
      qkv + 2*D_, (long)T_*3*D_, 3*D_, Vt1, T_,
      mkv + D_,   (long)S_*2*D_, 2*D_, Vt2, S_);
    // fused self-attention (128 q-rows / block)
    fattn_k<4><<<dim3(T_/128, NSLOT*H_),512,0,stream>>>(
      qkv, (long)T_*3*D_, 3*D_,
      qkv + D_, (long)T_*3*D_, 3*D_,
      Vt1, attn, (long)T_*D_, D_);
    // self-attn out proj (bf16 out)
    gemm_lds<64,128,32,32,64><<<dim3(4,4,NSLOT),512,0,stream>>>(
      attn, (long)T_*D_, 1, 0, D_,
      wSaOut, 0, 0, (long)D_*D_, D_,
      eidx, sa_out_b + (size_t)l*E_*D_, D_,
      proj, (long)T_*D_, 0, D_,
      512, 1, 0, 0, 0, 1.f);
    add_ln_k<0><<<2048,256,0,stream>>>(xcur, 2, (long)T_*D_, proj, (long)T_*D_,
      n1_g + (size_t)l*E_*D_, n1_b + (size_t)l*E_*D_, eidx, x1b);
    // cross-attn Q (scaled)
    gemm_lds<64,128,32,32,64><<<dim3(4,4,NSLOT),512,0,stream>>>(
      x1b, (long)T_*D_, 1, 0, D_,
      wCaIn, 0, 0, (long)3*D_*D_, D_,
      eidx, ca_in_b + (size_t)l*E_*3*D_, 3*D_,
      cq, (long)T_*D_, 0, D_,
      512, 1, 0, 0, D_, 0.125f);
    // fused cross-attention (128 q-rows / block)
    fattn_k<8><<<dim3(T_/128, NSLOT*H_),512,0,stream>>>(
      cq, (long)T_*D_, D_,
      mkv, (long)S_*2*D_, 2*D_,
      Vt2, attn, (long)T_*D_, D_);
    // cross-attn out proj (bf16 out)
    gemm_lds<64,128,32,32,64><<<dim3(4,4,NSLOT),512,0,stream>>>(
      attn, (long)T_*D_, 1, 0, D_,
      wCaOut, 0, 0, (long)D_*D_, D_,
      eidx, ca_out_b + (size_t)l*E_*D_, D_,
      proj, (long)T_*D_, 0, D_,
      512, 1, 0, 0, 0, 1.f);
    add_ln_k<1><<<2048,256,0,stream>>>(x1b, 1, (long)T_*D_, proj, (long)T_*D_,
      n2_g + (size_t)l*E_*D_, n2_b + (size_t)l*E_*D_, eidx, x2b);
    // FFN1 (+relu)
    gemm_lds<128,256,64,64,32><<<dim3(8,2,NSLOT),512,0,stream>>>(
      x2b, (long)T_*D_, 1, 0, D_,
      wL1, 0, 0, (long)DFF_*D_, D_,
      eidx, lin1_b + (size_t)l*E_*DFF_, DFF_,
      ffh, (long)T_*DFF_, 0, DFF_,
      512, 1, 0, 1, 0, 1.f);
    // FFN2 (bf16 out)
    gemm_lds<64,128,32,32,64><<<dim3(4,4,NSLOT),512,0,stream>>>(
      ffh, (long)T_*DFF_, 1, 0, DFF_,
      wL2, 0, 0, (long)D_*DFF_, DFF_,
      eidx, lin2_b + (size_t)l*E_*D_, D_,
      proj, (long)T_*D_, 0, D_,
      2048, 1, 0, 0, 0, 1.f);
    // n3 LN + weighted combine
    float* dstF = (l==L_-1) ? (float*)d_out : x;
    add_ln_comb_k<<<1024,256,0,stream>>>(x2b, proj,
      n3_g + (size_t)l*E_*D_, n3_b + (size_t)l*E_*D_, eidx, wgt, dstF, xb);
    xcur = x;
  }
}

// Round 15
// 930.502 us; speedup vs baseline: 1.2198x; 1.0038x over previous
//
#include <hip/hip_runtime.h>
#include <hip/hip_bf16.h>

#define L_ 4
#define E_ 4
#define D_ 512
#define DFF_ 2048
#define H_ 8
#define B_ 16
#define T_ 256
#define S_ 512
#define HD_ 64
#define NSLOT 32   // B * K

typedef __attribute__((ext_vector_type(4))) float f32x4;
typedef __attribute__((ext_vector_type(8))) short bf16x8;
typedef __attribute__((ext_vector_type(4))) int i32x4;

static __device__ __forceinline__ float bf2f(unsigned short u){
  union{float f; unsigned u;} c; c.u = ((unsigned)u)<<16; return c.f;
}
static __device__ __forceinline__ unsigned short f2bf(float f){
  union{float f; unsigned u;} c; c.f=f;
  unsigned u=c.u;
  return (unsigned short)((u + 0x7FFFu + ((u>>16)&1u))>>16);
}

static __device__ __forceinline__ void gload16(const unsigned short* g, unsigned short* l){
  __builtin_amdgcn_global_load_lds(
      (const __attribute__((address_space(1))) void*)g,
      (__attribute__((address_space(3))) void*)l, 16, 0, 0);
}

// bijective XCD-chunked block remap (m204)
static __device__ __forceinline__ int xcd_swz(int orig, int nwg){
  int q = nwg >> 3, r = nwg & 7;
  int xcd = orig & 7, idx = orig >> 3;
  return (xcd < r) ? (xcd*(q+1) + idx) : (r*(q+1) + (xcd-r)*q + idx);
}

// ---------------- routing: stage 1 — chunked pooled partial sums (deterministic) ----------------
__global__ void __launch_bounds__(256) pool_k(const float* __restrict__ x,
    float* __restrict__ part)
{
  int b = blockIdx.x >> 3, ch = blockIdx.x & 7;
  int tid = threadIdx.x;
  const float* xp = x + ((long)b*T_ + ch*32)*D_ + tid*2;
  float s0=0.f, s1=0.f;
  #pragma unroll 8
  for (int t=0;t<32;t++){
    float2 v = *(const float2*)(xp + (long)t*D_);
    s0 += v.x; s1 += v.y;
  }
  float* pp = part + ((long)b*8 + ch)*D_ + tid*2;
  pp[0]=s0; pp[1]=s1;
}

// ---------------- routing: stage 2 — combine partials, logits, top-2 ----------------
__global__ void __launch_bounds__(256) route2_k(const float* __restrict__ part,
    const float* __restrict__ rw, int* __restrict__ eidx, float* __restrict__ wgt)
{
  __shared__ float pooled[D_];
  __shared__ float logit[E_];
  int b = blockIdx.x, tid = threadIdx.x;
  for (int d = tid; d < D_; d += 256){
    float s = 0.f;
    #pragma unroll
    for (int c=0;c<8;c++) s += part[((long)b*8 + c)*D_ + d];
    pooled[d] = s * (1.f/T_);
  }
  __syncthreads();
  int wave = tid>>6, lane = tid&63;
  {
    float s=0.f;
    const float* w = rw + (long)wave*D_;
    for (int d=lane; d<D_; d+=64) s += pooled[d]*w[d];
    #pragma unroll
    for (int o=32;o;o>>=1) s += __shfl_xor(s,o);
    if (lane==0) logit[wave] = s;
  }
  __syncthreads();
  if (tid==0){
    int i1=0; float v1=logit[0];
    for (int e=1;e<E_;e++) if (logit[e] > v1){ v1=logit[e]; i1=e; }
    int i2=-1; float v2=-3.4e38f;
    for (int e=0;e<E_;e++) if (e!=i1 && logit[e] > v2){ v2=logit[e]; i2=e; }
    float e2 = __expf(v2 - v1);
    float w1 = 1.f/(1.f+e2);
    eidx[2*b]=i1; eidx[2*b+1]=i2;
    wgt[2*b]=w1; wgt[2*b+1]=e2*w1;
  }
}

// ---------------- casts ----------------
__global__ void __launch_bounds__(256) cast_bf16_k(const float* __restrict__ in,
    unsigned short* __restrict__ out, long n){
  long i = ((long)blockIdx.x*blockDim.x + threadIdx.x)*4;
  long st = (long)gridDim.x*blockDim.x*4;
  for (; i<n; i+=st){
    float4 v = *(const float4*)(in+i);
    ushort4 o; o.x=f2bf(v.x); o.y=f2bf(v.y); o.z=f2bf(v.z); o.w=f2bf(v.w);
    *(ushort4*)(out+i) = o;
  }
}

// fused per-layer weight cast (6 segments)
__global__ void __launch_bounds__(256) cast_weights_k(
    const float* __restrict__ s0, const float* __restrict__ s1,
    const float* __restrict__ s2, const float* __restrict__ s3,
    const float* __restrict__ s4, const float* __restrict__ s5,
    unsigned short* __restrict__ d0, unsigned short* __restrict__ d1,
    unsigned short* __restrict__ d2, unsigned short* __restrict__ d3,
    unsigned short* __restrict__ d4, unsigned short* __restrict__ d5)
{
  const long N0=(long)E_*3*D_*D_, N1=(long)E_*D_*D_;
  const long N2=N0, N3=N1, N4=(long)E_*DFF_*D_, N5=N4;
  const long total = N0+N1+N2+N3+N4+N5;
  long i = ((long)blockIdx.x*256 + threadIdx.x)*4;
  long st = (long)gridDim.x*256*4;
  for (; i<total; i+=st){
    const float* s; unsigned short* d; long j = i;
    if (j < N0){ s=s0; d=d0; }
    else if ((j-=N0) < N1){ s=s1; d=d1; }
    else if ((j-=N1) < N2){ s=s2; d=d2; }
    else if ((j-=N2) < N3){ s=s3; d=d3; }
    else if ((j-=N3) < N4){ s=s4; d=d4; }
    else { j-=N4; s=s5; d=d5; }
    float4 v = *(const float4*)(s+j);
    ushort4 o; o.x=f2bf(v.x); o.y=f2bf(v.y); o.z=f2bf(v.z); o.w=f2bf(v.w);
    *(ushort4*)(d+j) = o;
  }
}

// ---------------- dual V transpose (Vt1 from qkv-V, Vt2 from mkv-V) ----------------
__global__ void __launch_bounds__(256) vtrans2_k(
    const unsigned short* __restrict__ src0, long sSlot0, int ld0,
    unsigned short* __restrict__ dst0, int rows0,
    const unsigned short* __restrict__ src1, long sSlot1, int ld1,
    unsigned short* __restrict__ dst1, int rows1)
{
  __shared__ unsigned short t[64][68];
  int xb = blockIdx.x;
  const unsigned short* src; long sSlot; int ld; unsigned short* dst; int rows; int s0;
  if (xb < rows0/64){ src=src0; sSlot=sSlot0; ld=ld0; dst=dst0; rows=rows0; s0=xb*64; }
  else              { src=src1; sSlot=sSlot1; ld=ld1; dst=dst1; rows=rows1; s0=(xb-rows0/64)*64; }
  int h = blockIdx.y; int slot = blockIdx.z;
  const unsigned short* sp = src + (long)slot*sSlot + (long)h*64;
  int c = threadIdx.x&63, w = threadIdx.x>>6;
  #pragma unroll
  for (int i=0;i<16;i++){
    int r = i*4 + w;
    t[r][c] = sp[(long)(s0+r)*ld + c];
  }
  __syncthreads();
  unsigned short* dp = dst + ((long)slot*H_ + h)*((long)64*rows) + s0;
  #pragma unroll
  for (int i=0;i<16;i++){
    int d = i*4 + w;
    dp[(long)d*rows + c] = t[c][d];
  }
}

// ---------------- fused flash attention (128 q-rows, 8 waves, 128-k tile-pairs) ----------------
template<int NT>   // 64-k tiles: 4 (self) or 8 (cross); processed as NT/2 pairs
__global__ void __launch_bounds__(512) fattn_k(
    const unsigned short* __restrict__ Qg, long qSlot, int ldq,
    const unsigned short* __restrict__ Kg, long kSlot, int ldk,
    const unsigned short* __restrict__ Vtg,
    unsigned short* __restrict__ Og, long oSlot, int ldo)
{
  constexpr int SLEN = NT*64;
  constexpr int NT2 = NT/2;
  __shared__ unsigned short K_lds[128][72];
  __shared__ unsigned short V_lds[64][136];
  __shared__ unsigned short P_lds[8][16][72];

  int nwg = gridDim.x*gridDim.y;
  int wg = xcd_swz(blockIdx.x + gridDim.x*blockIdx.y, nwg);
  int qb = wg % gridDim.x;
  int z  = wg / gridDim.x;        // slot*H + h
  int slot = z >> 3, h = z & 7;
  int tid = threadIdx.x, wave = tid>>6, lane = tid&63;
  int lr = lane&15, lg = lane>>4;
  int lk = lg*8;

  const unsigned short* Qp = Qg + (long)slot*qSlot + (long)h*HD_;
  const unsigned short* Kp = Kg + (long)slot*kSlot + (long)h*HD_;
  const unsigned short* Vp = Vtg + (long)z*((long)HD_*SLEN);

  bf16x8 qf[2];
  {
    int qrow = qb*128 + wave*16 + lr;
    const unsigned short* qr = Qp + (long)qrow*ldq;
    qf[0] = *(const bf16x8*)(qr + lk);
    qf[1] = *(const bf16x8*)(qr + 32 + lk);
  }

  float m_prev[4], l_run[4];
  f32x4 acc_o[4];
  #pragma unroll
  for (int r=0;r<4;r++){ m_prev[r]=-1e30f; l_run[r]=0.f; }
  #pragma unroll
  for (int ni=0;ni<4;ni++) acc_o[ni]=(f32x4){0.f,0.f,0.f,0.f};

  int srow = tid>>3, sch = tid&7;   // K: rows srow, srow+64; V: row srow, chunks sch, sch+8

  // prologue: load pair 0
  i32x4 kr0 = *(const i32x4*)(Kp + (long)srow*ldk + sch*8);
  i32x4 kr1 = *(const i32x4*)(Kp + (long)(srow+64)*ldk + sch*8);
  i32x4 vr0 = *(const i32x4*)(Vp + (long)srow*SLEN + sch*8);
  i32x4 vr1 = *(const i32x4*)(Vp + (long)srow*SLEN + 64 + sch*8);

  for (int it=0; it<NT2; ++it){
    __syncthreads();   // all waves done reading prev pair's LDS
    *(i32x4*)&K_lds[srow][sch*8] = kr0;
    *(i32x4*)&K_lds[srow+64][sch*8] = kr1;
    *(i32x4*)&V_lds[srow][sch*8] = vr0;
    *(i32x4*)&V_lds[srow][64 + sch*8] = vr1;
    __syncthreads();

    // issue next pair's loads NOW; they complete under the compute below
    int itn = (it+1 < NT2) ? it+1 : it;
    int k0n = itn*128;
    kr0 = *(const i32x4*)(Kp + (long)(k0n+srow)*ldk + sch*8);
    kr1 = *(const i32x4*)(Kp + (long)(k0n+srow+64)*ldk + sch*8);
    vr0 = *(const i32x4*)(Vp + (long)srow*SLEN + k0n + sch*8);
    vr1 = *(const i32x4*)(Vp + (long)srow*SLEN + k0n + 64 + sch*8);

    #pragma unroll
    for (int sub=0; sub<2; ++sub){
      // S = Q @ K^T  (sub-tile of 64 k)
      f32x4 s[4];
      #pragma unroll
      for (int ni=0;ni<4;ni++) s[ni]=(f32x4){0.f,0.f,0.f,0.f};
      __builtin_amdgcn_s_setprio(1);
      #pragma unroll
      for (int ki=0;ki<2;ki++){
        #pragma unroll
        for (int ni=0;ni<4;ni++){
          bf16x8 kf = *(const bf16x8*)&K_lds[sub*64 + ni*16+lr][ki*32+lk];
          s[ni] = __builtin_amdgcn_mfma_f32_16x16x32_bf16(qf[ki], kf, s[ni],0,0,0);
        }
      }
      __builtin_amdgcn_s_setprio(0);
      // online softmax with rescale-skip
      float tmax[4];
      #pragma unroll
      for (int r=0;r<4;r++){
        tmax[r] = fmaxf(fmaxf(s[0][r],s[1][r]),fmaxf(s[2][r],s[3][r]));
        #pragma unroll
        for (int msk=1; msk<16; msk<<=1) tmax[r]=fmaxf(tmax[r], __shfl_xor(tmax[r],msk));
      }
      bool inc = (tmax[0]>m_prev[0])|(tmax[1]>m_prev[1])|(tmax[2]>m_prev[2])|(tmax[3]>m_prev[3]);
      if (__any(inc)){
        #pragma unroll
        for (int r=0;r<4;r++){
          float mnew = fmaxf(m_prev[r], tmax[r]);
          float corr = __expf(m_prev[r]-mnew);
          m_prev[r] = mnew;
          l_run[r] *= corr;
          #pragma unroll
          for (int ni=0;ni<4;ni++) acc_o[ni][r] *= corr;
        }
      }
      float rs[4] = {0.f,0.f,0.f,0.f};
      #pragma unroll
      for (int ni=0;ni<4;ni++){
        #pragma unroll
        for (int r=0;r<4;r++){
          float p = __expf(s[ni][r]-m_prev[r]);
          rs[r] += p;
          P_lds[wave][lg*4+r][ni*16+lr] = f2bf(p);
        }
      }
      #pragma unroll
      for (int r=0;r<4;r++){
        #pragma unroll
        for (int msk=1; msk<16; msk<<=1) rs[r] += __shfl_xor(rs[r],msk);
        l_run[r] += rs[r];
      }
      // O += P @ V   (P_lds wave-private; V sub-tile cols)
      __builtin_amdgcn_s_setprio(1);
      #pragma unroll
      for (int ki=0;ki<2;ki++){
        bf16x8 pf = *(const bf16x8*)&P_lds[wave][lr][ki*32+lk];
        #pragma unroll
        for (int ni=0;ni<4;ni++){
          bf16x8 vf = *(const bf16x8*)&V_lds[ni*16+lr][sub*64 + ki*32+lk];
          acc_o[ni] = __builtin_amdgcn_mfma_f32_16x16x32_bf16(pf, vf, acc_o[ni],0,0,0);
        }
      }
      __builtin_amdgcn_s_setprio(0);
    }
  }
  unsigned short* Op = Og + (long)slot*oSlot + (long)h*HD_;
  #pragma unroll
  for (int r=0;r<4;r++){
    float inv = 1.f/l_run[r];
    int q = qb*128 + wave*16 + lg*4 + r;
    #pragma unroll
    for (int ni=0;ni<4;ni++)
      Op[(long)q*ldo + ni*16 + lr] = f2bf(acc_o[ni][r]*inv);
  }
}

// ---------------- GEMM core (per-block body; dbuf LDS, chunk-XOR swizzle, 8 waves) ----------------
template<int BM, int BN, int WTM, int WTN, int BK>
static __device__ __forceinline__ void gemm_core(
    const unsigned short* __restrict__ Ap,
    const unsigned short* __restrict__ Wp,
    const float* __restrict__ bp,
    void* __restrict__ Cp, long cbase, int ldc,
    int lda, int ldw, int bm0, int bn0,
    int K, int f32out, int relu, int scaleNlim, float scaleVal,
    unsigned short* smem)
{
  constexpr int WAVES_N = BN/WTN;
  constexpr int MI = WTM/16, NI = WTN/16;
  constexpr int SLOTS = BK/8;
  int tid  = threadIdx.x;
  int wave = tid>>6, lane = tid&63;
  int wm = wave / WAVES_N, wn = wave % WAVES_N;
  int lr = lane&15;
  int lg = lane>>4;
  int swz = (BK==64) ? (lr&7) : ((lr>>1)&3);

  f32x4 acc[MI][NI];
  #pragma unroll
  for (int i=0;i<MI;i++)
  #pragma unroll
  for (int j=0;j<NI;j++) acc[i][j] = (f32x4){0.f,0.f,0.f,0.f};

  auto stage = [&](int buf, int k0){
    unsigned short* as = &smem[(size_t)buf*(BM+BN)*BK];
    unsigned short* bs = as + BM*BK;
    #pragma unroll
    for (int i=0;i<BM*SLOTS/512;i++){
      int cch = i*512 + tid;
      int row = cch / SLOTS, c = cch % SLOTS;
      int cs = (BK==64) ? (c ^ (row&7)) : (c ^ ((row>>1)&3));
      gload16(Ap + (long)row*lda + k0 + (cs<<3), as + cch*8);
    }
    #pragma unroll
    for (int i=0;i<BN*SLOTS/512;i++){
      int cch = i*512 + tid;
      int row = cch / SLOTS, c = cch % SLOTS;
      int cs = (BK==64) ? (c ^ (row&7)) : (c ^ ((row>>1)&3));
      gload16(Wp + (long)row*ldw + k0 + (cs<<3), bs + cch*8);
    }
  };

  auto compute = [&](int buf){
    unsigned short* as = &smem[(size_t)buf*(BM+BN)*BK];
    unsigned short* bs = as + BM*BK;
    #pragma unroll
    for (int ki=0;ki<BK/32;ki++){
      bf16x8 af[MI], bfr[NI];
      #pragma unroll
      for (int mi=0;mi<MI;mi++){
        int row = wm*WTM + mi*16 + lr;
        af[mi] = *(const bf16x8*)&as[row*BK + (((ki*4+lg) ^ swz)<<3)];
      }
      #pragma unroll
      for (int ni=0;ni<NI;ni++){
        int row = wn*WTN + ni*16 + lr;
        bfr[ni] = *(const bf16x8*)&bs[row*BK + (((ki*4+lg) ^ swz)<<3)];
      }
      __builtin_amdgcn_s_setprio(1);
      #pragma unroll
      for (int mi=0;mi<MI;mi++)
      #pragma unroll
      for (int ni=0;ni<NI;ni++)
        acc[mi][ni] = __builtin_amdgcn_mfma_f32_16x16x32_bf16(af[mi], bfr[ni], acc[mi][ni], 0,0,0);
      __builtin_amdgcn_s_setprio(0);
    }
  };

  int NT = K / BK;
  stage(0, 0);
  __syncthreads();
  int cur = 0;
  for (int t=0; t<NT; ++t){
    if (t+1 < NT) stage(cur^1, (t+1)*BK);
    compute(cur);
    __syncthreads();
    cur ^= 1;
  }

  int rbase = lg*4;
  #pragma unroll
  for (int mi=0;mi<MI;mi++)
  #pragma unroll
  for (int ni=0;ni<NI;ni++){
    f32x4 v = acc[mi][ni];
    int n = bn0 + wn*WTN + ni*16 + lr;
    float bv = bp ? bp[n] : 0.f;
    float scv = (n < scaleNlim) ? scaleVal : 1.f;
    #pragma unroll
    for (int r=0;r<4;r++){
      int m = bm0 + wm*WTM + mi*16 + rbase + r;
      float val = (v[r] + bv) * scv;
      if (relu) val = fmaxf(val, 0.f);
      long o = cbase + (long)m*ldc + n;
      if (f32out) ((float*)Cp)[o] = val;
      else ((unsigned short*)Cp)[o] = f2bf(val);
    }
  }
}

// ---------------- single GEMM  C = A @ W^T ----------------
template<int BM, int BN, int WTM, int WTN, int BK>
__global__ void __launch_bounds__(512) gemm_lds(
    const unsigned short* __restrict__ A, long aSlot, int aDiv, long aHead, int lda,
    const unsigned short* __restrict__ W, long wSlot, long wHead, long wExp, int ldw,
    const int* __restrict__ eidx, const float* __restrict__ bias, long biasExp,
    void* __restrict__ Cp, long cSlot, long cHead, int ldc,
    int K, int HZ, int f32out, int relu, int scaleNlim, float scaleVal)
{
  constexpr int SLOTS = BK/8;
  static_assert((BM/WTM)*(BN/WTN) == 8, "8 waves");
  static_assert((BM*SLOTS)%512==0 && (BN*SLOTS)%512==0, "stage coverage");
  __shared__ unsigned short smem[2*(BM+BN)*BK];

  int nwg = gridDim.x*gridDim.y*gridDim.z;
  int wg = xcd_swz(blockIdx.x + gridDim.x*(blockIdx.y + gridDim.y*blockIdx.z), nwg);
  int bx = wg % gridDim.x; int t1 = wg / gridDim.x;
  int by = t1 % gridDim.y; int z  = t1 / gridDim.y;

  int slot = z / HZ;
  int h = z - slot*HZ;
  int e = eidx ? eidx[slot] : 0;
  const unsigned short* Ap = A + (long)(slot/aDiv)*aSlot + (long)h*aHead + (long)by*BM*lda;
  const unsigned short* Wp = W + (long)slot*wSlot + (long)h*wHead + (long)e*wExp + (long)bx*BN*ldw;
  const float* bp = bias ? (bias + (long)e*biasExp) : nullptr;
  long cbase = (long)slot*cSlot + (long)h*cHead;

  gemm_core<BM,BN,WTM,WTN,BK>(Ap, Wp, bp, Cp, cbase, ldc, lda, ldw,
      by*BM, bx*BN, K, f32out, relu, scaleNlim, scaleVal, smem);
}

// ---------------- dual GEMM: QKV (set0) + CA-KV (set1) in one launch ----------------
__global__ void __launch_bounds__(512) gemm_dual(
    const unsigned short* __restrict__ A0, long aSlot0,
    const unsigned short* __restrict__ W0, const float* __restrict__ bias0,
    unsigned short* __restrict__ C0, long cSlot0, int ldc0,
    const unsigned short* __restrict__ A1, long aSlot1,
    const unsigned short* __restrict__ W1, const float* __restrict__ bias1,
    unsigned short* __restrict__ C1, long cSlot1, int ldc1,
    const int* __restrict__ eidx)
{
  constexpr int BM=128, BN=256, WTM=64, WTN=64, BK=32;
  __shared__ unsigned short smem[2*(BM+BN)*BK];
  const int NBLK0 = 6*2*NSLOT;   // QKV: bx<6, by<2
  int nwg = gridDim.x;
  int wg = xcd_swz(blockIdx.x, nwg);

  const unsigned short *Ap, *Wp; const float* bp;
  unsigned short* Cp; long cbase; int ldc, bm0, bn0, scaleNlim;
  if (wg < NBLK0){
    int bx = wg % 6; int t1 = wg / 6;
    int by = t1 % 2; int slot = t1 / 2;
    int e = eidx[slot];
    bm0 = by*BM; bn0 = bx*BN;
    Ap = A0 + (long)(slot/2)*aSlot0 + (long)bm0*D_;
    Wp = W0 + (long)e*(3*D_*D_) + (long)bn0*D_;
    bp = bias0 + (long)e*(3*D_);
    Cp = C0; cbase = (long)slot*cSlot0; ldc = ldc0; scaleNlim = D_;
  } else {
    int w1 = wg - NBLK0;
    int bx = w1 % 4; int t1 = w1 / 4;
    int by = t1 % 4; int slot = t1 / 4;
    int e = eidx[slot];
    bm0 = by*BM; bn0 = bx*BN;
    Ap = A1 + (long)(slot/2)*aSlot1 + (long)bm0*D_;
    Wp = W1 + (long)e*(3*D_*D_) + (long)bn0*D_;
    bp = bias1 + (long)e*(3*D_);
    Cp = C1; cbase = (long)slot*cSlot1; ldc = ldc1; scaleNlim = 0;
  }
  gemm_core<BM,BN,WTM,WTN,BK>(Ap, Wp, bp, Cp, cbase, ldc, D_, D_,
      bm0, bn0, 512, 0, 0, scaleNlim, 0.125f, smem);
}

// ---------------- residual add + LayerNorm (vectorized; A fp32 or bf16; bf16 out) ----------------
template<int ABF>
__global__ void __launch_bounds__(256) add_ln_k(
    const void* __restrict__ Ab_, int aDiv, long aStride,
    const unsigned short* __restrict__ Bb, long bStride,
    const float* __restrict__ G, const float* __restrict__ Bt,
    const int* __restrict__ eidx,
    unsigned short* __restrict__ OutB)
{
  int row = blockIdx.x*4 + (threadIdx.x>>6);
  int slot = row>>8, t = row&255;
  int lane = threadIdx.x&63;
  int d0 = lane*8;
  float x[8];
  if (ABF){
    const unsigned short* a = (const unsigned short*)Ab_ + (long)(slot/aDiv)*aStride + (long)t*D_ + d0;
    ushort4 a0 = *(const ushort4*)a, a1 = *(const ushort4*)(a+4);
    x[0]=bf2f(a0.x); x[1]=bf2f(a0.y); x[2]=bf2f(a0.z); x[3]=bf2f(a0.w);
    x[4]=bf2f(a1.x); x[5]=bf2f(a1.y); x[6]=bf2f(a1.z); x[7]=bf2f(a1.w);
  } else {
    const float* a = (const float*)Ab_ + (long)(slot/aDiv)*aStride + (long)t*D_ + d0;
    float4 a0 = *(const float4*)a, a1 = *(const float4*)(a+4);
    x[0]=a0.x; x[1]=a0.y; x[2]=a0.z; x[3]=a0.w;
    x[4]=a1.x; x[5]=a1.y; x[6]=a1.z; x[7]=a1.w;
  }
  const unsigned short* b = Bb + (long)slot*bStride + (long)t*D_ + d0;
  ushort4 b0 = *(const ushort4*)b, b1 = *(const ushort4*)(b+4);
  x[0]+=bf2f(b0.x); x[1]+=bf2f(b0.y); x[2]+=bf2f(b0.z); x[3]+=bf2f(b0.w);
  x[4]+=bf2f(b1.x); x[5]+=bf2f(b1.y); x[6]+=bf2f(b1.z); x[7]+=bf2f(b1.w);
  float s=0.f;
  #pragma unroll
  for (int i=0;i<8;i++) s += x[i];
  #pragma unroll
  for (int o=32;o;o>>=1) s += __shfl_xor(s,o);
  float m = s*(1.f/D_);
  float q=0.f;
  #pragma unroll
  for (int i=0;i<8;i++){ float d=x[i]-m; q+=d*d; }
  #pragma unroll
  for (int o=32;o;o>>=1) q += __shfl_xor(q,o);
  float rs = rsqrtf(q*(1.f/D_)+1e-5f);
  int e = eidx[slot];
  const float* g  = G  + (long)e*D_ + d0;
  const float* bt = Bt + (long)e*D_ + d0;
  float4 g0 = *(const float4*)g, g1 = *(const float4*)(g+4);
  float4 t0 = *(const float4*)bt, t1 = *(const float4*)(bt+4);
  float gg[8] = {g0.x,g0.y,g0.z,g0.w,g1.x,g1.y,g1.z,g1.w};
  float tt[8] = {t0.x,t0.y,t0.z,t0.w,t1.x,t1.y,t1.z,t1.w};
  long ob = (long)slot*(T_*D_) + (long)t*D_ + d0;
  ushort4 o0, o1;
  float y0=(x[0]-m)*rs*gg[0]+tt[0], y1=(x[1]-m)*rs*gg[1]+tt[1];
  float y2=(x[2]-m)*rs*gg[2]+tt[2], y3=(x[3]-m)*rs*gg[3]+tt[3];
  float y4=(x[4]-m)*rs*gg[4]+tt[4], y5=(x[5]-m)*rs*gg[5]+tt[5];
  float y6=(x[6]-m)*rs*gg[6]+tt[6], y7=(x[7]-m)*rs*gg[7]+tt[7];
  o0.x=f2bf(y0); o0.y=f2bf(y1); o0.z=f2bf(y2); o0.w=f2bf(y3);
  o1.x=f2bf(y4); o1.y=f2bf(y5); o1.z=f2bf(y6); o1.w=f2bf(y7);
  *(ushort4*)(OutB+ob) = o0;
  *(ushort4*)(OutB+ob+4) = o1;
}

// ---------------- residual add + LayerNorm (n3) + weighted slot combine (bf16 in) ----------------
__global__ void __launch_bounds__(256) add_ln_comb_k(
    const unsigned short* __restrict__ x2b, const unsigned short* __restrict__ proj,
    const float* __restrict__ G, const float* __restrict__ Bt,
    const int* __restrict__ eidx, const float* __restrict__ wgt,
    float* __restrict__ dstF, unsigned short* __restrict__ dstB)
{
  int row = blockIdx.x*4 + (threadIdx.x>>6);   // b*256+t
  int b = row>>8, t = row&255;
  int lane = threadIdx.x&63;
  int d0 = lane*8;
  float out[8];
  #pragma unroll
  for (int i=0;i<8;i++) out[i]=0.f;
  #pragma unroll
  for (int s2i=0;s2i<2;s2i++){
    int slot = 2*b + s2i;
    int e = eidx[slot];
    float w = wgt[slot];
    const unsigned short* a = x2b + (long)slot*(T_*D_) + (long)t*D_ + d0;
    const unsigned short* p = proj + (long)slot*(T_*D_) + (long)t*D_ + d0;
    ushort4 a0 = *(const ushort4*)a, a1 = *(const ushort4*)(a+4);
    ushort4 p0 = *(const ushort4*)p, p1 = *(const ushort4*)(p+4);
    float x[8];
    x[0]=bf2f(a0.x)+bf2f(p0.x); x[1]=bf2f(a0.y)+bf2f(p0.y);
    x[2]=bf2f(a0.z)+bf2f(p0.z); x[3]=bf2f(a0.w)+bf2f(p0.w);
    x[4]=bf2f(a1.x)+bf2f(p1.x); x[5]=bf2f(a1.y)+bf2f(p1.y);
    x[6]=bf2f(a1.z)+bf2f(p1.z); x[7]=bf2f(a1.w)+bf2f(p1.w);
    float s=0.f;
    #pragma unroll
    for (int i=0;i<8;i++) s += x[i];
    #pragma unroll
    for (int o=32;o;o>>=1) s += __shfl_xor(s,o);
    float m = s*(1.f/D_);
    float q=0.f;
    #pragma unroll
    for (int i=0;i<8;i++){ float d=x[i]-m; q+=d*d; }
    #pragma unroll
    for (int o=32;o;o>>=1) q += __shfl_xor(q,o);
    float rs = rsqrtf(q*(1.f/D_)+1e-5f);
    const float* g  = G  + (long)e*D_ + d0;
    const float* bt = Bt + (long)e*D_ + d0;
    float4 g0 = *(const float4*)g, g1 = *(const float4*)(g+4);
    float4 t0 = *(const float4*)bt, t1 = *(const float4*)(bt+4);
    float gg[8] = {g0.x,g0.y,g0.z,g0.w,g1.x,g1.y,g1.z,g1.w};
    float tt[8] = {t0.x,t0.y,t0.z,t0.w,t1.x,t1.y,t1.z,t1.w};
    #pragma unroll
    for (int i=0;i<8;i++) out[i] += w*((x[i]-m)*rs*gg[i]+tt[i]);
  }
  long ob = (long)row*D_ + d0;
  float4 f0 = {out[0],out[1],out[2],out[3]};
  float4 f1 = {out[4],out[5],out[6],out[7]};
  *(float4*)(dstF+ob) = f0;
  *(float4*)(dstF+ob+4) = f1;
  ushort4 o0, o1;
  o0.x=f2bf(out[0]); o0.y=f2bf(out[1]); o0.z=f2bf(out[2]); o0.w=f2bf(out[3]);
  o1.x=f2bf(out[4]); o1.y=f2bf(out[5]); o1.z=f2bf(out[6]); o1.w=f2bf(out[7]);
  *(ushort4*)(dstB+ob) = o0;
  *(ushort4*)(dstB+ob+4) = o1;
}

extern "C" void kernel_launch(void* const* d_in, const int* in_sizes, int n_in,
                              void* d_out, int out_size, void* d_ws, size_t ws_size,
                              hipStream_t stream)
{
  const float* tgt      = (const float*)d_in[0];
  const float* memory   = (const float*)d_in[1];
  const float* router_w = (const float*)d_in[2];
  const float* sa_in_w  = (const float*)d_in[3];
  const float* sa_in_b  = (const float*)d_in[4];
  const float* sa_out_w = (const float*)d_in[5];
  const float* sa_out_b = (const float*)d_in[6];
  const float* ca_in_w  = (const float*)d_in[7];
  const float* ca_in_b  = (const float*)d_in[8];
  const float* ca_out_w = (const float*)d_in[9];
  const float* ca_out_b = (const float*)d_in[10];
  const float* lin1_w   = (const float*)d_in[11];
  const float* lin1_b   = (const float*)d_in[12];
  const float* lin2_w   = (const float*)d_in[13];
  const float* lin2_b   = (const float*)d_in[14];
  const float* n1_g = (const float*)d_in[15];
  const float* n1_b = (const float*)d_in[16];
  const float* n2_g = (const float*)d_in[17];
  const float* n2_b = (const float*)d_in[18];
  const float* n3_g = (const float*)d_in[19];
  const float* n3_b = (const float*)d_in[20];

  char* ws = (char*)d_ws;
  size_t off = 0;
  auto alloc = [&](size_t bytes)->char*{
    char* p = ws + off; off += (bytes + 255) & ~(size_t)255; return p;
  };
  unsigned short* xb    = (unsigned short*)alloc(2ull*B_*T_*D_);
  unsigned short* memb  = (unsigned short*)alloc(2ull*B_*S_*D_);
  float*          x     = (float*)alloc(4ull*B_*T_*D_);
  float*          part  = (float*)alloc(4ull*B_*8*D_);
  int*            eidx  = (int*)alloc(4ull*NSLOT);
  float*          wgt   = (float*)alloc(4ull*NSLOT);
  unsigned short* wSaIn  = (unsigned short*)alloc(2ull*E_*3*D_*D_);
  unsigned short* wSaOut = (unsigned short*)alloc(2ull*E_*D_*D_);
  unsigned short* wCaIn  = (unsigned short*)alloc(2ull*E_*3*D_*D_);
  unsigned short* wCaOut = (unsigned short*)alloc(2ull*E_*D_*D_);
  unsigned short* wL1    = (unsigned short*)alloc(2ull*E_*DFF_*D_);
  unsigned short* wL2    = (unsigned short*)alloc(2ull*E_*D_*DFF_);
  unsigned short* qkv   = (unsigned short*)alloc(2ull*NSLOT*T_*3*D_);
  unsigned short* ffh   = (unsigned short*)alloc(2ull*NSLOT*T_*DFF_);
  unsigned short* attn  = (unsigned short*)alloc(2ull*NSLOT*T_*D_);
  unsigned short* proj  = (unsigned short*)alloc(2ull*NSLOT*T_*D_);
  unsigned short* x1b   = (unsigned short*)alloc(2ull*NSLOT*T_*D_);
  unsigned short* cq    = (unsigned short*)alloc(2ull*NSLOT*T_*D_);
  unsigned short* mkv   = (unsigned short*)alloc(2ull*NSLOT*S_*2*D_);
  unsigned short* x2b   = (unsigned short*)alloc(2ull*NSLOT*T_*D_);
  unsigned short* Vt2   = (unsigned short*)alloc(2ull*NSLOT*H_*HD_*S_);
  unsigned short* Vt1   = cq;   // alias: [slot][h][64][T]; cq written after fattn-self consumed Vt1

  cast_bf16_k<<<1024,256,0,stream>>>(tgt,    xb,   (long)B_*T_*D_);
  cast_bf16_k<<<1024,256,0,stream>>>(memory, memb, (long)B_*S_*D_);

  const float* xcur = tgt;
  for (int l=0; l<L_; ++l){
    pool_k<<<B_*8,256,0,stream>>>(xcur, part);
    route2_k<<<B_,256,0,stream>>>(part, router_w + (size_t)l*E_*D_, eidx, wgt);
    cast_weights_k<<<2048,256,0,stream>>>(
      sa_in_w  + (size_t)l*E_*3*D_*D_, sa_out_w + (size_t)l*E_*D_*D_,
      ca_in_w  + (size_t)l*E_*3*D_*D_, ca_out_w + (size_t)l*E_*D_*D_,
      lin1_w   + (size_t)l*E_*DFF_*D_, lin2_w   + (size_t)l*E_*D_*DFF_,
      wSaIn, wSaOut, wCaIn, wCaOut, wL1, wL2);

    // fused QKV (set0) + cross-attn K,V (set1)
    gemm_dual<<<dim3(6*2*NSLOT + 4*4*NSLOT),512,0,stream>>>(
      xb,   (long)T_*D_, wSaIn,                sa_in_b + (size_t)l*E_*3*D_,
      qkv,  (long)T_*3*D_, 3*D_,
      memb, (long)S_*D_, wCaIn + (size_t)D_*D_, ca_in_b + (size_t)l*E_*3*D_ + D_,
      mkv,  (long)S_*2*D_, 2*D_,
      eidx);
    // dual V transpose: Vt1 from qkv-V, Vt2 from mkv-V
    vtrans2_k<<<dim3(T_/64 + S_/64, H_, NSLOT),256,0,stream>>>(
      qkv + 2*D_, (long)T_*3*D_, 3*D_, Vt1, T_,
      mkv + D_,   (long)S_*2*D_, 2*D_, Vt2, S_);
    // fused self-attention (128 q-rows, 128-k pairs)
    fattn_k<4><<<dim3(T_/128, NSLOT*H_),512,0,stream>>>(
      qkv, (long)T_*3*D_, 3*D_,
      qkv + D_, (long)T_*3*D_, 3*D_,
      Vt1, attn, (long)T_*D_, D_);
    // self-attn out proj (bf16 out)
    gemm_lds<64,128,32,32,64><<<dim3(4,4,NSLOT),512,0,stream>>>(
      attn, (long)T_*D_, 1, 0, D_,
      wSaOut, 0, 0, (long)D_*D_, D_,
      eidx, sa_out_b + (size_t)l*E_*D_, D_,
      proj, (long)T_*D_, 0, D_,
      512, 1, 0, 0, 0, 1.f);
    add_ln_k<0><<<2048,256,0,stream>>>(xcur, 2, (long)T_*D_, proj, (long)T_*D_,
      n1_g + (size_t)l*E_*D_, n1_b + (size_t)l*E_*D_, eidx, x1b);
    // cross-attn Q (scaled)
    gemm_lds<64,128,32,32,64><<<dim3(4,4,NSLOT),512,0,stream>>>(
      x1b, (long)T_*D_, 1, 0, D_,
      wCaIn, 0, 0, (long)3*D_*D_, D_,
      eidx, ca_in_b + (size_t)l*E_*3*D_, 3*D_,
      cq, (long)T_*D_, 0, D_,
      512, 1, 0, 0, D_, 0.125f);
    // fused cross-attention (128 q-rows, 128-k pairs)
    fattn_k<8><<<dim3(T_/128, NSLOT*H_),512,0,stream>>>(
      cq, (long)T_*D_, D_,
      mkv, (long)S_*2*D_, 2*D_,
      Vt2, attn, (long)T_*D_, D_);
    // cross-attn out proj (bf16 out)
    gemm_lds<64,128,32,32,64><<<dim3(4,4,NSLOT),512,0,stream>>>(
      attn, (long)T_*D_, 1, 0, D_,
      wCaOut, 0, 0, (long)D_*D_, D_,
      eidx, ca_out_b + (size_t)l*E_*D_, D_,
      proj, (long)T_*D_, 0, D_,
      512, 1, 0, 0, 0, 1.f);
    add_ln_k<1><<<2048,256,0,stream>>>(x1b, 1, (long)T_*D_, proj, (long)T_*D_,
      n2_g + (size_t)l*E_*D_, n2_b + (size_t)l*E_*D_, eidx, x2b);
    // FFN1 (+relu)
    gemm_lds<128,256,64,64,32><<<dim3(8,2,NSLOT),512,0,stream>>>(
      x2b, (long)T_*D_, 1, 0, D_,
      wL1, 0, 0, (long)DFF_*D_, D_,
      eidx, lin1_b + (size_t)l*E_*DFF_, DFF_,
      ffh, (long)T_*DFF_, 0, DFF_,
      512, 1, 0, 1, 0, 1.f);
    // FFN2 (bf16 out)
    gemm_lds<64,128,32,32,64><<<dim3(4,4,NSLOT),512,0,stream>>>(
      ffh, (long)T_*DFF_, 1, 0, DFF_,
      wL2, 0, 0, (long)D_*DFF_, DFF_,
      eidx, lin2_b + (size_t)l*E_*D_, D_,
      proj, (long)T_*D_, 0, D_,
      2048, 1, 0, 0, 0, 1.f);
    // n3 LN + weighted combine
    float* dstF = (l==L_-1) ? (float*)d_out : x;
    add_ln_comb_k<<<1024,256,0,stream>>>(x2b, proj,
      n3_g + (size_t)l*E_*D_, n3_b + (size_t)l*E_*D_, eidx, wgt, dstF, xb);
    xcur = x;
  }
}

// Round 16
// 930.050 us; speedup vs baseline: 1.2204x; 1.0005x over previous
//
#include <hip/hip_runtime.h>
#include <hip/hip_bf16.h>

#define L_ 4
#define E_ 4
#define D_ 512
#define DFF_ 2048
#define H_ 8
#define B_ 16
#define T_ 256
#define S_ 512
#define HD_ 64
#define NSLOT 32   // B * K

typedef __attribute__((ext_vector_type(4))) float f32x4;
typedef __attribute__((ext_vector_type(8))) short bf16x8;
typedef __attribute__((ext_vector_type(4))) int i32x4;

static __device__ __forceinline__ float bf2f(unsigned short u){
  union{float f; unsigned u;} c; c.u = ((unsigned)u)<<16; return c.f;
}
static __device__ __forceinline__ unsigned short f2bf(float f){
  union{float f; unsigned u;} c; c.f=f;
  unsigned u=c.u;
  return (unsigned short)((u + 0x7FFFu + ((u>>16)&1u))>>16);
}

static __device__ __forceinline__ void gload16(const unsigned short* g, unsigned short* l){
  __builtin_amdgcn_global_load_lds(
      (const __attribute__((address_space(1))) void*)g,
      (__attribute__((address_space(3))) void*)l, 16, 0, 0);
}

// bijective XCD-chunked block remap (m204)
static __device__ __forceinline__ int xcd_swz(int orig, int nwg){
  int q = nwg >> 3, r = nwg & 7;
  int xcd = orig & 7, idx = orig >> 3;
  return (xcd < r) ? (xcd*(q+1) + idx) : (r*(q+1) + (xcd-r)*q + idx);
}

// ---------------- prep: pooled partial sums (blocks 0..127) + weight cast (rest) ----------------
__global__ void __launch_bounds__(256) prep_k(const float* __restrict__ x,
    float* __restrict__ part,
    const float* __restrict__ s0, const float* __restrict__ s1,
    const float* __restrict__ s2, const float* __restrict__ s3,
    const float* __restrict__ s4, const float* __restrict__ s5,
    unsigned short* __restrict__ d0, unsigned short* __restrict__ d1,
    unsigned short* __restrict__ d2, unsigned short* __restrict__ d3,
    unsigned short* __restrict__ d4, unsigned short* __restrict__ d5)
{
  int tid = threadIdx.x;
  if (blockIdx.x < B_*8){
    int b = blockIdx.x >> 3, ch = blockIdx.x & 7;
    const float* xp = x + ((long)b*T_ + ch*32)*D_ + tid*2;
    float p0=0.f, p1=0.f;
    #pragma unroll 8
    for (int t=0;t<32;t++){
      float2 v = *(const float2*)(xp + (long)t*D_);
      p0 += v.x; p1 += v.y;
    }
    float* pp = part + ((long)b*8 + ch)*D_ + tid*2;
    pp[0]=p0; pp[1]=p1;
    return;
  }
  const long N0=(long)E_*3*D_*D_, N1=(long)E_*D_*D_;
  const long N2=N0, N3=N1, N4=(long)E_*DFF_*D_, N5=N4;
  const long total = N0+N1+N2+N3+N4+N5;
  long i = ((long)(blockIdx.x - B_*8)*256 + tid)*4;
  long st = (long)(gridDim.x - B_*8)*256*4;
  for (; i<total; i+=st){
    const float* s; unsigned short* d; long j = i;
    if (j < N0){ s=s0; d=d0; }
    else if ((j-=N0) < N1){ s=s1; d=d1; }
    else if ((j-=N1) < N2){ s=s2; d=d2; }
    else if ((j-=N2) < N3){ s=s3; d=d3; }
    else if ((j-=N3) < N4){ s=s4; d=d4; }
    else { j-=N4; s=s5; d=d5; }
    float4 v = *(const float4*)(s+j);
    ushort4 o; o.x=f2bf(v.x); o.y=f2bf(v.y); o.z=f2bf(v.z); o.w=f2bf(v.w);
    *(ushort4*)(d+j) = o;
  }
}

// ---------------- routing: stage 2 — combine partials, logits, top-2 ----------------
__global__ void __launch_bounds__(256) route2_k(const float* __restrict__ part,
    const float* __restrict__ rw, int* __restrict__ eidx, float* __restrict__ wgt)
{
  __shared__ float pooled[D_];
  __shared__ float logit[E_];
  int b = blockIdx.x, tid = threadIdx.x;
  for (int d = tid; d < D_; d += 256){
    float s = 0.f;
    #pragma unroll
    for (int c=0;c<8;c++) s += part[((long)b*8 + c)*D_ + d];
    pooled[d] = s * (1.f/T_);
  }
  __syncthreads();
  int wave = tid>>6, lane = tid&63;
  {
    float s=0.f;
    const float* w = rw + (long)wave*D_;
    for (int d=lane; d<D_; d+=64) s += pooled[d]*w[d];
    #pragma unroll
    for (int o=32;o;o>>=1) s += __shfl_xor(s,o);
    if (lane==0) logit[wave] = s;
  }
  __syncthreads();
  if (tid==0){
    int i1=0; float v1=logit[0];
    for (int e=1;e<E_;e++) if (logit[e] > v1){ v1=logit[e]; i1=e; }
    int i2=-1; float v2=-3.4e38f;
    for (int e=0;e<E_;e++) if (e!=i1 && logit[e] > v2){ v2=logit[e]; i2=e; }
    float e2 = __expf(v2 - v1);
    float w1 = 1.f/(1.f+e2);
    eidx[2*b]=i1; eidx[2*b+1]=i2;
    wgt[2*b]=w1; wgt[2*b+1]=e2*w1;
  }
}

// ---------------- casts ----------------
__global__ void __launch_bounds__(256) cast_bf16_k(const float* __restrict__ in,
    unsigned short* __restrict__ out, long n){
  long i = ((long)blockIdx.x*blockDim.x + threadIdx.x)*4;
  long st = (long)gridDim.x*blockDim.x*4;
  for (; i<n; i+=st){
    float4 v = *(const float4*)(in+i);
    ushort4 o; o.x=f2bf(v.x); o.y=f2bf(v.y); o.z=f2bf(v.z); o.w=f2bf(v.w);
    *(ushort4*)(out+i) = o;
  }
}

// ---------------- fused flash attention (128 q-rows, 8 waves, 128-k pairs, in-kernel V^T) ----------------
template<int NT>   // 64-k tiles: 4 (self) or 8 (cross); processed as NT/2 pairs
__global__ void __launch_bounds__(512) fattn_k(
    const unsigned short* __restrict__ Qg, long qSlot, int ldq,
    const unsigned short* __restrict__ Kg, long kSlot, int ldk,
    const unsigned short* __restrict__ Vg, long vSlot, int ldv,
    unsigned short* __restrict__ Og, long oSlot, int ldo)
{
  constexpr int NT2 = NT/2;
  __shared__ unsigned short K_lds[128][72];
  __shared__ unsigned short V_lds[64][136];   // [d][k] — transposed in-kernel
  __shared__ unsigned short P_lds[8][16][72];

  int nwg = gridDim.x*gridDim.y;
  int wg = xcd_swz(blockIdx.x + gridDim.x*blockIdx.y, nwg);
  int qb = wg % gridDim.x;
  int z  = wg / gridDim.x;        // slot*H + h
  int slot = z >> 3, h = z & 7;
  int tid = threadIdx.x, wave = tid>>6, lane = tid&63;
  int lr = lane&15, lg = lane>>4;
  int lk = lg*8;

  const unsigned short* Qp = Qg + (long)slot*qSlot + (long)h*HD_;
  const unsigned short* Kp = Kg + (long)slot*kSlot + (long)h*HD_;
  const unsigned short* Vp = Vg + (long)slot*vSlot + (long)h*HD_;

  bf16x8 qf[2];
  {
    int qrow = qb*128 + wave*16 + lr;
    const unsigned short* qr = Qp + (long)qrow*ldq;
    qf[0] = *(const bf16x8*)(qr + lk);
    qf[1] = *(const bf16x8*)(qr + 32 + lk);
  }

  float m_prev[4], l_run[4];
  f32x4 acc_o[4];
  #pragma unroll
  for (int r=0;r<4;r++){ m_prev[r]=-1e30f; l_run[r]=0.f; }
  #pragma unroll
  for (int ni=0;ni<4;ni++) acc_o[ni]=(f32x4){0.f,0.f,0.f,0.f};

  int srow = tid>>3, sch = tid&7;   // K: rows srow, srow+64 of 128; V: k-rows srow/srow+64, d-chunk sch

  // prologue: load pair 0
  i32x4 kr0 = *(const i32x4*)(Kp + (long)srow*ldk + sch*8);
  i32x4 kr1 = *(const i32x4*)(Kp + (long)(srow+64)*ldk + sch*8);
  i32x4 vr0 = *(const i32x4*)(Vp + (long)srow*ldv + sch*8);
  i32x4 vr1 = *(const i32x4*)(Vp + (long)(srow+64)*ldv + sch*8);

  for (int it=0; it<NT2; ++it){
    __syncthreads();   // all waves done reading prev pair's LDS
    *(i32x4*)&K_lds[srow][sch*8] = kr0;
    *(i32x4*)&K_lds[srow+64][sch*8] = kr1;
    {
      const unsigned short* p0 = (const unsigned short*)&vr0;
      const unsigned short* p1 = (const unsigned short*)&vr1;
      #pragma unroll
      for (int j=0;j<8;j++){
        V_lds[sch*8+j][srow]      = p0[j];
        V_lds[sch*8+j][srow+64]   = p1[j];
      }
    }
    __syncthreads();

    // issue next pair's loads NOW; they complete under the compute below
    int itn = (it+1 < NT2) ? it+1 : it;
    int k0n = itn*128;
    kr0 = *(const i32x4*)(Kp + (long)(k0n+srow)*ldk + sch*8);
    kr1 = *(const i32x4*)(Kp + (long)(k0n+srow+64)*ldk + sch*8);
    vr0 = *(const i32x4*)(Vp + (long)(k0n+srow)*ldv + sch*8);
    vr1 = *(const i32x4*)(Vp + (long)(k0n+srow+64)*ldv + sch*8);

    #pragma unroll
    for (int sub=0; sub<2; ++sub){
      // S = Q @ K^T  (sub-tile of 64 k)
      f32x4 s[4];
      #pragma unroll
      for (int ni=0;ni<4;ni++) s[ni]=(f32x4){0.f,0.f,0.f,0.f};
      __builtin_amdgcn_s_setprio(1);
      #pragma unroll
      for (int ki=0;ki<2;ki++){
        #pragma unroll
        for (int ni=0;ni<4;ni++){
          bf16x8 kf = *(const bf16x8*)&K_lds[sub*64 + ni*16+lr][ki*32+lk];
          s[ni] = __builtin_amdgcn_mfma_f32_16x16x32_bf16(qf[ki], kf, s[ni],0,0,0);
        }
      }
      __builtin_amdgcn_s_setprio(0);
      // online softmax with rescale-skip
      float tmax[4];
      #pragma unroll
      for (int r=0;r<4;r++){
        tmax[r] = fmaxf(fmaxf(s[0][r],s[1][r]),fmaxf(s[2][r],s[3][r]));
        #pragma unroll
        for (int msk=1; msk<16; msk<<=1) tmax[r]=fmaxf(tmax[r], __shfl_xor(tmax[r],msk));
      }
      bool inc = (tmax[0]>m_prev[0])|(tmax[1]>m_prev[1])|(tmax[2]>m_prev[2])|(tmax[3]>m_prev[3]);
      if (__any(inc)){
        #pragma unroll
        for (int r=0;r<4;r++){
          float mnew = fmaxf(m_prev[r], tmax[r]);
          float corr = __expf(m_prev[r]-mnew);
          m_prev[r] = mnew;
          l_run[r] *= corr;
          #pragma unroll
          for (int ni=0;ni<4;ni++) acc_o[ni][r] *= corr;
        }
      }
      float rs[4] = {0.f,0.f,0.f,0.f};
      #pragma unroll
      for (int ni=0;ni<4;ni++){
        #pragma unroll
        for (int r=0;r<4;r++){
          float p = __expf(s[ni][r]-m_prev[r]);
          rs[r] += p;
          P_lds[wave][lg*4+r][ni*16+lr] = f2bf(p);
        }
      }
      #pragma unroll
      for (int r=0;r<4;r++){
        #pragma unroll
        for (int msk=1; msk<16; msk<<=1) rs[r] += __shfl_xor(rs[r],msk);
        l_run[r] += rs[r];
      }
      // O += P @ V   (P_lds wave-private; V_lds[d][k] sub-tile cols)
      __builtin_amdgcn_s_setprio(1);
      #pragma unroll
      for (int ki=0;ki<2;ki++){
        bf16x8 pf = *(const bf16x8*)&P_lds[wave][lr][ki*32+lk];
        #pragma unroll
        for (int ni=0;ni<4;ni++){
          bf16x8 vf = *(const bf16x8*)&V_lds[ni*16+lr][sub*64 + ki*32+lk];
          acc_o[ni] = __builtin_amdgcn_mfma_f32_16x16x32_bf16(pf, vf, acc_o[ni],0,0,0);
        }
      }
      __builtin_amdgcn_s_setprio(0);
    }
  }
  unsigned short* Op = Og + (long)slot*oSlot + (long)h*HD_;
  #pragma unroll
  for (int r=0;r<4;r++){
    float inv = 1.f/l_run[r];
    int q = qb*128 + wave*16 + lg*4 + r;
    #pragma unroll
    for (int ni=0;ni<4;ni++)
      Op[(long)q*ldo + ni*16 + lr] = f2bf(acc_o[ni][r]*inv);
  }
}

// ---------------- GEMM core (per-block body; dbuf LDS, chunk-XOR swizzle, 8 waves) ----------------
template<int BM, int BN, int WTM, int WTN, int BK>
static __device__ __forceinline__ void gemm_core(
    const unsigned short* __restrict__ Ap,
    const unsigned short* __restrict__ Wp,
    const float* __restrict__ bp,
    void* __restrict__ Cp, long cbase, int ldc,
    int lda, int ldw, int bm0, int bn0,
    int K, int f32out, int relu, int scaleNlim, float scaleVal,
    unsigned short* smem)
{
  constexpr int WAVES_N = BN/WTN;
  constexpr int MI = WTM/16, NI = WTN/16;
  constexpr int SLOTS = BK/8;
  int tid  = threadIdx.x;
  int wave = tid>>6, lane = tid&63;
  int wm = wave / WAVES_N, wn = wave % WAVES_N;
  int lr = lane&15;
  int lg = lane>>4;
  int swz = (BK==64) ? (lr&7) : ((lr>>1)&3);

  f32x4 acc[MI][NI];
  #pragma unroll
  for (int i=0;i<MI;i++)
  #pragma unroll
  for (int j=0;j<NI;j++) acc[i][j] = (f32x4){0.f,0.f,0.f,0.f};

  auto stage = [&](int buf, int k0){
    unsigned short* as = &smem[(size_t)buf*(BM+BN)*BK];
    unsigned short* bs = as + BM*BK;
    #pragma unroll
    for (int i=0;i<BM*SLOTS/512;i++){
      int cch = i*512 + tid;
      int row = cch / SLOTS, c = cch % SLOTS;
      int cs = (BK==64) ? (c ^ (row&7)) : (c ^ ((row>>1)&3));
      gload16(Ap + (long)row*lda + k0 + (cs<<3), as + cch*8);
    }
    #pragma unroll
    for (int i=0;i<BN*SLOTS/512;i++){
      int cch = i*512 + tid;
      int row = cch / SLOTS, c = cch % SLOTS;
      int cs = (BK==64) ? (c ^ (row&7)) : (c ^ ((row>>1)&3));
      gload16(Wp + (long)row*ldw + k0 + (cs<<3), bs + cch*8);
    }
  };

  auto compute = [&](int buf){
    unsigned short* as = &smem[(size_t)buf*(BM+BN)*BK];
    unsigned short* bs = as + BM*BK;
    #pragma unroll
    for (int ki=0;ki<BK/32;ki++){
      bf16x8 af[MI], bfr[NI];
      #pragma unroll
      for (int mi=0;mi<MI;mi++){
        int row = wm*WTM + mi*16 + lr;
        af[mi] = *(const bf16x8*)&as[row*BK + (((ki*4+lg) ^ swz)<<3)];
      }
      #pragma unroll
      for (int ni=0;ni<NI;ni++){
        int row = wn*WTN + ni*16 + lr;
        bfr[ni] = *(const bf16x8*)&bs[row*BK + (((ki*4+lg) ^ swz)<<3)];
      }
      __builtin_amdgcn_s_setprio(1);
      #pragma unroll
      for (int mi=0;mi<MI;mi++)
      #pragma unroll
      for (int ni=0;ni<NI;ni++)
        acc[mi][ni] = __builtin_amdgcn_mfma_f32_16x16x32_bf16(af[mi], bfr[ni], acc[mi][ni], 0,0,0);
      __builtin_amdgcn_s_setprio(0);
    }
  };

  int NT = K / BK;
  stage(0, 0);
  __syncthreads();
  int cur = 0;
  for (int t=0; t<NT; ++t){
    if (t+1 < NT) stage(cur^1, (t+1)*BK);
    compute(cur);
    __syncthreads();
    cur ^= 1;
  }

  int rbase = lg*4;
  #pragma unroll
  for (int mi=0;mi<MI;mi++)
  #pragma unroll
  for (int ni=0;ni<NI;ni++){
    f32x4 v = acc[mi][ni];
    int n = bn0 + wn*WTN + ni*16 + lr;
    float bv = bp ? bp[n] : 0.f;
    float scv = (n < scaleNlim) ? scaleVal : 1.f;
    #pragma unroll
    for (int r=0;r<4;r++){
      int m = bm0 + wm*WTM + mi*16 + rbase + r;
      float val = (v[r] + bv) * scv;
      if (relu) val = fmaxf(val, 0.f);
      long o = cbase + (long)m*ldc + n;
      if (f32out) ((float*)Cp)[o] = val;
      else ((unsigned short*)Cp)[o] = f2bf(val);
    }
  }
}

// ---------------- single GEMM  C = A @ W^T ----------------
template<int BM, int BN, int WTM, int WTN, int BK>
__global__ void __launch_bounds__(512) gemm_lds(
    const unsigned short* __restrict__ A, long aSlot, int aDiv, long aHead, int lda,
    const unsigned short* __restrict__ W, long wSlot, long wHead, long wExp, int ldw,
    const int* __restrict__ eidx, const float* __restrict__ bias, long biasExp,
    void* __restrict__ Cp, long cSlot, long cHead, int ldc,
    int K, int HZ, int f32out, int relu, int scaleNlim, float scaleVal)
{
  constexpr int SLOTS = BK/8;
  static_assert((BM/WTM)*(BN/WTN) == 8, "8 waves");
  static_assert((BM*SLOTS)%512==0 && (BN*SLOTS)%512==0, "stage coverage");
  __shared__ unsigned short smem[2*(BM+BN)*BK];

  int nwg = gridDim.x*gridDim.y*gridDim.z;
  int wg = xcd_swz(blockIdx.x + gridDim.x*(blockIdx.y + gridDim.y*blockIdx.z), nwg);
  int bx = wg % gridDim.x; int t1 = wg / gridDim.x;
  int by = t1 % gridDim.y; int z  = t1 / gridDim.y;

  int slot = z / HZ;
  int h = z - slot*HZ;
  int e = eidx ? eidx[slot] : 0;
  const unsigned short* Ap = A + (long)(slot/aDiv)*aSlot + (long)h*aHead + (long)by*BM*lda;
  const unsigned short* Wp = W + (long)slot*wSlot + (long)h*wHead + (long)e*wExp + (long)bx*BN*ldw;
  const float* bp = bias ? (bias + (long)e*biasExp) : nullptr;
  long cbase = (long)slot*cSlot + (long)h*cHead;

  gemm_core<BM,BN,WTM,WTN,BK>(Ap, Wp, bp, Cp, cbase, ldc, lda, ldw,
      by*BM, bx*BN, K, f32out, relu, scaleNlim, scaleVal, smem);
}

// ---------------- dual GEMM: QKV (set0) + CA-KV (set1) in one launch ----------------
__global__ void __launch_bounds__(512) gemm_dual(
    const unsigned short* __restrict__ A0, long aSlot0,
    const unsigned short* __restrict__ W0, const float* __restrict__ bias0,
    unsigned short* __restrict__ C0, long cSlot0, int ldc0,
    const unsigned short* __restrict__ A1, long aSlot1,
    const unsigned short* __restrict__ W1, const float* __restrict__ bias1,
    unsigned short* __restrict__ C1, long cSlot1, int ldc1,
    const int* __restrict__ eidx)
{
  constexpr int BM=128, BN=256, WTM=64, WTN=64, BK=32;
  __shared__ unsigned short smem[2*(BM+BN)*BK];
  const int NBLK0 = 6*2*NSLOT;   // QKV: bx<6, by<2
  int nwg = gridDim.x;
  int wg = xcd_swz(blockIdx.x, nwg);

  const unsigned short *Ap, *Wp; const float* bp;
  unsigned short* Cp; long cbase; int ldc, bm0, bn0, scaleNlim;
  if (wg < NBLK0){
    int bx = wg % 6; int t1 = wg / 6;
    int by = t1 % 2; int slot = t1 / 2;
    int e = eidx[slot];
    bm0 = by*BM; bn0 = bx*BN;
    Ap = A0 + (long)(slot/2)*aSlot0 + (long)bm0*D_;
    Wp = W0 + (long)e*(3*D_*D_) + (long)bn0*D_;
    bp = bias0 + (long)e*(3*D_);
    Cp = C0; cbase = (long)slot*cSlot0; ldc = ldc0; scaleNlim = D_;
  } else {
    int w1 = wg - NBLK0;
    int bx = w1 % 4; int t1 = w1 / 4;
    int by = t1 % 4; int slot = t1 / 4;
    int e = eidx[slot];
    bm0 = by*BM; bn0 = bx*BN;
    Ap = A1 + (long)(slot/2)*aSlot1 + (long)bm0*D_;
    Wp = W1 + (long)e*(3*D_*D_) + (long)bn0*D_;
    bp = bias1 + (long)e*(3*D_);
    Cp = C1; cbase = (long)slot*cSlot1; ldc = ldc1; scaleNlim = 0;
  }
  gemm_core<BM,BN,WTM,WTN,BK>(Ap, Wp, bp, Cp, cbase, ldc, D_, D_,
      bm0, bn0, 512, 0, 0, scaleNlim, 0.125f, smem);
}

// ---------------- residual add + LayerNorm (vectorized; A fp32 or bf16; bf16 out) ----------------
template<int ABF>
__global__ void __launch_bounds__(256) add_ln_k(
    const void* __restrict__ Ab_, int aDiv, long aStride,
    const unsigned short* __restrict__ Bb, long bStride,
    const float* __restrict__ G, const float* __restrict__ Bt,
    const int* __restrict__ eidx,
    unsigned short* __restrict__ OutB)
{
  int row = blockIdx.x*4 + (threadIdx.x>>6);
  int slot = row>>8, t = row&255;
  int lane = threadIdx.x&63;
  int d0 = lane*8;
  float x[8];
  if (ABF){
    const unsigned short* a = (const unsigned short*)Ab_ + (long)(slot/aDiv)*aStride + (long)t*D_ + d0;
    ushort4 a0 = *(const ushort4*)a, a1 = *(const ushort4*)(a+4);
    x[0]=bf2f(a0.x); x[1]=bf2f(a0.y); x[2]=bf2f(a0.z); x[3]=bf2f(a0.w);
    x[4]=bf2f(a1.x); x[5]=bf2f(a1.y); x[6]=bf2f(a1.z); x[7]=bf2f(a1.w);
  } else {
    const float* a = (const float*)Ab_ + (long)(slot/aDiv)*aStride + (long)t*D_ + d0;
    float4 a0 = *(const float4*)a, a1 = *(const float4*)(a+4);
    x[0]=a0.x; x[1]=a0.y; x[2]=a0.z; x[3]=a0.w;
    x[4]=a1.x; x[5]=a1.y; x[6]=a1.z; x[7]=a1.w;
  }
  const unsigned short* b = Bb + (long)slot*bStride + (long)t*D_ + d0;
  ushort4 b0 = *(const ushort4*)b, b1 = *(const ushort4*)(b+4);
  x[0]+=bf2f(b0.x); x[1]+=bf2f(b0.y); x[2]+=bf2f(b0.z); x[3]+=bf2f(b0.w);
  x[4]+=bf2f(b1.x); x[5]+=bf2f(b1.y); x[6]+=bf2f(b1.z); x[7]+=bf2f(b1.w);
  float s=0.f;
  #pragma unroll
  for (int i=0;i<8;i++) s += x[i];
  #pragma unroll
  for (int o=32;o;o>>=1) s += __shfl_xor(s,o);
  float m = s*(1.f/D_);
  float q=0.f;
  #pragma unroll
  for (int i=0;i<8;i++){ float d=x[i]-m; q+=d*d; }
  #pragma unroll
  for (int o=32;o;o>>=1) q += __shfl_xor(q,o);
  float rs = rsqrtf(q*(1.f/D_)+1e-5f);
  int e = eidx[slot];
  const float* g  = G  + (long)e*D_ + d0;
  const float* bt = Bt + (long)e*D_ + d0;
  float4 g0 = *(const float4*)g, g1 = *(const float4*)(g+4);
  float4 t0 = *(const float4*)bt, t1 = *(const float4*)(bt+4);
  float gg[8] = {g0.x,g0.y,g0.z,g0.w,g1.x,g1.y,g1.z,g1.w};
  float tt[8] = {t0.x,t0.y,t0.z,t0.w,t1.x,t1.y,t1.z,t1.w};
  long ob = (long)slot*(T_*D_) + (long)t*D_ + d0;
  ushort4 o0, o1;
  float y0=(x[0]-m)*rs*gg[0]+tt[0], y1=(x[1]-m)*rs*gg[1]+tt[1];
  float y2=(x[2]-m)*rs*gg[2]+tt[2], y3=(x[3]-m)*rs*gg[3]+tt[3];
  float y4=(x[4]-m)*rs*gg[4]+tt[4], y5=(x[5]-m)*rs*gg[5]+tt[5];
  float y6=(x[6]-m)*rs*gg[6]+tt[6], y7=(x[7]-m)*rs*gg[7]+tt[7];
  o0.x=f2bf(y0); o0.y=f2bf(y1); o0.z=f2bf(y2); o0.w=f2bf(y3);
  o1.x=f2bf(y4); o1.y=f2bf(y5); o1.z=f2bf(y6); o1.w=f2bf(y7);
  *(ushort4*)(OutB+ob) = o0;
  *(ushort4*)(OutB+ob+4) = o1;
}

// ---------------- residual add + LayerNorm (n3) + weighted slot combine (bf16 in) ----------------
__global__ void __launch_bounds__(256) add_ln_comb_k(
    const unsigned short* __restrict__ x2b, const unsigned short* __restrict__ proj,
    const float* __restrict__ G, const float* __restrict__ Bt,
    const int* __restrict__ eidx, const float* __restrict__ wgt,
    float* __restrict__ dstF, unsigned short* __restrict__ dstB)
{
  int row = blockIdx.x*4 + (threadIdx.x>>6);   // b*256+t
  int b = row>>8, t = row&255;
  int lane = threadIdx.x&63;
  int d0 = lane*8;
  float out[8];
  #pragma unroll
  for (int i=0;i<8;i++) out[i]=0.f;
  #pragma unroll
  for (int s2i=0;s2i<2;s2i++){
    int slot = 2*b + s2i;
    int e = eidx[slot];
    float w = wgt[slot];
    const unsigned short* a = x2b + (long)slot*(T_*D_) + (long)t*D_ + d0;
    const unsigned short* p = proj + (long)slot*(T_*D_) + (long)t*D_ + d0;
    ushort4 a0 = *(const ushort4*)a, a1 = *(const ushort4*)(a+4);
    ushort4 p0 = *(const ushort4*)p, p1 = *(const ushort4*)(p+4);
    float x[8];
    x[0]=bf2f(a0.x)+bf2f(p0.x); x[1]=bf2f(a0.y)+bf2f(p0.y);
    x[2]=bf2f(a0.z)+bf2f(p0.z); x[3]=bf2f(a0.w)+bf2f(p0.w);
    x[4]=bf2f(a1.x)+bf2f(p1.x); x[5]=bf2f(a1.y)+bf2f(p1.y);
    x[6]=bf2f(a1.z)+bf2f(p1.z); x[7]=bf2f(a1.w)+bf2f(p1.w);
    float s=0.f;
    #pragma unroll
    for (int i=0;i<8;i++) s += x[i];
    #pragma unroll
    for (int o=32;o;o>>=1) s += __shfl_xor(s,o);
    float m = s*(1.f/D_);
    float q=0.f;
    #pragma unroll
    for (int i=0;i<8;i++){ float d=x[i]-m; q+=d*d; }
    #pragma unroll
    for (int o=32;o;o>>=1) q += __shfl_xor(q,o);
    float rs = rsqrtf(q*(1.f/D_)+1e-5f);
    const float* g  = G  + (long)e*D_ + d0;
    const float* bt = Bt + (long)e*D_ + d0;
    float4 g0 = *(const float4*)g, g1 = *(const float4*)(g+4);
    float4 t0 = *(const float4*)bt, t1 = *(const float4*)(bt+4);
    float gg[8] = {g0.x,g0.y,g0.z,g0.w,g1.x,g1.y,g1.z,g1.w};
    float tt[8] = {t0.x,t0.y,t0.z,t0.w,t1.x,t1.y,t1.z,t1.w};
    #pragma unroll
    for (int i=0;i<8;i++) out[i] += w*((x[i]-m)*rs*gg[i]+tt[i]);
  }
  long ob = (long)row*D_ + d0;
  float4 f0 = {out[0],out[1],out[2],out[3]};
  float4 f1 = {out[4],out[5],out[6],out[7]};
  *(float4*)(dstF+ob) = f0;
  *(float4*)(dstF+ob+4) = f1;
  ushort4 o0, o1;
  o0.x=f2bf(out[0]); o0.y=f2bf(out[1]); o0.z=f2bf(out[2]); o0.w=f2bf(out[3]);
  o1.x=f2bf(out[4]); o1.y=f2bf(out[5]); o1.z=f2bf(out[6]); o1.w=f2bf(out[7]);
  *(ushort4*)(dstB+ob) = o0;
  *(ushort4*)(dstB+ob+4) = o1;
}

extern "C" void kernel_launch(void* const* d_in, const int* in_sizes, int n_in,
                              void* d_out, int out_size, void* d_ws, size_t ws_size,
                              hipStream_t stream)
{
  const float* tgt      = (const float*)d_in[0];
  const float* memory   = (const float*)d_in[1];
  const float* router_w = (const float*)d_in[2];
  const float* sa_in_w  = (const float*)d_in[3];
  const float* sa_in_b  = (const float*)d_in[4];
  const float* sa_out_w = (const float*)d_in[5];
  const float* sa_out_b = (const float*)d_in[6];
  const float* ca_in_w  = (const float*)d_in[7];
  const float* ca_in_b  = (const float*)d_in[8];
  const float* ca_out_w = (const float*)d_in[9];
  const float* ca_out_b = (const float*)d_in[10];
  const float* lin1_w   = (const float*)d_in[11];
  const float* lin1_b   = (const float*)d_in[12];
  const float* lin2_w   = (const float*)d_in[13];
  const float* lin2_b   = (const float*)d_in[14];
  const float* n1_g = (const float*)d_in[15];
  const float* n1_b = (const float*)d_in[16];
  const float* n2_g = (const float*)d_in[17];
  const float* n2_b = (const float*)d_in[18];
  const float* n3_g = (const float*)d_in[19];
  const float* n3_b = (const float*)d_in[20];

  char* ws = (char*)d_ws;
  size_t off = 0;
  auto alloc = [&](size_t bytes)->char*{
    char* p = ws + off; off += (bytes + 255) & ~(size_t)255; return p;
  };
  unsigned short* xb    = (unsigned short*)alloc(2ull*B_*T_*D_);
  unsigned short* memb  = (unsigned short*)alloc(2ull*B_*S_*D_);
  float*          x     = (float*)alloc(4ull*B_*T_*D_);
  float*          part  = (float*)alloc(4ull*B_*8*D_);
  int*            eidx  = (int*)alloc(4ull*NSLOT);
  float*          wgt   = (float*)alloc(4ull*NSLOT);
  unsigned short* wSaIn  = (unsigned short*)alloc(2ull*E_*3*D_*D_);
  unsigned short* wSaOut = (unsigned short*)alloc(2ull*E_*D_*D_);
  unsigned short* wCaIn  = (unsigned short*)alloc(2ull*E_*3*D_*D_);
  unsigned short* wCaOut = (unsigned short*)alloc(2ull*E_*D_*D_);
  unsigned short* wL1    = (unsigned short*)alloc(2ull*E_*DFF_*D_);
  unsigned short* wL2    = (unsigned short*)alloc(2ull*E_*D_*DFF_);
  unsigned short* qkv   = (unsigned short*)alloc(2ull*NSLOT*T_*3*D_);
  unsigned short* ffh   = (unsigned short*)alloc(2ull*NSLOT*T_*DFF_);
  unsigned short* attn  = (unsigned short*)alloc(2ull*NSLOT*T_*D_);
  unsigned short* proj  = (unsigned short*)alloc(2ull*NSLOT*T_*D_);
  unsigned short* x1b   = (unsigned short*)alloc(2ull*NSLOT*T_*D_);
  unsigned short* cq    = (unsigned short*)alloc(2ull*NSLOT*T_*D_);
  unsigned short* mkv   = (unsigned short*)alloc(2ull*NSLOT*S_*2*D_);
  unsigned short* x2b   = (unsigned short*)alloc(2ull*NSLOT*T_*D_);

  cast_bf16_k<<<1024,256,0,stream>>>(tgt,    xb,   (long)B_*T_*D_);
  cast_bf16_k<<<1024,256,0,stream>>>(memory, memb, (long)B_*S_*D_);

  const float* xcur = tgt;
  for (int l=0; l<L_; ++l){
    // pooled partials (blocks 0..127) + weight cast (blocks 128..) in one launch
    prep_k<<<B_*8 + 2048,256,0,stream>>>(xcur, part,
      sa_in_w  + (size_t)l*E_*3*D_*D_, sa_out_w + (size_t)l*E_*D_*D_,
      ca_in_w  + (size_t)l*E_*3*D_*D_, ca_out_w + (size_t)l*E_*D_*D_,
      lin1_w   + (size_t)l*E_*DFF_*D_, lin2_w   + (size_t)l*E_*D_*DFF_,
      wSaIn, wSaOut, wCaIn, wCaOut, wL1, wL2);
    route2_k<<<B_,256,0,stream>>>(part, router_w + (size_t)l*E_*D_, eidx, wgt);

    // fused QKV (set0) + cross-attn K,V (set1)
    gemm_dual<<<dim3(6*2*NSLOT + 4*4*NSLOT),512,0,stream>>>(
      xb,   (long)T_*D_, wSaIn,                sa_in_b + (size_t)l*E_*3*D_,
      qkv,  (long)T_*3*D_, 3*D_,
      memb, (long)S_*D_, wCaIn + (size_t)D_*D_, ca_in_b + (size_t)l*E_*3*D_ + D_,
      mkv,  (long)S_*2*D_, 2*D_,
      eidx);
    // fused self-attention (V transposed in-kernel from qkv)
    fattn_k<4><<<dim3(T_/128, NSLOT*H_),512,0,stream>>>(
      qkv, (long)T_*3*D_, 3*D_,
      qkv + D_, (long)T_*3*D_, 3*D_,
      qkv + 2*D_, (long)T_*3*D_, 3*D_,
      attn, (long)T_*D_, D_);
    // self-attn out proj (bf16 out)
    gemm_lds<64,128,32,32,64><<<dim3(4,4,NSLOT),512,0,stream>>>(
      attn, (long)T_*D_, 1, 0, D_,
      wSaOut, 0, 0, (long)D_*D_, D_,
      eidx, sa_out_b + (size_t)l*E_*D_, D_,
      proj, (long)T_*D_, 0, D_,
      512, 1, 0, 0, 0, 1.f);
    add_ln_k<0><<<2048,256,0,stream>>>(xcur, 2, (long)T_*D_, proj, (long)T_*D_,
      n1_g + (size_t)l*E_*D_, n1_b + (size_t)l*E_*D_, eidx, x1b);
    // cross-attn Q (scaled)
    gemm_lds<64,128,32,32,64><<<dim3(4,4,NSLOT),512,0,stream>>>(
      x1b, (long)T_*D_, 1, 0, D_,
      wCaIn, 0, 0, (long)3*D_*D_, D_,
      eidx, ca_in_b + (size_t)l*E_*3*D_, 3*D_,
      cq, (long)T_*D_, 0, D_,
      512, 1, 0, 0, D_, 0.125f);
    // fused cross-attention (V transposed in-kernel from mkv)
    fattn_k<8><<<dim3(T_/128, NSLOT*H_),512,0,stream>>>(
      cq, (long)T_*D_, D_,
      mkv, (long)S_*2*D_, 2*D_,
      mkv + D_, (long)S_*2*D_, 2*D_,
      attn, (long)T_*D_, D_);
    // cross-attn out proj (bf16 out)
    gemm_lds<64,128,32,32,64><<<dim3(4,4,NSLOT),512,0,stream>>>(
      attn, (long)T_*D_, 1, 0, D_,
      wCaOut, 0, 0, (long)D_*D_, D_,
      eidx, ca_out_b + (size_t)l*E_*D_, D_,
      proj, (long)T_*D_, 0, D_,
      512, 1, 0, 0, 0, 1.f);
    add_ln_k<1><<<2048,256,0,stream>>>(x1b, 1, (long)T_*D_, proj, (long)T_*D_,
      n2_g + (size_t)l*E_*D_, n2_b + (size_t)l*E_*D_, eidx, x2b);
    // FFN1 (+relu)
    gemm_lds<128,256,64,64,32><<<dim3(8,2,NSLOT),512,0,stream>>>(
      x2b, (long)T_*D_, 1, 0, D_,
      wL1, 0, 0, (long)DFF_*D_, D_,
      eidx, lin1_b + (size_t)l*E_*DFF_, DFF_,
      ffh, (long)T_*DFF_, 0, DFF_,
      512, 1, 0, 1, 0, 1.f);
    // FFN2 (bf16 out)
    gemm_lds<64,128,32,32,64><<<dim3(4,4,NSLOT),512,0,stream>>>(
      ffh, (long)T_*DFF_, 1, 0, DFF_,
      wL2, 0, 0, (long)D_*DFF_, DFF_,
      eidx, lin2_b + (size_t)l*E_*D_, D_,
      proj, (long)T_*D_, 0, D_,
      2048, 1, 0, 0, 0, 1.f);
    // n3 LN + weighted combine
    float* dstF = (l==L_-1) ? (float*)d_out : x;
    add_ln_comb_k<<<1024,256,0,stream>>>(x2b, proj,
      n3_g + (size_t)l*E_*D_, n3_b + (size_t)l*E_*D_, eidx, wgt, dstF, xb);
    xcur = x;
  }
}

// Round 17
// 907.675 us; speedup vs baseline: 1.2505x; 1.0247x over previous
//
#include <hip/hip_runtime.h>
#include <hip/hip_bf16.h>

#define L_ 4
#define E_ 4
#define D_ 512
#define DFF_ 2048
#define H_ 8
#define B_ 16
#define T_ 256
#define S_ 512
#define HD_ 64
#define NSLOT 32   // B * K

typedef __attribute__((ext_vector_type(4))) float f32x4;
typedef __attribute__((ext_vector_type(8))) short bf16x8;
typedef __attribute__((ext_vector_type(4))) int i32x4;

static __device__ __forceinline__ float bf2f(unsigned short u){
  union{float f; unsigned u;} c; c.u = ((unsigned)u)<<16; return c.f;
}
static __device__ __forceinline__ unsigned short f2bf(float f){
  union{float f; unsigned u;} c; c.f=f;
  unsigned u=c.u;
  return (unsigned short)((u + 0x7FFFu + ((u>>16)&1u))>>16);
}

static __device__ __forceinline__ void gload16(const unsigned short* g, unsigned short* l){
  __builtin_amdgcn_global_load_lds(
      (const __attribute__((address_space(1))) void*)g,
      (__attribute__((address_space(3))) void*)l, 16, 0, 0);
}

// bijective XCD-chunked block remap (m204)
static __device__ __forceinline__ int xcd_swz(int orig, int nwg){
  int q = nwg >> 3, r = nwg & 7;
  int xcd = orig & 7, idx = orig >> 3;
  return (xcd < r) ? (xcd*(q+1) + idx) : (r*(q+1) + (xcd-r)*q + idx);
}

// ---------------- prep: pooled partial sums (blocks 0..127) + weight cast (rest) ----------------
__global__ void __launch_bounds__(256) prep_k(const float* __restrict__ x,
    float* __restrict__ part,
    const float* __restrict__ s0, const float* __restrict__ s1,
    const float* __restrict__ s2, const float* __restrict__ s3,
    const float* __restrict__ s4, const float* __restrict__ s5,
    unsigned short* __restrict__ d0, unsigned short* __restrict__ d1,
    unsigned short* __restrict__ d2, unsigned short* __restrict__ d3,
    unsigned short* __restrict__ d4, unsigned short* __restrict__ d5)
{
  int tid = threadIdx.x;
  if (blockIdx.x < B_*8){
    int b = blockIdx.x >> 3, ch = blockIdx.x & 7;
    const float* xp = x + ((long)b*T_ + ch*32)*D_ + tid*2;
    float p0=0.f, p1=0.f;
    #pragma unroll 8
    for (int t=0;t<32;t++){
      float2 v = *(const float2*)(xp + (long)t*D_);
      p0 += v.x; p1 += v.y;
    }
    float* pp = part + ((long)b*8 + ch)*D_ + tid*2;
    pp[0]=p0; pp[1]=p1;
    return;
  }
  const long N0=(long)E_*3*D_*D_, N1=(long)E_*D_*D_;
  const long N2=N0, N3=N1, N4=(long)E_*DFF_*D_, N5=N4;
  const long total = N0+N1+N2+N3+N4+N5;
  long i = ((long)(blockIdx.x - B_*8)*256 + tid)*4;
  long st = (long)(gridDim.x - B_*8)*256*4;
  for (; i<total; i+=st){
    const float* s; unsigned short* d; long j = i;
    if (j < N0){ s=s0; d=d0; }
    else if ((j-=N0) < N1){ s=s1; d=d1; }
    else if ((j-=N1) < N2){ s=s2; d=d2; }
    else if ((j-=N2) < N3){ s=s3; d=d3; }
    else if ((j-=N3) < N4){ s=s4; d=d4; }
    else { j-=N4; s=s5; d=d5; }
    float4 v = *(const float4*)(s+j);
    ushort4 o; o.x=f2bf(v.x); o.y=f2bf(v.y); o.z=f2bf(v.z); o.w=f2bf(v.w);
    *(ushort4*)(d+j) = o;
  }
}

// ---------------- routing: stage 2 — combine partials, logits, top-2 ----------------
__global__ void __launch_bounds__(256) route2_k(const float* __restrict__ part,
    const float* __restrict__ rw, int* __restrict__ eidx, float* __restrict__ wgt)
{
  __shared__ float pooled[D_];
  __shared__ float logit[E_];
  int b = blockIdx.x, tid = threadIdx.x;
  for (int d = tid; d < D_; d += 256){
    float s = 0.f;
    #pragma unroll
    for (int c=0;c<8;c++) s += part[((long)b*8 + c)*D_ + d];
    pooled[d] = s * (1.f/T_);
  }
  __syncthreads();
  int wave = tid>>6, lane = tid&63;
  {
    float s=0.f;
    const float* w = rw + (long)wave*D_;
    for (int d=lane; d<D_; d+=64) s += pooled[d]*w[d];
    #pragma unroll
    for (int o=32;o;o>>=1) s += __shfl_xor(s,o);
    if (lane==0) logit[wave] = s;
  }
  __syncthreads();
  if (tid==0){
    int i1=0; float v1=logit[0];
    for (int e=1;e<E_;e++) if (logit[e] > v1){ v1=logit[e]; i1=e; }
    int i2=-1; float v2=-3.4e38f;
    for (int e=0;e<E_;e++) if (e!=i1 && logit[e] > v2){ v2=logit[e]; i2=e; }
    float e2 = __expf(v2 - v1);
    float w1 = 1.f/(1.f+e2);
    eidx[2*b]=i1; eidx[2*b+1]=i2;
    wgt[2*b]=w1; wgt[2*b+1]=e2*w1;
  }
}

// ---------------- casts ----------------
__global__ void __launch_bounds__(256) cast_bf16_k(const float* __restrict__ in,
    unsigned short* __restrict__ out, long n){
  long i = ((long)blockIdx.x*blockDim.x + threadIdx.x)*4;
  long st = (long)gridDim.x*blockDim.x*4;
  for (; i<n; i+=st){
    float4 v = *(const float4*)(in+i);
    ushort4 o; o.x=f2bf(v.x); o.y=f2bf(v.y); o.z=f2bf(v.z); o.w=f2bf(v.w);
    *(ushort4*)(out+i) = o;
  }
}

// ---------------- fused flash attention (128 q-rows, 8 waves, 128-k pairs, in-kernel V^T) ----------------
// V_lds layout XOR-swizzled: logical (d,k) stored at col k ^ (((d>>3)&7)<<3)
// -> transposed b16 scatter writes spread all 32 banks (2-way, free).
template<int NT>   // 64-k tiles: 4 (self) or 8 (cross); processed as NT/2 pairs
__global__ void __launch_bounds__(512) fattn_k(
    const unsigned short* __restrict__ Qg, long qSlot, int ldq,
    const unsigned short* __restrict__ Kg, long kSlot, int ldk,
    const unsigned short* __restrict__ Vg, long vSlot, int ldv,
    unsigned short* __restrict__ Og, long oSlot, int ldo)
{
  constexpr int NT2 = NT/2;
  __shared__ unsigned short K_lds[128][72];
  __shared__ unsigned short V_lds[64][136];   // [d][kx] — transposed + XOR swizzled
  __shared__ unsigned short P_lds[8][16][72];

  int nwg = gridDim.x*gridDim.y;
  int wg = xcd_swz(blockIdx.x + gridDim.x*blockIdx.y, nwg);
  int qb = wg % gridDim.x;
  int z  = wg / gridDim.x;        // slot*H + h
  int slot = z >> 3, h = z & 7;
  int tid = threadIdx.x, wave = tid>>6, lane = tid&63;
  int lr = lane&15, lg = lane>>4;
  int lk = lg*8;

  const unsigned short* Qp = Qg + (long)slot*qSlot + (long)h*HD_;
  const unsigned short* Kp = Kg + (long)slot*kSlot + (long)h*HD_;
  const unsigned short* Vp = Vg + (long)slot*vSlot + (long)h*HD_;

  bf16x8 qf[2];
  {
    int qrow = qb*128 + wave*16 + lr;
    const unsigned short* qr = Qp + (long)qrow*ldq;
    qf[0] = *(const bf16x8*)(qr + lk);
    qf[1] = *(const bf16x8*)(qr + 32 + lk);
  }

  float m_prev[4], l_run[4];
  f32x4 acc_o[4];
  #pragma unroll
  for (int r=0;r<4;r++){ m_prev[r]=-1e30f; l_run[r]=0.f; }
  #pragma unroll
  for (int ni=0;ni<4;ni++) acc_o[ni]=(f32x4){0.f,0.f,0.f,0.f};

  int srow = tid>>3, sch = tid&7;   // K: rows srow, srow+64 of 128; V: k-rows srow/srow+64, d-chunk sch

  // prologue: load pair 0
  i32x4 kr0 = *(const i32x4*)(Kp + (long)srow*ldk + sch*8);
  i32x4 kr1 = *(const i32x4*)(Kp + (long)(srow+64)*ldk + sch*8);
  i32x4 vr0 = *(const i32x4*)(Vp + (long)srow*ldv + sch*8);
  i32x4 vr1 = *(const i32x4*)(Vp + (long)(srow+64)*ldv + sch*8);

  for (int it=0; it<NT2; ++it){
    __syncthreads();   // all waves done reading prev pair's LDS
    *(i32x4*)&K_lds[srow][sch*8] = kr0;
    *(i32x4*)&K_lds[srow+64][sch*8] = kr1;
    {
      const unsigned short* p0 = (const unsigned short*)&vr0;
      const unsigned short* p1 = (const unsigned short*)&vr1;
      int kx0 = srow ^ (sch<<3);   // key(d)=((d>>3)&7)<<3 = sch<<3 for d=sch*8+j
      #pragma unroll
      for (int j=0;j<8;j++){
        V_lds[sch*8+j][kx0]      = p0[j];
        V_lds[sch*8+j][kx0+64]   = p1[j];   // (srow+64)^key = kx0+64 (key is bits 3..5)
      }
    }
    __syncthreads();

    // issue next pair's loads NOW; they complete under the compute below
    int itn = (it+1 < NT2) ? it+1 : it;
    int k0n = itn*128;
    kr0 = *(const i32x4*)(Kp + (long)(k0n+srow)*ldk + sch*8);
    kr1 = *(const i32x4*)(Kp + (long)(k0n+srow+64)*ldk + sch*8);
    vr0 = *(const i32x4*)(Vp + (long)(k0n+srow)*ldv + sch*8);
    vr1 = *(const i32x4*)(Vp + (long)(k0n+srow+64)*ldv + sch*8);

    #pragma unroll
    for (int sub=0; sub<2; ++sub){
      // S = Q @ K^T  (sub-tile of 64 k)
      f32x4 s[4];
      #pragma unroll
      for (int ni=0;ni<4;ni++) s[ni]=(f32x4){0.f,0.f,0.f,0.f};
      __builtin_amdgcn_s_setprio(1);
      #pragma unroll
      for (int ki=0;ki<2;ki++){
        #pragma unroll
        for (int ni=0;ni<4;ni++){
          bf16x8 kf = *(const bf16x8*)&K_lds[sub*64 + ni*16+lr][ki*32+lk];
          s[ni] = __builtin_amdgcn_mfma_f32_16x16x32_bf16(qf[ki], kf, s[ni],0,0,0);
        }
      }
      __builtin_amdgcn_s_setprio(0);
      // online softmax with rescale-skip
      float tmax[4];
      #pragma unroll
      for (int r=0;r<4;r++){
        tmax[r] = fmaxf(fmaxf(s[0][r],s[1][r]),fmaxf(s[2][r],s[3][r]));
        #pragma unroll
        for (int msk=1; msk<16; msk<<=1) tmax[r]=fmaxf(tmax[r], __shfl_xor(tmax[r],msk));
      }
      bool inc = (tmax[0]>m_prev[0])|(tmax[1]>m_prev[1])|(tmax[2]>m_prev[2])|(tmax[3]>m_prev[3]);
      if (__any(inc)){
        #pragma unroll
        for (int r=0;r<4;r++){
          float mnew = fmaxf(m_prev[r], tmax[r]);
          float corr = __expf(m_prev[r]-mnew);
          m_prev[r] = mnew;
          l_run[r] *= corr;
          #pragma unroll
          for (int ni=0;ni<4;ni++) acc_o[ni][r] *= corr;
        }
      }
      float rs[4] = {0.f,0.f,0.f,0.f};
      #pragma unroll
      for (int ni=0;ni<4;ni++){
        #pragma unroll
        for (int r=0;r<4;r++){
          float p = __expf(s[ni][r]-m_prev[r]);
          rs[r] += p;
          P_lds[wave][lg*4+r][ni*16+lr] = f2bf(p);
        }
      }
      #pragma unroll
      for (int r=0;r<4;r++){
        #pragma unroll
        for (int msk=1; msk<16; msk<<=1) rs[r] += __shfl_xor(rs[r],msk);
        l_run[r] += rs[r];
      }
      // O += P @ V   (P_lds wave-private; V_lds[d][kx] with same XOR key per d-row)
      __builtin_amdgcn_s_setprio(1);
      #pragma unroll
      for (int ki=0;ki<2;ki++){
        bf16x8 pf = *(const bf16x8*)&P_lds[wave][lr][ki*32+lk];
        #pragma unroll
        for (int ni=0;ni<4;ni++){
          int vkey = ((ni*2 + (lr>>3)) & 7) << 3;
          bf16x8 vf = *(const bf16x8*)&V_lds[ni*16+lr][sub*64 + ((ki*32+lk) ^ vkey)];
          acc_o[ni] = __builtin_amdgcn_mfma_f32_16x16x32_bf16(pf, vf, acc_o[ni],0,0,0);
        }
      }
      __builtin_amdgcn_s_setprio(0);
    }
  }
  unsigned short* Op = Og + (long)slot*oSlot + (long)h*HD_;
  #pragma unroll
  for (int r=0;r<4;r++){
    float inv = 1.f/l_run[r];
    int q = qb*128 + wave*16 + lg*4 + r;
    #pragma unroll
    for (int ni=0;ni<4;ni++)
      Op[(long)q*ldo + ni*16 + lr] = f2bf(acc_o[ni][r]*inv);
  }
}

// ---------------- GEMM core (per-block body; dbuf LDS, chunk-XOR swizzle, 8 waves) ----------------
template<int BM, int BN, int WTM, int WTN, int BK>
static __device__ __forceinline__ void gemm_core(
    const unsigned short* __restrict__ Ap,
    const unsigned short* __restrict__ Wp,
    const float* __restrict__ bp,
    void* __restrict__ Cp, long cbase, int ldc,
    int lda, int ldw, int bm0, int bn0,
    int K, int f32out, int relu, int scaleNlim, float scaleVal,
    unsigned short* smem)
{
  constexpr int WAVES_N = BN/WTN;
  constexpr int MI = WTM/16, NI = WTN/16;
  constexpr int SLOTS = BK/8;
  int tid  = threadIdx.x;
  int wave = tid>>6, lane = tid&63;
  int wm = wave / WAVES_N, wn = wave % WAVES_N;
  int lr = lane&15;
  int lg = lane>>4;
  int swz = (BK==64) ? (lr&7) : ((lr>>1)&3);

  f32x4 acc[MI][NI];
  #pragma unroll
  for (int i=0;i<MI;i++)
  #pragma unroll
  for (int j=0;j<NI;j++) acc[i][j] = (f32x4){0.f,0.f,0.f,0.f};

  auto stage = [&](int buf, int k0){
    unsigned short* as = &smem[(size_t)buf*(BM+BN)*BK];
    unsigned short* bs = as + BM*BK;
    #pragma unroll
    for (int i=0;i<BM*SLOTS/512;i++){
      int cch = i*512 + tid;
      int row = cch / SLOTS, c = cch % SLOTS;
      int cs = (BK==64) ? (c ^ (row&7)) : (c ^ ((row>>1)&3));
      gload16(Ap + (long)row*lda + k0 + (cs<<3), as + cch*8);
    }
    #pragma unroll
    for (int i=0;i<BN*SLOTS/512;i++){
      int cch = i*512 + tid;
      int row = cch / SLOTS, c = cch % SLOTS;
      int cs = (BK==64) ? (c ^ (row&7)) : (c ^ ((row>>1)&3));
      gload16(Wp + (long)row*ldw + k0 + (cs<<3), bs + cch*8);
    }
  };

  auto compute = [&](int buf){
    unsigned short* as = &smem[(size_t)buf*(BM+BN)*BK];
    unsigned short* bs = as + BM*BK;
    #pragma unroll
    for (int ki=0;ki<BK/32;ki++){
      bf16x8 af[MI], bfr[NI];
      #pragma unroll
      for (int mi=0;mi<MI;mi++){
        int row = wm*WTM + mi*16 + lr;
        af[mi] = *(const bf16x8*)&as[row*BK + (((ki*4+lg) ^ swz)<<3)];
      }
      #pragma unroll
      for (int ni=0;ni<NI;ni++){
        int row = wn*WTN + ni*16 + lr;
        bfr[ni] = *(const bf16x8*)&bs[row*BK + (((ki*4+lg) ^ swz)<<3)];
      }
      __builtin_amdgcn_s_setprio(1);
      #pragma unroll
      for (int mi=0;mi<MI;mi++)
      #pragma unroll
      for (int ni=0;ni<NI;ni++)
        acc[mi][ni] = __builtin_amdgcn_mfma_f32_16x16x32_bf16(af[mi], bfr[ni], acc[mi][ni], 0,0,0);
      __builtin_amdgcn_s_setprio(0);
    }
  };

  int NT = K / BK;
  stage(0, 0);
  __syncthreads();
  int cur = 0;
  for (int t=0; t<NT; ++t){
    if (t+1 < NT) stage(cur^1, (t+1)*BK);
    compute(cur);
    __syncthreads();
    cur ^= 1;
  }

  int rbase = lg*4;
  #pragma unroll
  for (int mi=0;mi<MI;mi++)
  #pragma unroll
  for (int ni=0;ni<NI;ni++){
    f32x4 v = acc[mi][ni];
    int n = bn0 + wn*WTN + ni*16 + lr;
    float bv = bp ? bp[n] : 0.f;
    float scv = (n < scaleNlim) ? scaleVal : 1.f;
    #pragma unroll
    for (int r=0;r<4;r++){
      int m = bm0 + wm*WTM + mi*16 + rbase + r;
      float val = (v[r] + bv) * scv;
      if (relu) val = fmaxf(val, 0.f);
      long o = cbase + (long)m*ldc + n;
      if (f32out) ((float*)Cp)[o] = val;
      else ((unsigned short*)Cp)[o] = f2bf(val);
    }
  }
}

// ---------------- single GEMM  C = A @ W^T ----------------
template<int BM, int BN, int WTM, int WTN, int BK>
__global__ void __launch_bounds__(512) gemm_lds(
    const unsigned short* __restrict__ A, long aSlot, int aDiv, long aHead, int lda,
    const unsigned short* __restrict__ W, long wSlot, long wHead, long wExp, int ldw,
    const int* __restrict__ eidx, const float* __restrict__ bias, long biasExp,
    void* __restrict__ Cp, long cSlot, long cHead, int ldc,
    int K, int HZ, int f32out, int relu, int scaleNlim, float scaleVal)
{
  constexpr int SLOTS = BK/8;
  static_assert((BM/WTM)*(BN/WTN) == 8, "8 waves");
  static_assert((BM*SLOTS)%512==0 && (BN*SLOTS)%512==0, "stage coverage");
  __shared__ unsigned short smem[2*(BM+BN)*BK];

  int nwg = gridDim.x*gridDim.y*gridDim.z;
  int wg = xcd_swz(blockIdx.x + gridDim.x*(blockIdx.y + gridDim.y*blockIdx.z), nwg);
  int bx = wg % gridDim.x; int t1 = wg / gridDim.x;
  int by = t1 % gridDim.y; int z  = t1 / gridDim.y;

  int slot = z / HZ;
  int h = z - slot*HZ;
  int e = eidx ? eidx[slot] : 0;
  const unsigned short* Ap = A + (long)(slot/aDiv)*aSlot + (long)h*aHead + (long)by*BM*lda;
  const unsigned short* Wp = W + (long)slot*wSlot + (long)h*wHead + (long)e*wExp + (long)bx*BN*ldw;
  const float* bp = bias ? (bias + (long)e*biasExp) : nullptr;
  long cbase = (long)slot*cSlot + (long)h*cHead;

  gemm_core<BM,BN,WTM,WTN,BK>(Ap, Wp, bp, Cp, cbase, ldc, lda, ldw,
      by*BM, bx*BN, K, f32out, relu, scaleNlim, scaleVal, smem);
}

// ---------------- dual GEMM: QKV (set0) + CA-KV (set1) in one launch ----------------
__global__ void __launch_bounds__(512) gemm_dual(
    const unsigned short* __restrict__ A0, long aSlot0,
    const unsigned short* __restrict__ W0, const float* __restrict__ bias0,
    unsigned short* __restrict__ C0, long cSlot0, int ldc0,
    const unsigned short* __restrict__ A1, long aSlot1,
    const unsigned short* __restrict__ W1, const float* __restrict__ bias1,
    unsigned short* __restrict__ C1, long cSlot1, int ldc1,
    const int* __restrict__ eidx)
{
  constexpr int BM=128, BN=256, WTM=64, WTN=64, BK=32;
  __shared__ unsigned short smem[2*(BM+BN)*BK];
  const int NBLK0 = 6*2*NSLOT;   // QKV: bx<6, by<2
  int nwg = gridDim.x;
  int wg = xcd_swz(blockIdx.x, nwg);

  const unsigned short *Ap, *Wp; const float* bp;
  unsigned short* Cp; long cbase; int ldc, bm0, bn0, scaleNlim;
  if (wg < NBLK0){
    int bx = wg % 6; int t1 = wg / 6;
    int by = t1 % 2; int slot = t1 / 2;
    int e = eidx[slot];
    bm0 = by*BM; bn0 = bx*BN;
    Ap = A0 + (long)(slot/2)*aSlot0 + (long)bm0*D_;
    Wp = W0 + (long)e*(3*D_*D_) + (long)bn0*D_;
    bp = bias0 + (long)e*(3*D_);
    Cp = C0; cbase = (long)slot*cSlot0; ldc = ldc0; scaleNlim = D_;
  } else {
    int w1 = wg - NBLK0;
    int bx = w1 % 4; int t1 = w1 / 4;
    int by = t1 % 4; int slot = t1 / 4;
    int e = eidx[slot];
    bm0 = by*BM; bn0 = bx*BN;
    Ap = A1 + (long)(slot/2)*aSlot1 + (long)bm0*D_;
    Wp = W1 + (long)e*(3*D_*D_) + (long)bn0*D_;
    bp = bias1 + (long)e*(3*D_);
    Cp = C1; cbase = (long)slot*cSlot1; ldc = ldc1; scaleNlim = 0;
  }
  gemm_core<BM,BN,WTM,WTN,BK>(Ap, Wp, bp, Cp, cbase, ldc, D_, D_,
      bm0, bn0, 512, 0, 0, scaleNlim, 0.125f, smem);
}

// ---------------- residual add + LayerNorm (vectorized; A fp32 or bf16; bf16 out) ----------------
template<int ABF>
__global__ void __launch_bounds__(256) add_ln_k(
    const void* __restrict__ Ab_, int aDiv, long aStride,
    const unsigned short* __restrict__ Bb, long bStride,
    const float* __restrict__ G, const float* __restrict__ Bt,
    const int* __restrict__ eidx,
    unsigned short* __restrict__ OutB)
{
  int row = blockIdx.x*4 + (threadIdx.x>>6);
  int slot = row>>8, t = row&255;
  int lane = threadIdx.x&63;
  int d0 = lane*8;
  float x[8];
  if (ABF){
    const unsigned short* a = (const unsigned short*)Ab_ + (long)(slot/aDiv)*aStride + (long)t*D_ + d0;
    ushort4 a0 = *(const ushort4*)a, a1 = *(const ushort4*)(a+4);
    x[0]=bf2f(a0.x); x[1]=bf2f(a0.y); x[2]=bf2f(a0.z); x[3]=bf2f(a0.w);
    x[4]=bf2f(a1.x); x[5]=bf2f(a1.y); x[6]=bf2f(a1.z); x[7]=bf2f(a1.w);
  } else {
    const float* a = (const float*)Ab_ + (long)(slot/aDiv)*aStride + (long)t*D_ + d0;
    float4 a0 = *(const float4*)a, a1 = *(const float4*)(a+4);
    x[0]=a0.x; x[1]=a0.y; x[2]=a0.z; x[3]=a0.w;
    x[4]=a1.x; x[5]=a1.y; x[6]=a1.z; x[7]=a1.w;
  }
  const unsigned short* b = Bb + (long)slot*bStride + (long)t*D_ + d0;
  ushort4 b0 = *(const ushort4*)b, b1 = *(const ushort4*)(b+4);
  x[0]+=bf2f(b0.x); x[1]+=bf2f(b0.y); x[2]+=bf2f(b0.z); x[3]+=bf2f(b0.w);
  x[4]+=bf2f(b1.x); x[5]+=bf2f(b1.y); x[6]+=bf2f(b1.z); x[7]+=bf2f(b1.w);
  float s=0.f;
  #pragma unroll
  for (int i=0;i<8;i++) s += x[i];
  #pragma unroll
  for (int o=32;o;o>>=1) s += __shfl_xor(s,o);
  float m = s*(1.f/D_);
  float q=0.f;
  #pragma unroll
  for (int i=0;i<8;i++){ float d=x[i]-m; q+=d*d; }
  #pragma unroll
  for (int o=32;o;o>>=1) q += __shfl_xor(q,o);
  float rs = rsqrtf(q*(1.f/D_)+1e-5f);
  int e = eidx[slot];
  const float* g  = G  + (long)e*D_ + d0;
  const float* bt = Bt + (long)e*D_ + d0;
  float4 g0 = *(const float4*)g, g1 = *(const float4*)(g+4);
  float4 t0 = *(const float4*)bt, t1 = *(const float4*)(bt+4);
  float gg[8] = {g0.x,g0.y,g0.z,g0.w,g1.x,g1.y,g1.z,g1.w};
  float tt[8] = {t0.x,t0.y,t0.z,t0.w,t1.x,t1.y,t1.z,t1.w};
  long ob = (long)slot*(T_*D_) + (long)t*D_ + d0;
  ushort4 o0, o1;
  float y0=(x[0]-m)*rs*gg[0]+tt[0], y1=(x[1]-m)*rs*gg[1]+tt[1];
  float y2=(x[2]-m)*rs*gg[2]+tt[2], y3=(x[3]-m)*rs*gg[3]+tt[3];
  float y4=(x[4]-m)*rs*gg[4]+tt[4], y5=(x[5]-m)*rs*gg[5]+tt[5];
  float y6=(x[6]-m)*rs*gg[6]+tt[6], y7=(x[7]-m)*rs*gg[7]+tt[7];
  o0.x=f2bf(y0); o0.y=f2bf(y1); o0.z=f2bf(y2); o0.w=f2bf(y3);
  o1.x=f2bf(y4); o1.y=f2bf(y5); o1.z=f2bf(y6); o1.w=f2bf(y7);
  *(ushort4*)(OutB+ob) = o0;
  *(ushort4*)(OutB+ob+4) = o1;
}

// ---------------- residual add + LayerNorm (n3) + weighted slot combine (bf16 in) ----------------
__global__ void __launch_bounds__(256) add_ln_comb_k(
    const unsigned short* __restrict__ x2b, const unsigned short* __restrict__ proj,
    const float* __restrict__ G, const float* __restrict__ Bt,
    const int* __restrict__ eidx, const float* __restrict__ wgt,
    float* __restrict__ dstF, unsigned short* __restrict__ dstB)
{
  int row = blockIdx.x*4 + (threadIdx.x>>6);   // b*256+t
  int b = row>>8, t = row&255;
  int lane = threadIdx.x&63;
  int d0 = lane*8;
  float out[8];
  #pragma unroll
  for (int i=0;i<8;i++) out[i]=0.f;
  #pragma unroll
  for (int s2i=0;s2i<2;s2i++){
    int slot = 2*b + s2i;
    int e = eidx[slot];
    float w = wgt[slot];
    const unsigned short* a = x2b + (long)slot*(T_*D_) + (long)t*D_ + d0;
    const unsigned short* p = proj + (long)slot*(T_*D_) + (long)t*D_ + d0;
    ushort4 a0 = *(const ushort4*)a, a1 = *(const ushort4*)(a+4);
    ushort4 p0 = *(const ushort4*)p, p1 = *(const ushort4*)(p+4);
    float x[8];
    x[0]=bf2f(a0.x)+bf2f(p0.x); x[1]=bf2f(a0.y)+bf2f(p0.y);
    x[2]=bf2f(a0.z)+bf2f(p0.z); x[3]=bf2f(a0.w)+bf2f(p0.w);
    x[4]=bf2f(a1.x)+bf2f(p1.x); x[5]=bf2f(a1.y)+bf2f(p1.y);
    x[6]=bf2f(a1.z)+bf2f(p1.z); x[7]=bf2f(a1.w)+bf2f(p1.w);
    float s=0.f;
    #pragma unroll
    for (int i=0;i<8;i++) s += x[i];
    #pragma unroll
    for (int o=32;o;o>>=1) s += __shfl_xor(s,o);
    float m = s*(1.f/D_);
    float q=0.f;
    #pragma unroll
    for (int i=0;i<8;i++){ float d=x[i]-m; q+=d*d; }
    #pragma unroll
    for (int o=32;o;o>>=1) q += __shfl_xor(q,o);
    float rs = rsqrtf(q*(1.f/D_)+1e-5f);
    const float* g  = G  + (long)e*D_ + d0;
    const float* bt = Bt + (long)e*D_ + d0;
    float4 g0 = *(const float4*)g, g1 = *(const float4*)(g+4);
    float4 t0 = *(const float4*)bt, t1 = *(const float4*)(bt+4);
    float gg[8] = {g0.x,g0.y,g0.z,g0.w,g1.x,g1.y,g1.z,g1.w};
    float tt[8] = {t0.x,t0.y,t0.z,t0.w,t1.x,t1.y,t1.z,t1.w};
    #pragma unroll
    for (int i=0;i<8;i++) out[i] += w*((x[i]-m)*rs*gg[i]+tt[i]);
  }
  long ob = (long)row*D_ + d0;
  float4 f0 = {out[0],out[1],out[2],out[3]};
  float4 f1 = {out[4],out[5],out[6],out[7]};
  *(float4*)(dstF+ob) = f0;
  *(float4*)(dstF+ob+4) = f1;
  ushort4 o0, o1;
  o0.x=f2bf(out[0]); o0.y=f2bf(out[1]); o0.z=f2bf(out[2]); o0.w=f2bf(out[3]);
  o1.x=f2bf(out[4]); o1.y=f2bf(out[5]); o1.z=f2bf(out[6]); o1.w=f2bf(out[7]);
  *(ushort4*)(dstB+ob) = o0;
  *(ushort4*)(dstB+ob+4) = o1;
}

extern "C" void kernel_launch(void* const* d_in, const int* in_sizes, int n_in,
                              void* d_out, int out_size, void* d_ws, size_t ws_size,
                              hipStream_t stream)
{
  const float* tgt      = (const float*)d_in[0];
  const float* memory   = (const float*)d_in[1];
  const float* router_w = (const float*)d_in[2];
  const float* sa_in_w  = (const float*)d_in[3];
  const float* sa_in_b  = (const float*)d_in[4];
  const float* sa_out_w = (const float*)d_in[5];
  const float* sa_out_b = (const float*)d_in[6];
  const float* ca_in_w  = (const float*)d_in[7];
  const float* ca_in_b  = (const float*)d_in[8];
  const float* ca_out_w = (const float*)d_in[9];
  const float* ca_out_b = (const float*)d_in[10];
  const float* lin1_w   = (const float*)d_in[11];
  const float* lin1_b   = (const float*)d_in[12];
  const float* lin2_w   = (const float*)d_in[13];
  const float* lin2_b   = (const float*)d_in[14];
  const float* n1_g = (const float*)d_in[15];
  const float* n1_b = (const float*)d_in[16];
  const float* n2_g = (const float*)d_in[17];
  const float* n2_b = (const float*)d_in[18];
  const float* n3_g = (const float*)d_in[19];
  const float* n3_b = (const float*)d_in[20];

  char* ws = (char*)d_ws;
  size_t off = 0;
  auto alloc = [&](size_t bytes)->char*{
    char* p = ws + off; off += (bytes + 255) & ~(size_t)255; return p;
  };
  unsigned short* xb    = (unsigned short*)alloc(2ull*B_*T_*D_);
  unsigned short* memb  = (unsigned short*)alloc(2ull*B_*S_*D_);
  float*          x     = (float*)alloc(4ull*B_*T_*D_);
  float*          part  = (float*)alloc(4ull*B_*8*D_);
  int*            eidx  = (int*)alloc(4ull*NSLOT);
  float*          wgt   = (float*)alloc(4ull*NSLOT);
  unsigned short* wSaIn  = (unsigned short*)alloc(2ull*E_*3*D_*D_);
  unsigned short* wSaOut = (unsigned short*)alloc(2ull*E_*D_*D_);
  unsigned short* wCaIn  = (unsigned short*)alloc(2ull*E_*3*D_*D_);
  unsigned short* wCaOut = (unsigned short*)alloc(2ull*E_*D_*D_);
  unsigned short* wL1    = (unsigned short*)alloc(2ull*E_*DFF_*D_);
  unsigned short* wL2    = (unsigned short*)alloc(2ull*E_*D_*DFF_);
  unsigned short* qkv   = (unsigned short*)alloc(2ull*NSLOT*T_*3*D_);
  unsigned short* ffh   = (unsigned short*)alloc(2ull*NSLOT*T_*DFF_);
  unsigned short* attn  = (unsigned short*)alloc(2ull*NSLOT*T_*D_);
  unsigned short* proj  = (unsigned short*)alloc(2ull*NSLOT*T_*D_);
  unsigned short* x1b   = (unsigned short*)alloc(2ull*NSLOT*T_*D_);
  unsigned short* cq    = (unsigned short*)alloc(2ull*NSLOT*T_*D_);
  unsigned short* mkv   = (unsigned short*)alloc(2ull*NSLOT*S_*2*D_);
  unsigned short* x2b   = (unsigned short*)alloc(2ull*NSLOT*T_*D_);

  cast_bf16_k<<<1024,256,0,stream>>>(tgt,    xb,   (long)B_*T_*D_);
  cast_bf16_k<<<1024,256,0,stream>>>(memory, memb, (long)B_*S_*D_);

  const float* xcur = tgt;
  for (int l=0; l<L_; ++l){
    // pooled partials (blocks 0..127) + weight cast (blocks 128..) in one launch
    prep_k<<<B_*8 + 2048,256,0,stream>>>(xcur, part,
      sa_in_w  + (size_t)l*E_*3*D_*D_, sa_out_w + (size_t)l*E_*D_*D_,
      ca_in_w  + (size_t)l*E_*3*D_*D_, ca_out_w + (size_t)l*E_*D_*D_,
      lin1_w   + (size_t)l*E_*DFF_*D_, lin2_w   + (size_t)l*E_*D_*DFF_,
      wSaIn, wSaOut, wCaIn, wCaOut, wL1, wL2);
    route2_k<<<B_,256,0,stream>>>(part, router_w + (size_t)l*E_*D_, eidx, wgt);

    // fused QKV (set0) + cross-attn K,V (set1)
    gemm_dual<<<dim3(6*2*NSLOT + 4*4*NSLOT),512,0,stream>>>(
      xb,   (long)T_*D_, wSaIn,                sa_in_b + (size_t)l*E_*3*D_,
      qkv,  (long)T_*3*D_, 3*D_,
      memb, (long)S_*D_, wCaIn + (size_t)D_*D_, ca_in_b + (size_t)l*E_*3*D_ + D_,
      mkv,  (long)S_*2*D_, 2*D_,
      eidx);
    // fused self-attention (V transposed in-kernel from qkv)
    fattn_k<4><<<dim3(T_/128, NSLOT*H_),512,0,stream>>>(
      qkv, (long)T_*3*D_, 3*D_,
      qkv + D_, (long)T_*3*D_, 3*D_,
      qkv + 2*D_, (long)T_*3*D_, 3*D_,
      attn, (long)T_*D_, D_);
    // self-attn out proj (bf16 out)
    gemm_lds<64,128,32,32,64><<<dim3(4,4,NSLOT),512,0,stream>>>(
      attn, (long)T_*D_, 1, 0, D_,
      wSaOut, 0, 0, (long)D_*D_, D_,
      eidx, sa_out_b + (size_t)l*E_*D_, D_,
      proj, (long)T_*D_, 0, D_,
      512, 1, 0, 0, 0, 1.f);
    add_ln_k<0><<<2048,256,0,stream>>>(xcur, 2, (long)T_*D_, proj, (long)T_*D_,
      n1_g + (size_t)l*E_*D_, n1_b + (size_t)l*E_*D_, eidx, x1b);
    // cross-attn Q (scaled)
    gemm_lds<64,128,32,32,64><<<dim3(4,4,NSLOT),512,0,stream>>>(
      x1b, (long)T_*D_, 1, 0, D_,
      wCaIn, 0, 0, (long)3*D_*D_, D_,
      eidx, ca_in_b + (size_t)l*E_*3*D_, 3*D_,
      cq, (long)T_*D_, 0, D_,
      512, 1, 0, 0, D_, 0.125f);
    // fused cross-attention (V transposed in-kernel from mkv)
    fattn_k<8><<<dim3(T_/128, NSLOT*H_),512,0,stream>>>(
      cq, (long)T_*D_, D_,
      mkv, (long)S_*2*D_, 2*D_,
      mkv + D_, (long)S_*2*D_, 2*D_,
      attn, (long)T_*D_, D_);
    // cross-attn out proj (bf16 out)
    gemm_lds<64,128,32,32,64><<<dim3(4,4,NSLOT),512,0,stream>>>(
      attn, (long)T_*D_, 1, 0, D_,
      wCaOut, 0, 0, (long)D_*D_, D_,
      eidx, ca_out_b + (size_t)l*E_*D_, D_,
      proj, (long)T_*D_, 0, D_,
      512, 1, 0, 0, 0, 1.f);
    add_ln_k<1><<<2048,256,0,stream>>>(x1b, 1, (long)T_*D_, proj, (long)T_*D_,
      n2_g + (size_t)l*E_*D_, n2_b + (size_t)l*E_*D_, eidx, x2b);
    // FFN1 (+relu)
    gemm_lds<128,256,64,64,32><<<dim3(8,2,NSLOT),512,0,stream>>>(
      x2b, (long)T_*D_, 1, 0, D_,
      wL1, 0, 0, (long)DFF_*D_, D_,
      eidx, lin1_b + (size_t)l*E_*DFF_, DFF_,
      ffh, (long)T_*DFF_, 0, DFF_,
      512, 1, 0, 1, 0, 1.f);
    // FFN2 (bf16 out)
    gemm_lds<64,128,32,32,64><<<dim3(4,4,NSLOT),512,0,stream>>>(
      ffh, (long)T_*DFF_, 1, 0, DFF_,
      wL2, 0, 0, (long)D_*DFF_, DFF_,
      eidx, lin2_b + (size_t)l*E_*D_, D_,
      proj, (long)T_*D_, 0, D_,
      2048, 1, 0, 0, 0, 1.f);
    // n3 LN + weighted combine
    float* dstF = (l==L_-1) ? (float*)d_out : x;
    add_ln_comb_k<<<1024,256,0,stream>>>(x2b, proj,
      n3_g + (size_t)l*E_*D_, n3_b + (size_t)l*E_*D_, eidx, wgt, dstF, xb);
    xcur = x;
  }
}

// Round 18
// 897.845 us; speedup vs baseline: 1.2642x; 1.0109x over previous
//
#include <hip/hip_runtime.h>
#include <hip/hip_bf16.h>

#define L_ 4
#define E_ 4
#define D_ 512
#define DFF_ 2048
#define H_ 8
#define B_ 16
#define T_ 256
#define S_ 512
#define HD_ 64
#define NSLOT 32   // B * K

typedef __attribute__((ext_vector_type(4))) float f32x4;
typedef __attribute__((ext_vector_type(8))) short bf16x8;
typedef __attribute__((ext_vector_type(4))) int i32x4;

static __device__ __forceinline__ float bf2f(unsigned short u){
  union{float f; unsigned u;} c; c.u = ((unsigned)u)<<16; return c.f;
}
static __device__ __forceinline__ unsigned short f2bf(float f){
  union{float f; unsigned u;} c; c.f=f;
  unsigned u=c.u;
  return (unsigned short)((u + 0x7FFFu + ((u>>16)&1u))>>16);
}

static __device__ __forceinline__ void gload16(const unsigned short* g, unsigned short* l){
  __builtin_amdgcn_global_load_lds(
      (const __attribute__((address_space(1))) void*)g,
      (__attribute__((address_space(3))) void*)l, 16, 0, 0);
}

// bijective XCD-chunked block remap (m204)
static __device__ __forceinline__ int xcd_swz(int orig, int nwg){
  int q = nwg >> 3, r = nwg & 7;
  int xcd = orig & 7, idx = orig >> 3;
  return (xcd < r) ? (xcd*(q+1) + idx) : (r*(q+1) + (xcd-r)*q + idx);
}

// ---------------- prep: pooled partial sums (blocks 0..127) + weight cast (rest) ----------------
__global__ void __launch_bounds__(256) prep_k(const float* __restrict__ x,
    float* __restrict__ part,
    const float* __restrict__ s0, const float* __restrict__ s1,
    const float* __restrict__ s2, const float* __restrict__ s3,
    const float* __restrict__ s4, const float* __restrict__ s5,
    unsigned short* __restrict__ d0, unsigned short* __restrict__ d1,
    unsigned short* __restrict__ d2, unsigned short* __restrict__ d3,
    unsigned short* __restrict__ d4, unsigned short* __restrict__ d5)
{
  int tid = threadIdx.x;
  if (blockIdx.x < B_*8){
    int b = blockIdx.x >> 3, ch = blockIdx.x & 7;
    const float* xp = x + ((long)b*T_ + ch*32)*D_ + tid*2;
    float p0=0.f, p1=0.f;
    #pragma unroll 8
    for (int t=0;t<32;t++){
      float2 v = *(const float2*)(xp + (long)t*D_);
      p0 += v.x; p1 += v.y;
    }
    float* pp = part + ((long)b*8 + ch)*D_ + tid*2;
    pp[0]=p0; pp[1]=p1;
    return;
  }
  const long N0=(long)E_*3*D_*D_, N1=(long)E_*D_*D_;
  const long N2=N0, N3=N1, N4=(long)E_*DFF_*D_, N5=N4;
  const long total = N0+N1+N2+N3+N4+N5;
  long i = ((long)(blockIdx.x - B_*8)*256 + tid)*4;
  long st = (long)(gridDim.x - B_*8)*256*4;
  for (; i<total; i+=st){
    const float* s; unsigned short* d; long j = i;
    if (j < N0){ s=s0; d=d0; }
    else if ((j-=N0) < N1){ s=s1; d=d1; }
    else if ((j-=N1) < N2){ s=s2; d=d2; }
    else if ((j-=N2) < N3){ s=s3; d=d3; }
    else if ((j-=N3) < N4){ s=s4; d=d4; }
    else { j-=N4; s=s5; d=d5; }
    float4 v = *(const float4*)(s+j);
    ushort4 o; o.x=f2bf(v.x); o.y=f2bf(v.y); o.z=f2bf(v.z); o.w=f2bf(v.w);
    *(ushort4*)(d+j) = o;
  }
}

// ---------------- routing: stage 2 — combine partials, logits, top-2 ----------------
__global__ void __launch_bounds__(256) route2_k(const float* __restrict__ part,
    const float* __restrict__ rw, int* __restrict__ eidx, float* __restrict__ wgt)
{
  __shared__ float pooled[D_];
  __shared__ float logit[E_];
  int b = blockIdx.x, tid = threadIdx.x;
  for (int d = tid; d < D_; d += 256){
    float s = 0.f;
    #pragma unroll
    for (int c=0;c<8;c++) s += part[((long)b*8 + c)*D_ + d];
    pooled[d] = s * (1.f/T_);
  }
  __syncthreads();
  int wave = tid>>6, lane = tid&63;
  {
    float s=0.f;
    const float* w = rw + (long)wave*D_;
    for (int d=lane; d<D_; d+=64) s += pooled[d]*w[d];
    #pragma unroll
    for (int o=32;o;o>>=1) s += __shfl_xor(s,o);
    if (lane==0) logit[wave] = s;
  }
  __syncthreads();
  if (tid==0){
    int i1=0; float v1=logit[0];
    for (int e=1;e<E_;e++) if (logit[e] > v1){ v1=logit[e]; i1=e; }
    int i2=-1; float v2=-3.4e38f;
    for (int e=0;e<E_;e++) if (e!=i1 && logit[e] > v2){ v2=logit[e]; i2=e; }
    float e2 = __expf(v2 - v1);
    float w1 = 1.f/(1.f+e2);
    eidx[2*b]=i1; eidx[2*b+1]=i2;
    wgt[2*b]=w1; wgt[2*b+1]=e2*w1;
  }
}

// ---------------- casts ----------------
__global__ void __launch_bounds__(256) cast_bf16_k(const float* __restrict__ in,
    unsigned short* __restrict__ out, long n){
  long i = ((long)blockIdx.x*blockDim.x + threadIdx.x)*4;
  long st = (long)gridDim.x*blockDim.x*4;
  for (; i<n; i+=st){
    float4 v = *(const float4*)(in+i);
    ushort4 o; o.x=f2bf(v.x); o.y=f2bf(v.y); o.z=f2bf(v.z); o.w=f2bf(v.w);
    *(ushort4*)(out+i) = o;
  }
}

// ---------------- fused flash attention (128 q-rows, 8 waves, 128-k pairs, in-kernel V^T) ----------------
// K_lds [128][64] XOR-swizzled: logical (row,k) at col k ^ ((row&7)<<3) — no pad, conflict-free.
// V_lds [64][136]: logical (d,k) at col k ^ (((d>>3)&7)<<3).
// Total LDS 52.2 KB -> 3 blocks/CU.
template<int NT>   // 64-k tiles: 4 (self) or 8 (cross); processed as NT/2 pairs
__global__ void __launch_bounds__(512) fattn_k(
    const unsigned short* __restrict__ Qg, long qSlot, int ldq,
    const unsigned short* __restrict__ Kg, long kSlot, int ldk,
    const unsigned short* __restrict__ Vg, long vSlot, int ldv,
    unsigned short* __restrict__ Og, long oSlot, int ldo)
{
  constexpr int NT2 = NT/2;
  __shared__ unsigned short K_lds[128][64];
  __shared__ unsigned short V_lds[64][136];
  __shared__ unsigned short P_lds[8][16][72];

  int nwg = gridDim.x*gridDim.y;
  int wg = xcd_swz(blockIdx.x + gridDim.x*blockIdx.y, nwg);
  int qb = wg % gridDim.x;
  int z  = wg / gridDim.x;        // slot*H + h
  int slot = z >> 3, h = z & 7;
  int tid = threadIdx.x, wave = tid>>6, lane = tid&63;
  int lr = lane&15, lg = lane>>4;
  int lk = lg*8;

  const unsigned short* Qp = Qg + (long)slot*qSlot + (long)h*HD_;
  const unsigned short* Kp = Kg + (long)slot*kSlot + (long)h*HD_;
  const unsigned short* Vp = Vg + (long)slot*vSlot + (long)h*HD_;

  bf16x8 qf[2];
  {
    int qrow = qb*128 + wave*16 + lr;
    const unsigned short* qr = Qp + (long)qrow*ldq;
    qf[0] = *(const bf16x8*)(qr + lk);
    qf[1] = *(const bf16x8*)(qr + 32 + lk);
  }

  float m_prev[4], l_run[4];
  f32x4 acc_o[4];
  #pragma unroll
  for (int r=0;r<4;r++){ m_prev[r]=-1e30f; l_run[r]=0.f; }
  #pragma unroll
  for (int ni=0;ni<4;ni++) acc_o[ni]=(f32x4){0.f,0.f,0.f,0.f};

  int srow = tid>>3, sch = tid&7;   // K: rows srow, srow+64 of 128; V: k-rows srow/srow+64, d-chunk sch
  int kKx = (sch*8) ^ ((srow&7)<<3);  // K store col (swizzled); same key for srow+64

  // prologue: load pair 0
  i32x4 kr0 = *(const i32x4*)(Kp + (long)srow*ldk + sch*8);
  i32x4 kr1 = *(const i32x4*)(Kp + (long)(srow+64)*ldk + sch*8);
  i32x4 vr0 = *(const i32x4*)(Vp + (long)srow*ldv + sch*8);
  i32x4 vr1 = *(const i32x4*)(Vp + (long)(srow+64)*ldv + sch*8);

  for (int it=0; it<NT2; ++it){
    __syncthreads();   // all waves done reading prev pair's LDS
    *(i32x4*)&K_lds[srow][kKx] = kr0;
    *(i32x4*)&K_lds[srow+64][kKx] = kr1;
    {
      const unsigned short* p0 = (const unsigned short*)&vr0;
      const unsigned short* p1 = (const unsigned short*)&vr1;
      int kx0 = srow ^ (sch<<3);   // V key(d)=((d>>3)&7)<<3 = sch<<3 for d=sch*8+j
      #pragma unroll
      for (int j=0;j<8;j++){
        V_lds[sch*8+j][kx0]      = p0[j];
        V_lds[sch*8+j][kx0+64]   = p1[j];   // (srow+64)^key = kx0+64 (key is bits 3..5)
      }
    }
    __syncthreads();

    // issue next pair's loads NOW; they complete under the compute below
    int itn = (it+1 < NT2) ? it+1 : it;
    int k0n = itn*128;
    kr0 = *(const i32x4*)(Kp + (long)(k0n+srow)*ldk + sch*8);
    kr1 = *(const i32x4*)(Kp + (long)(k0n+srow+64)*ldk + sch*8);
    vr0 = *(const i32x4*)(Vp + (long)(k0n+srow)*ldv + sch*8);
    vr1 = *(const i32x4*)(Vp + (long)(k0n+srow+64)*ldv + sch*8);

    #pragma unroll
    for (int sub=0; sub<2; ++sub){
      // S = Q @ K^T  (sub-tile of 64 k)
      f32x4 s[4];
      #pragma unroll
      for (int ni=0;ni<4;ni++) s[ni]=(f32x4){0.f,0.f,0.f,0.f};
      __builtin_amdgcn_s_setprio(1);
      #pragma unroll
      for (int ki=0;ki<2;ki++){
        #pragma unroll
        for (int ni=0;ni<4;ni++){
          bf16x8 kf = *(const bf16x8*)&K_lds[sub*64 + ni*16+lr][(ki*32+lk) ^ ((lr&7)<<3)];
          s[ni] = __builtin_amdgcn_mfma_f32_16x16x32_bf16(qf[ki], kf, s[ni],0,0,0);
        }
      }
      __builtin_amdgcn_s_setprio(0);
      // online softmax with rescale-skip
      float tmax[4];
      #pragma unroll
      for (int r=0;r<4;r++){
        tmax[r] = fmaxf(fmaxf(s[0][r],s[1][r]),fmaxf(s[2][r],s[3][r]));
        #pragma unroll
        for (int msk=1; msk<16; msk<<=1) tmax[r]=fmaxf(tmax[r], __shfl_xor(tmax[r],msk));
      }
      bool inc = (tmax[0]>m_prev[0])|(tmax[1]>m_prev[1])|(tmax[2]>m_prev[2])|(tmax[3]>m_prev[3]);
      if (__any(inc)){
        #pragma unroll
        for (int r=0;r<4;r++){
          float mnew = fmaxf(m_prev[r], tmax[r]);
          float corr = __expf(m_prev[r]-mnew);
          m_prev[r] = mnew;
          l_run[r] *= corr;
          #pragma unroll
          for (int ni=0;ni<4;ni++) acc_o[ni][r] *= corr;
        }
      }
      float rs[4] = {0.f,0.f,0.f,0.f};
      #pragma unroll
      for (int ni=0;ni<4;ni++){
        #pragma unroll
        for (int r=0;r<4;r++){
          float p = __expf(s[ni][r]-m_prev[r]);
          rs[r] += p;
          P_lds[wave][lg*4+r][ni*16+lr] = f2bf(p);
        }
      }
      #pragma unroll
      for (int r=0;r<4;r++){
        #pragma unroll
        for (int msk=1; msk<16; msk<<=1) rs[r] += __shfl_xor(rs[r],msk);
        l_run[r] += rs[r];
      }
      // O += P @ V   (P_lds wave-private; V_lds[d][kx] with same XOR key per d-row)
      __builtin_amdgcn_s_setprio(1);
      #pragma unroll
      for (int ki=0;ki<2;ki++){
        bf16x8 pf = *(const bf16x8*)&P_lds[wave][lr][ki*32+lk];
        #pragma unroll
        for (int ni=0;ni<4;ni++){
          int vkey = ((ni*2 + (lr>>3)) & 7) << 3;
          bf16x8 vf = *(const bf16x8*)&V_lds[ni*16+lr][sub*64 + ((ki*32+lk) ^ vkey)];
          acc_o[ni] = __builtin_amdgcn_mfma_f32_16x16x32_bf16(pf, vf, acc_o[ni],0,0,0);
        }
      }
      __builtin_amdgcn_s_setprio(0);
    }
  }
  unsigned short* Op = Og + (long)slot*oSlot + (long)h*HD_;
  #pragma unroll
  for (int r=0;r<4;r++){
    float inv = 1.f/l_run[r];
    int q = qb*128 + wave*16 + lg*4 + r;
    #pragma unroll
    for (int ni=0;ni<4;ni++)
      Op[(long)q*ldo + ni*16 + lr] = f2bf(acc_o[ni][r]*inv);
  }
}

// ---------------- GEMM core (per-block body; dbuf LDS, chunk-XOR swizzle, 8 waves) ----------------
template<int BM, int BN, int WTM, int WTN, int BK>
static __device__ __forceinline__ void gemm_core(
    const unsigned short* __restrict__ Ap,
    const unsigned short* __restrict__ Wp,
    const float* __restrict__ bp,
    void* __restrict__ Cp, long cbase, int ldc,
    int lda, int ldw, int bm0, int bn0,
    int K, int f32out, int relu, int scaleNlim, float scaleVal,
    unsigned short* smem)
{
  constexpr int WAVES_N = BN/WTN;
  constexpr int MI = WTM/16, NI = WTN/16;
  constexpr int SLOTS = BK/8;
  int tid  = threadIdx.x;
  int wave = tid>>6, lane = tid&63;
  int wm = wave / WAVES_N, wn = wave % WAVES_N;
  int lr = lane&15;
  int lg = lane>>4;
  int swz = (BK==64) ? (lr&7) : ((lr>>1)&3);

  f32x4 acc[MI][NI];
  #pragma unroll
  for (int i=0;i<MI;i++)
  #pragma unroll
  for (int j=0;j<NI;j++) acc[i][j] = (f32x4){0.f,0.f,0.f,0.f};

  auto stage = [&](int buf, int k0){
    unsigned short* as = &smem[(size_t)buf*(BM+BN)*BK];
    unsigned short* bs = as + BM*BK;
    #pragma unroll
    for (int i=0;i<BM*SLOTS/512;i++){
      int cch = i*512 + tid;
      int row = cch / SLOTS, c = cch % SLOTS;
      int cs = (BK==64) ? (c ^ (row&7)) : (c ^ ((row>>1)&3));
      gload16(Ap + (long)row*lda + k0 + (cs<<3), as + cch*8);
    }
    #pragma unroll
    for (int i=0;i<BN*SLOTS/512;i++){
      int cch = i*512 + tid;
      int row = cch / SLOTS, c = cch % SLOTS;
      int cs = (BK==64) ? (c ^ (row&7)) : (c ^ ((row>>1)&3));
      gload16(Wp + (long)row*ldw + k0 + (cs<<3), bs + cch*8);
    }
  };

  auto compute = [&](int buf){
    unsigned short* as = &smem[(size_t)buf*(BM+BN)*BK];
    unsigned short* bs = as + BM*BK;
    #pragma unroll
    for (int ki=0;ki<BK/32;ki++){
      bf16x8 af[MI], bfr[NI];
      #pragma unroll
      for (int mi=0;mi<MI;mi++){
        int row = wm*WTM + mi*16 + lr;
        af[mi] = *(const bf16x8*)&as[row*BK + (((ki*4+lg) ^ swz)<<3)];
      }
      #pragma unroll
      for (int ni=0;ni<NI;ni++){
        int row = wn*WTN + ni*16 + lr;
        bfr[ni] = *(const bf16x8*)&bs[row*BK + (((ki*4+lg) ^ swz)<<3)];
      }
      __builtin_amdgcn_s_setprio(1);
      #pragma unroll
      for (int mi=0;mi<MI;mi++)
      #pragma unroll
      for (int ni=0;ni<NI;ni++)
        acc[mi][ni] = __builtin_amdgcn_mfma_f32_16x16x32_bf16(af[mi], bfr[ni], acc[mi][ni], 0,0,0);
      __builtin_amdgcn_s_setprio(0);
    }
  };

  int NT = K / BK;
  stage(0, 0);
  __syncthreads();
  int cur = 0;
  for (int t=0; t<NT; ++t){
    if (t+1 < NT) stage(cur^1, (t+1)*BK);
    compute(cur);
    __syncthreads();
    cur ^= 1;
  }

  int rbase = lg*4;
  #pragma unroll
  for (int mi=0;mi<MI;mi++)
  #pragma unroll
  for (int ni=0;ni<NI;ni++){
    f32x4 v = acc[mi][ni];
    int n = bn0 + wn*WTN + ni*16 + lr;
    float bv = bp ? bp[n] : 0.f;
    float scv = (n < scaleNlim) ? scaleVal : 1.f;
    #pragma unroll
    for (int r=0;r<4;r++){
      int m = bm0 + wm*WTM + mi*16 + rbase + r;
      float val = (v[r] + bv) * scv;
      if (relu) val = fmaxf(val, 0.f);
      long o = cbase + (long)m*ldc + n;
      if (f32out) ((float*)Cp)[o] = val;
      else ((unsigned short*)Cp)[o] = f2bf(val);
    }
  }
}

// ---------------- single GEMM  C = A @ W^T ----------------
template<int BM, int BN, int WTM, int WTN, int BK>
__global__ void __launch_bounds__(512) gemm_lds(
    const unsigned short* __restrict__ A, long aSlot, int aDiv, long aHead, int lda,
    const unsigned short* __restrict__ W, long wSlot, long wHead, long wExp, int ldw,
    const int* __restrict__ eidx, const float* __restrict__ bias, long biasExp,
    void* __restrict__ Cp, long cSlot, long cHead, int ldc,
    int K, int HZ, int f32out, int relu, int scaleNlim, float scaleVal)
{
  constexpr int SLOTS = BK/8;
  static_assert((BM/WTM)*(BN/WTN) == 8, "8 waves");
  static_assert((BM*SLOTS)%512==0 && (BN*SLOTS)%512==0, "stage coverage");
  __shared__ unsigned short smem[2*(BM+BN)*BK];

  int nwg = gridDim.x*gridDim.y*gridDim.z;
  int wg = xcd_swz(blockIdx.x + gridDim.x*(blockIdx.y + gridDim.y*blockIdx.z), nwg);
  int bx = wg % gridDim.x; int t1 = wg / gridDim.x;
  int by = t1 % gridDim.y; int z  = t1 / gridDim.y;

  int slot = z / HZ;
  int h = z - slot*HZ;
  int e = eidx ? eidx[slot] : 0;
  const unsigned short* Ap = A + (long)(slot/aDiv)*aSlot + (long)h*aHead + (long)by*BM*lda;
  const unsigned short* Wp = W + (long)slot*wSlot + (long)h*wHead + (long)e*wExp + (long)bx*BN*ldw;
  const float* bp = bias ? (bias + (long)e*biasExp) : nullptr;
  long cbase = (long)slot*cSlot + (long)h*cHead;

  gemm_core<BM,BN,WTM,WTN,BK>(Ap, Wp, bp, Cp, cbase, ldc, lda, ldw,
      by*BM, bx*BN, K, f32out, relu, scaleNlim, scaleVal, smem);
}

// ---------------- dual GEMM: QKV (set0) + CA-KV (set1) in one launch ----------------
__global__ void __launch_bounds__(512) gemm_dual(
    const unsigned short* __restrict__ A0, long aSlot0,
    const unsigned short* __restrict__ W0, const float* __restrict__ bias0,
    unsigned short* __restrict__ C0, long cSlot0, int ldc0,
    const unsigned short* __restrict__ A1, long aSlot1,
    const unsigned short* __restrict__ W1, const float* __restrict__ bias1,
    unsigned short* __restrict__ C1, long cSlot1, int ldc1,
    const int* __restrict__ eidx)
{
  constexpr int BM=128, BN=256, WTM=64, WTN=64, BK=32;
  __shared__ unsigned short smem[2*(BM+BN)*BK];
  const int NBLK0 = 6*2*NSLOT;   // QKV: bx<6, by<2
  int nwg = gridDim.x;
  int wg = xcd_swz(blockIdx.x, nwg);

  const unsigned short *Ap, *Wp; const float* bp;
  unsigned short* Cp; long cbase; int ldc, bm0, bn0, scaleNlim;
  if (wg < NBLK0){
    int bx = wg % 6; int t1 = wg / 6;
    int by = t1 % 2; int slot = t1 / 2;
    int e = eidx[slot];
    bm0 = by*BM; bn0 = bx*BN;
    Ap = A0 + (long)(slot/2)*aSlot0 + (long)bm0*D_;
    Wp = W0 + (long)e*(3*D_*D_) + (long)bn0*D_;
    bp = bias0 + (long)e*(3*D_);
    Cp = C0; cbase = (long)slot*cSlot0; ldc = ldc0; scaleNlim = D_;
  } else {
    int w1 = wg - NBLK0;
    int bx = w1 % 4; int t1 = w1 / 4;
    int by = t1 % 4; int slot = t1 / 4;
    int e = eidx[slot];
    bm0 = by*BM; bn0 = bx*BN;
    Ap = A1 + (long)(slot/2)*aSlot1 + (long)bm0*D_;
    Wp = W1 + (long)e*(3*D_*D_) + (long)bn0*D_;
    bp = bias1 + (long)e*(3*D_);
    Cp = C1; cbase = (long)slot*cSlot1; ldc = ldc1; scaleNlim = 0;
  }
  gemm_core<BM,BN,WTM,WTN,BK>(Ap, Wp, bp, Cp, cbase, ldc, D_, D_,
      bm0, bn0, 512, 0, 0, scaleNlim, 0.125f, smem);
}

// ---------------- residual add + LayerNorm (vectorized; A fp32 or bf16; bf16 out) ----------------
template<int ABF>
__global__ void __launch_bounds__(256) add_ln_k(
    const void* __restrict__ Ab_, int aDiv, long aStride,
    const unsigned short* __restrict__ Bb, long bStride,
    const float* __restrict__ G, const float* __restrict__ Bt,
    const int* __restrict__ eidx,
    unsigned short* __restrict__ OutB)
{
  int row = blockIdx.x*4 + (threadIdx.x>>6);
  int slot = row>>8, t = row&255;
  int lane = threadIdx.x&63;
  int d0 = lane*8;
  float x[8];
  if (ABF){
    const unsigned short* a = (const unsigned short*)Ab_ + (long)(slot/aDiv)*aStride + (long)t*D_ + d0;
    ushort4 a0 = *(const ushort4*)a, a1 = *(const ushort4*)(a+4);
    x[0]=bf2f(a0.x); x[1]=bf2f(a0.y); x[2]=bf2f(a0.z); x[3]=bf2f(a0.w);
    x[4]=bf2f(a1.x); x[5]=bf2f(a1.y); x[6]=bf2f(a1.z); x[7]=bf2f(a1.w);
  } else {
    const float* a = (const float*)Ab_ + (long)(slot/aDiv)*aStride + (long)t*D_ + d0;
    float4 a0 = *(const float4*)a, a1 = *(const float4*)(a+4);
    x[0]=a0.x; x[1]=a0.y; x[2]=a0.z; x[3]=a0.w;
    x[4]=a1.x; x[5]=a1.y; x[6]=a1.z; x[7]=a1.w;
  }
  const unsigned short* b = Bb + (long)slot*bStride + (long)t*D_ + d0;
  ushort4 b0 = *(const ushort4*)b, b1 = *(const ushort4*)(b+4);
  x[0]+=bf2f(b0.x); x[1]+=bf2f(b0.y); x[2]+=bf2f(b0.z); x[3]+=bf2f(b0.w);
  x[4]+=bf2f(b1.x); x[5]+=bf2f(b1.y); x[6]+=bf2f(b1.z); x[7]+=bf2f(b1.w);
  float s=0.f;
  #pragma unroll
  for (int i=0;i<8;i++) s += x[i];
  #pragma unroll
  for (int o=32;o;o>>=1) s += __shfl_xor(s,o);
  float m = s*(1.f/D_);
  float q=0.f;
  #pragma unroll
  for (int i=0;i<8;i++){ float d=x[i]-m; q+=d*d; }
  #pragma unroll
  for (int o=32;o;o>>=1) q += __shfl_xor(q,o);
  float rs = rsqrtf(q*(1.f/D_)+1e-5f);
  int e = eidx[slot];
  const float* g  = G  + (long)e*D_ + d0;
  const float* bt = Bt + (long)e*D_ + d0;
  float4 g0 = *(const float4*)g, g1 = *(const float4*)(g+4);
  float4 t0 = *(const float4*)bt, t1 = *(const float4*)(bt+4);
  float gg[8] = {g0.x,g0.y,g0.z,g0.w,g1.x,g1.y,g1.z,g1.w};
  float tt[8] = {t0.x,t0.y,t0.z,t0.w,t1.x,t1.y,t1.z,t1.w};
  long ob = (long)slot*(T_*D_) + (long)t*D_ + d0;
  ushort4 o0, o1;
  float y0=(x[0]-m)*rs*gg[0]+tt[0], y1=(x[1]-m)*rs*gg[1]+tt[1];
  float y2=(x[2]-m)*rs*gg[2]+tt[2], y3=(x[3]-m)*rs*gg[3]+tt[3];
  float y4=(x[4]-m)*rs*gg[4]+tt[4], y5=(x[5]-m)*rs*gg[5]+tt[5];
  float y6=(x[6]-m)*rs*gg[6]+tt[6], y7=(x[7]-m)*rs*gg[7]+tt[7];
  o0.x=f2bf(y0); o0.y=f2bf(y1); o0.z=f2bf(y2); o0.w=f2bf(y3);
  o1.x=f2bf(y4); o1.y=f2bf(y5); o1.z=f2bf(y6); o1.w=f2bf(y7);
  *(ushort4*)(OutB+ob) = o0;
  *(ushort4*)(OutB+ob+4) = o1;
}

// ---------------- residual add + LayerNorm (n3) + weighted slot combine (bf16 in) ----------------
__global__ void __launch_bounds__(256) add_ln_comb_k(
    const unsigned short* __restrict__ x2b, const unsigned short* __restrict__ proj,
    const float* __restrict__ G, const float* __restrict__ Bt,
    const int* __restrict__ eidx, const float* __restrict__ wgt,
    float* __restrict__ dstF, unsigned short* __restrict__ dstB)
{
  int row = blockIdx.x*4 + (threadIdx.x>>6);   // b*256+t
  int b = row>>8, t = row&255;
  int lane = threadIdx.x&63;
  int d0 = lane*8;
  float out[8];
  #pragma unroll
  for (int i=0;i<8;i++) out[i]=0.f;
  #pragma unroll
  for (int s2i=0;s2i<2;s2i++){
    int slot = 2*b + s2i;
    int e = eidx[slot];
    float w = wgt[slot];
    const unsigned short* a = x2b + (long)slot*(T_*D_) + (long)t*D_ + d0;
    const unsigned short* p = proj + (long)slot*(T_*D_) + (long)t*D_ + d0;
    ushort4 a0 = *(const ushort4*)a, a1 = *(const ushort4*)(a+4);
    ushort4 p0 = *(const ushort4*)p, p1 = *(const ushort4*)(p+4);
    float x[8];
    x[0]=bf2f(a0.x)+bf2f(p0.x); x[1]=bf2f(a0.y)+bf2f(p0.y);
    x[2]=bf2f(a0.z)+bf2f(p0.z); x[3]=bf2f(a0.w)+bf2f(p0.w);
    x[4]=bf2f(a1.x)+bf2f(p1.x); x[5]=bf2f(a1.y)+bf2f(p1.y);
    x[6]=bf2f(a1.z)+bf2f(p1.z); x[7]=bf2f(a1.w)+bf2f(p1.w);
    float s=0.f;
    #pragma unroll
    for (int i=0;i<8;i++) s += x[i];
    #pragma unroll
    for (int o=32;o;o>>=1) s += __shfl_xor(s,o);
    float m = s*(1.f/D_);
    float q=0.f;
    #pragma unroll
    for (int i=0;i<8;i++){ float d=x[i]-m; q+=d*d; }
    #pragma unroll
    for (int o=32;o;o>>=1) q += __shfl_xor(q,o);
    float rs = rsqrtf(q*(1.f/D_)+1e-5f);
    const float* g  = G  + (long)e*D_ + d0;
    const float* bt = Bt + (long)e*D_ + d0;
    float4 g0 = *(const float4*)g, g1 = *(const float4*)(g+4);
    float4 t0 = *(const float4*)bt, t1 = *(const float4*)(bt+4);
    float gg[8] = {g0.x,g0.y,g0.z,g0.w,g1.x,g1.y,g1.z,g1.w};
    float tt[8] = {t0.x,t0.y,t0.z,t0.w,t1.x,t1.y,t1.z,t1.w};
    #pragma unroll
    for (int i=0;i<8;i++) out[i] += w*((x[i]-m)*rs*gg[i]+tt[i]);
  }
  long ob = (long)row*D_ + d0;
  float4 f0 = {out[0],out[1],out[2],out[3]};
  float4 f1 = {out[4],out[5],out[6],out[7]};
  *(float4*)(dstF+ob) = f0;
  *(float4*)(dstF+ob+4) = f1;
  ushort4 o0, o1;
  o0.x=f2bf(out[0]); o0.y=f2bf(out[1]); o0.z=f2bf(out[2]); o0.w=f2bf(out[3]);
  o1.x=f2bf(out[4]); o1.y=f2bf(out[5]); o1.z=f2bf(out[6]); o1.w=f2bf(out[7]);
  *(ushort4*)(dstB+ob) = o0;
  *(ushort4*)(dstB+ob+4) = o1;
}

extern "C" void kernel_launch(void* const* d_in, const int* in_sizes, int n_in,
                              void* d_out, int out_size, void* d_ws, size_t ws_size,
                              hipStream_t stream)
{
  const float* tgt      = (const float*)d_in[0];
  const float* memory   = (const float*)d_in[1];
  const float* router_w = (const float*)d_in[2];
  const float* sa_in_w  = (const float*)d_in[3];
  const float* sa_in_b  = (const float*)d_in[4];
  const float* sa_out_w = (const float*)d_in[5];
  const float* sa_out_b = (const float*)d_in[6];
  const float* ca_in_w  = (const float*)d_in[7];
  const float* ca_in_b  = (const float*)d_in[8];
  const float* ca_out_w = (const float*)d_in[9];
  const float* ca_out_b = (const float*)d_in[10];
  const float* lin1_w   = (const float*)d_in[11];
  const float* lin1_b   = (const float*)d_in[12];
  const float* lin2_w   = (const float*)d_in[13];
  const float* lin2_b   = (const float*)d_in[14];
  const float* n1_g = (const float*)d_in[15];
  const float* n1_b = (const float*)d_in[16];
  const float* n2_g = (const float*)d_in[17];
  const float* n2_b = (const float*)d_in[18];
  const float* n3_g = (const float*)d_in[19];
  const float* n3_b = (const float*)d_in[20];

  char* ws = (char*)d_ws;
  size_t off = 0;
  auto alloc = [&](size_t bytes)->char*{
    char* p = ws + off; off += (bytes + 255) & ~(size_t)255; return p;
  };
  unsigned short* xb    = (unsigned short*)alloc(2ull*B_*T_*D_);
  unsigned short* memb  = (unsigned short*)alloc(2ull*B_*S_*D_);
  float*          x     = (float*)alloc(4ull*B_*T_*D_);
  float*          part  = (float*)alloc(4ull*B_*8*D_);
  int*            eidx  = (int*)alloc(4ull*NSLOT);
  float*          wgt   = (float*)alloc(4ull*NSLOT);
  unsigned short* wSaIn  = (unsigned short*)alloc(2ull*E_*3*D_*D_);
  unsigned short* wSaOut = (unsigned short*)alloc(2ull*E_*D_*D_);
  unsigned short* wCaIn  = (unsigned short*)alloc(2ull*E_*3*D_*D_);
  unsigned short* wCaOut = (unsigned short*)alloc(2ull*E_*D_*D_);
  unsigned short* wL1    = (unsigned short*)alloc(2ull*E_*DFF_*D_);
  unsigned short* wL2    = (unsigned short*)alloc(2ull*E_*D_*DFF_);
  unsigned short* qkv   = (unsigned short*)alloc(2ull*NSLOT*T_*3*D_);
  unsigned short* ffh   = (unsigned short*)alloc(2ull*NSLOT*T_*DFF_);
  unsigned short* attn  = (unsigned short*)alloc(2ull*NSLOT*T_*D_);
  unsigned short* proj  = (unsigned short*)alloc(2ull*NSLOT*T_*D_);
  unsigned short* x1b   = (unsigned short*)alloc(2ull*NSLOT*T_*D_);
  unsigned short* cq    = (unsigned short*)alloc(2ull*NSLOT*T_*D_);
  unsigned short* mkv   = (unsigned short*)alloc(2ull*NSLOT*S_*2*D_);
  unsigned short* x2b   = (unsigned short*)alloc(2ull*NSLOT*T_*D_);

  cast_bf16_k<<<1024,256,0,stream>>>(tgt,    xb,   (long)B_*T_*D_);
  cast_bf16_k<<<1024,256,0,stream>>>(memory, memb, (long)B_*S_*D_);

  const float* xcur = tgt;
  for (int l=0; l<L_; ++l){
    // pooled partials (blocks 0..127) + weight cast (blocks 128..) in one launch
    prep_k<<<B_*8 + 2048,256,0,stream>>>(xcur, part,
      sa_in_w  + (size_t)l*E_*3*D_*D_, sa_out_w + (size_t)l*E_*D_*D_,
      ca_in_w  + (size_t)l*E_*3*D_*D_, ca_out_w + (size_t)l*E_*D_*D_,
      lin1_w   + (size_t)l*E_*DFF_*D_, lin2_w   + (size_t)l*E_*D_*DFF_,
      wSaIn, wSaOut, wCaIn, wCaOut, wL1, wL2);
    route2_k<<<B_,256,0,stream>>>(part, router_w + (size_t)l*E_*D_, eidx, wgt);

    // fused QKV (set0) + cross-attn K,V (set1)
    gemm_dual<<<dim3(6*2*NSLOT + 4*4*NSLOT),512,0,stream>>>(
      xb,   (long)T_*D_, wSaIn,                sa_in_b + (size_t)l*E_*3*D_,
      qkv,  (long)T_*3*D_, 3*D_,
      memb, (long)S_*D_, wCaIn + (size_t)D_*D_, ca_in_b + (size_t)l*E_*3*D_ + D_,
      mkv,  (long)S_*2*D_, 2*D_,
      eidx);
    // fused self-attention (V transposed in-kernel from qkv)
    fattn_k<4><<<dim3(T_/128, NSLOT*H_),512,0,stream>>>(
      qkv, (long)T_*3*D_, 3*D_,
      qkv + D_, (long)T_*3*D_, 3*D_,
      qkv + 2*D_, (long)T_*3*D_, 3*D_,
      attn, (long)T_*D_, D_);
    // self-attn out proj (bf16 out)
    gemm_lds<64,128,32,32,64><<<dim3(4,4,NSLOT),512,0,stream>>>(
      attn, (long)T_*D_, 1, 0, D_,
      wSaOut, 0, 0, (long)D_*D_, D_,
      eidx, sa_out_b + (size_t)l*E_*D_, D_,
      proj, (long)T_*D_, 0, D_,
      512, 1, 0, 0, 0, 1.f);
    add_ln_k<0><<<2048,256,0,stream>>>(xcur, 2, (long)T_*D_, proj, (long)T_*D_,
      n1_g + (size_t)l*E_*D_, n1_b + (size_t)l*E_*D_, eidx, x1b);
    // cross-attn Q (scaled)
    gemm_lds<64,128,32,32,64><<<dim3(4,4,NSLOT),512,0,stream>>>(
      x1b, (long)T_*D_, 1, 0, D_,
      wCaIn, 0, 0, (long)3*D_*D_, D_,
      eidx, ca_in_b + (size_t)l*E_*3*D_, 3*D_,
      cq, (long)T_*D_, 0, D_,
      512, 1, 0, 0, D_, 0.125f);
    // fused cross-attention (V transposed in-kernel from mkv)
    fattn_k<8><<<dim3(T_/128, NSLOT*H_),512,0,stream>>>(
      cq, (long)T_*D_, D_,
      mkv, (long)S_*2*D_, 2*D_,
      mkv + D_, (long)S_*2*D_, 2*D_,
      attn, (long)T_*D_, D_);
    // cross-attn out proj (bf16 out)
    gemm_lds<64,128,32,32,64><<<dim3(4,4,NSLOT),512,0,stream>>>(
      attn, (long)T_*D_, 1, 0, D_,
      wCaOut, 0, 0, (long)D_*D_, D_,
      eidx, ca_out_b + (size_t)l*E_*D_, D_,
      proj, (long)T_*D_, 0, D_,
      512, 1, 0, 0, 0, 1.f);
    add_ln_k<1><<<2048,256,0,stream>>>(x1b, 1, (long)T_*D_, proj, (long)T_*D_,
      n2_g + (size_t)l*E_*D_, n2_b + (size_t)l*E_*D_, eidx, x2b);
    // FFN1 (+relu)
    gemm_lds<128,256,64,64,32><<<dim3(8,2,NSLOT),512,0,stream>>>(
      x2b, (long)T_*D_, 1, 0, D_,
      wL1, 0, 0, (long)DFF_*D_, D_,
      eidx, lin1_b + (size_t)l*E_*DFF_, DFF_,
      ffh, (long)T_*DFF_, 0, DFF_,
      512, 1, 0, 1, 0, 1.f);
    // FFN2 (bf16 out)
    gemm_lds<64,128,32,32,64><<<dim3(4,4,NSLOT),512,0,stream>>>(
      ffh, (long)T_*DFF_, 1, 0, DFF_,
      wL2, 0, 0, (long)D_*DFF_, DFF_,
      eidx, lin2_b + (size_t)l*E_*D_, D_,
      proj, (long)T_*D_, 0, D_,
      2048, 1, 0, 0, 0, 1.f);
    // n3 LN + weighted combine
    float* dstF = (l==L_-1) ? (float*)d_out : x;
    add_ln_comb_k<<<1024,256,0,stream>>>(x2b, proj,
      n3_g + (size_t)l*E_*D_, n3_b + (size_t)l*E_*D_, eidx, wgt, dstF, xb);
    xcur = x;
  }
}